// Round 3
// baseline (3995.539 us; speedup 1.0000x reference)
//
#include <hip/hip_runtime.h>
#include <cstdint>
#include <cstddef>

// ---------------- problem constants ----------------
#define B_    64
#define N_    197
#define DIM_  768
#define NH_   12
#define HD_   64
#define NP_   196
#define SCALE_ 0.125f
#define EPS_   1.1920929e-07f
#define BN_EPS_ 1e-5f
#define ALPHA_ 0.01f

#define M_TOK   (B_*N_)        // 12608
#define M_PATCH (B_*NP_)       // 12544
#define OUT_MAIN (M_TOK*DIM_)  // 9682944

#define SROW_ 200              // padded col stride of score rows
#define CHUNK_ 192             // (b,h) batches per attention chunk
#define SBATCH_ (N_*SROW_)     // 39400 floats per batch

// scalar workspace layout (float offsets within SC)
#define W_OFF     0
#define HP_OFF    16
#define HPROW_OFF 128
#define NVB_OFF   144
#define SVB_OFF   720
#define STATS_OFF 784
#define W1_OFF    1024
#define W3_OFF    50176
#define PART_OFF  99328
#define SC_FLOATS 132096

// ---------------- prep ----------------
__global__ void prep_kernel(const float* __restrict__ uniforms, const float* __restrict__ kth,
                            const float* __restrict__ head_probs, const float* __restrict__ v_b,
                            float* __restrict__ SC, float* __restrict__ out_tail)
{
    int t = threadIdx.x;
    if (t == 0) {
        float ind[3];
        for (int i = 0; i < 3; i++) {
            float s = 1.f/(1.f + expf(-kth[i]));
            float p = fminf(fmaxf(s, EPS_), 1.f - EPS_);
            float u = fminf(fmaxf(uniforms[i], EPS_), 1.f - EPS_);
            float logit = logf(u) - log1pf(-u) + logf(p) - log1pf(-p);
            ind[i] = (logit > 0.f) ? 1.f : 0.f;
        }
        SC[W_OFF+0] = ind[2];
        SC[W_OFF+1] = ind[1]*(1.f-ind[2]);
        SC[W_OFF+2] = ind[0]*(1.f-ind[1])*(1.f-ind[2]);
        float kprod = 1.f;
        for (int i = 0; i < 3; i++) {
            float ktv = 1.f/(1.f + expf(-kth[i]));
            kprod *= (ktv > 0.5f) ? 1.f : 0.f;
            out_tail[i]   = kprod;
            out_tail[3+i] = ktv;
        }
    }
    if (t < 9) {
        float mx = -1e30f;
        for (int h = 0; h < 12; h++) mx = fmaxf(mx, head_probs[h*9+t]);
        float e[12]; float s = 0.f;
        for (int h = 0; h < 12; h++) { e[h] = expf((head_probs[h*9+t]-mx)/ALPHA_); s += e[h]; }
        for (int h = 0; h < 12; h++) SC[HP_OFF + h*9 + t] = e[h]/s;
    }
    __syncthreads();
    if (t < 12) {
        float s = 0.f;
        for (int k = 0; k < 9; k++) s += SC[HP_OFF + t*9 + k];
        SC[HPROW_OFF + t] = s;
    }
    if (t < 64) {
        float sv = 0.f;
        for (int k = 0; k < 9; k++) {
            float s = 0.f;
            for (int h = 0; h < 12; h++) s += v_b[h*64+t]*SC[HP_OFF + h*9 + k];
            SC[NVB_OFF + t*9 + k] = s;
            sv += s;
        }
        SC[SVB_OFF + t] = sv;
    }
}

// ---------------- generic GEMM: C[M x Nc] = A[M x K] @ W[Nc x K]^T (+bias) ----------------
#define GT 64
#define GK 16
template<bool BIAS>
__global__ __launch_bounds__(256) void gemm_xwt(
    const float* __restrict__ A, const float* __restrict__ W,
    const float* __restrict__ bias, float* __restrict__ C,
    int M, int Ncols, int K)
{
    __shared__ float As[GK][GT+4];
    __shared__ float Bs[GK][GT+4];
    const int tid = threadIdx.x;
    const int tx = tid & 15, ty = tid >> 4;
    const int m0 = blockIdx.y * GT, n0 = blockIdx.x * GT;
    float acc[4][4] = {};
    for (int k0 = 0; k0 < K; k0 += GK) {
        #pragma unroll
        for (int i = 0; i < 4; i++) {
            int r = ty + i*16;
            As[tx][r] = A[(size_t)(m0 + r)*K + (k0 + tx)];
            Bs[tx][r] = W[(size_t)(n0 + r)*K + (k0 + tx)];
        }
        __syncthreads();
        #pragma unroll
        for (int kk = 0; kk < GK; kk++) {
            const float4 a4 = *(const float4*)&As[kk][ty*4];
            const float4 b4 = *(const float4*)&Bs[kk][tx*4];
            const float a[4] = {a4.x, a4.y, a4.z, a4.w};
            const float b[4] = {b4.x, b4.y, b4.z, b4.w};
            #pragma unroll
            for (int i = 0; i < 4; i++)
                #pragma unroll
                for (int j = 0; j < 4; j++)
                    acc[i][j] += a[i]*b[j];
        }
        __syncthreads();
    }
    #pragma unroll
    for (int i = 0; i < 4; i++) {
        int m = m0 + ty*4 + i;
        #pragma unroll
        for (int j = 0; j < 4; j++) {
            int n = n0 + tx*4 + j;
            float v = acc[i][j];
            if (BIAS) v += bias[n];
            C[(size_t)m*Ncols + n] = v;
        }
    }
}

// ---------------- batched S = Q K^T * SCALE ----------------
__global__ __launch_bounds__(256) void sgemm_qk(
    const float* __restrict__ qk, float* __restrict__ S, int bh0)
{
    __shared__ float As[16][68];
    __shared__ float Bs[16][68];
    const int tid = threadIdx.x;
    const int tx = tid & 15, ty = tid >> 4;
    const int n0 = blockIdx.x * 64, m0 = blockIdx.y * 64;
    const int bz = blockIdx.z;
    const int bh = bh0 + bz;
    const int b = bh / NH_, h = bh % NH_;
    const float* Abase = qk + (size_t)(b*N_)*1536 + h*64;        // Q
    const float* Bbase = Abase + 768;                            // K
    float acc[4][4] = {};
    #pragma unroll
    for (int k0 = 0; k0 < 64; k0 += 16) {
        #pragma unroll
        for (int i = 0; i < 4; i++) {
            int r = ty + i*16;
            int ra = m0 + r; ra = (ra < N_) ? ra : (N_-1);
            int rb = n0 + r; rb = (rb < N_) ? rb : (N_-1);
            As[tx][r] = Abase[(size_t)ra*1536 + k0 + tx];
            Bs[tx][r] = Bbase[(size_t)rb*1536 + k0 + tx];
        }
        __syncthreads();
        #pragma unroll
        for (int kk = 0; kk < 16; kk++) {
            const float4 a4 = *(const float4*)&As[kk][ty*4];
            const float4 b4 = *(const float4*)&Bs[kk][tx*4];
            const float a[4] = {a4.x, a4.y, a4.z, a4.w};
            const float b[4] = {b4.x, b4.y, b4.z, b4.w};
            #pragma unroll
            for (int i = 0; i < 4; i++)
                #pragma unroll
                for (int j = 0; j < 4; j++)
                    acc[i][j] += a[i]*b[j];
        }
        __syncthreads();
    }
    float* Sb = S + (size_t)bz*SBATCH_;
    #pragma unroll
    for (int i = 0; i < 4; i++) {
        int m = m0 + ty*4 + i;
        if (m >= N_) continue;
        #pragma unroll
        for (int j = 0; j < 4; j++) {
            int n = n0 + tx*4 + j;
            if (n < N_) Sb[(size_t)m*SROW_ + n] = acc[i][j] * SCALE_;
        }
    }
}

// ---------------- softmax over score rows (wave per row) ----------------
__global__ __launch_bounds__(256) void softmax_kernel(float* __restrict__ S)
{
    const int bz = blockIdx.x;
    const int row = blockIdx.y*4 + (threadIdx.x >> 6);
    const int lane = threadIdx.x & 63;
    if (row >= N_) return;
    float* p = S + (size_t)bz*SBATCH_ + (size_t)row*SROW_;
    float v0 = (lane       < N_) ? p[lane]       : -1e30f;
    float v1 = (lane + 64  < N_) ? p[lane + 64]  : -1e30f;
    float v2 = (lane + 128 < N_) ? p[lane + 128] : -1e30f;
    float v3 = (lane + 192 < N_) ? p[lane + 192] : -1e30f;
    float mx = fmaxf(fmaxf(v0, v1), fmaxf(v2, v3));
    #pragma unroll
    for (int o = 32; o; o >>= 1) mx = fmaxf(mx, __shfl_xor(mx, o, 64));
    float e0 = (lane       < N_) ? __expf(v0 - mx) : 0.f;
    float e1 = (lane + 64  < N_) ? __expf(v1 - mx) : 0.f;
    float e2 = (lane + 128 < N_) ? __expf(v2 - mx) : 0.f;
    float e3 = (lane + 192 < N_) ? __expf(v3 - mx) : 0.f;
    float sum = e0 + e1 + e2 + e3;
    #pragma unroll
    for (int o = 32; o; o >>= 1) sum += __shfl_xor(sum, o, 64);
    float inv = 1.f / sum;
    if (lane       < N_) p[lane]       = e0 * inv;
    if (lane + 64  < N_) p[lane + 64]  = e1 * inv;
    if (lane + 128 < N_) p[lane + 128] = e2 * inv;
    if (lane + 192 < N_) p[lane + 192] = e3 * inv;
}

// ---------------- batched O = P V + v_b ----------------
__global__ __launch_bounds__(256) void pv_gemm(
    const float* __restrict__ S, const float* __restrict__ vw,
    const float* __restrict__ v_b, float* __restrict__ msa, int bh0)
{
    __shared__ float As[16][68];   // [k][n-row]
    __shared__ float Bs[16][68];   // [k][d]
    const int tid = threadIdx.x;
    const int tx = tid & 15, ty = tid >> 4;
    const int m0 = blockIdx.x * 64;
    const int bz = blockIdx.y;
    const int bh = bh0 + bz;
    const int b = bh / NH_, h = bh % NH_;
    const float* A  = S + (size_t)bz*SBATCH_;
    const float* Vb = vw + (size_t)(b*N_)*768 + h*64;
    const int kk_ld = tid >> 4;          // 0..15
    const int nn_ld = (tid & 15) * 4;    // 0..60
    float acc[4][4] = {};
    for (int k0 = 0; k0 < N_; k0 += 16) {
        #pragma unroll
        for (int i = 0; i < 4; i++) {
            int r = ty + i*16;
            int ra = m0 + r; ra = (ra < N_) ? ra : (N_-1);
            As[tx][r] = (k0 + tx < N_) ? A[(size_t)ra*SROW_ + k0 + tx] : 0.f;
        }
        {
            int kr = k0 + kk_ld;
            float4 v4 = make_float4(0.f, 0.f, 0.f, 0.f);
            if (kr < N_) v4 = *(const float4*)&Vb[(size_t)kr*768 + nn_ld];
            *(float4*)&Bs[kk_ld][nn_ld] = v4;
        }
        __syncthreads();
        #pragma unroll
        for (int kk = 0; kk < 16; kk++) {
            const float4 a4 = *(const float4*)&As[kk][ty*4];
            const float4 b4 = *(const float4*)&Bs[kk][tx*4];
            const float a[4] = {a4.x, a4.y, a4.z, a4.w};
            const float b[4] = {b4.x, b4.y, b4.z, b4.w};
            #pragma unroll
            for (int i = 0; i < 4; i++)
                #pragma unroll
                for (int j = 0; j < 4; j++)
                    acc[i][j] += a[i]*b[j];
        }
        __syncthreads();
    }
    #pragma unroll
    for (int i = 0; i < 4; i++) {
        int n = m0 + ty*4 + i;
        if (n >= N_) continue;
        float* orow = msa + (size_t)(b*N_ + n)*768 + h*64;
        #pragma unroll
        for (int j = 0; j < 4; j++) {
            int d = tx*4 + j;
            orow[d] = acc[i][j] + v_b[h*64 + d];
        }
    }
}

// ---------------- new_v ----------------
__global__ __launch_bounds__(256) void newv_kernel(
    const float* __restrict__ vw, const float* __restrict__ SC, float* __restrict__ newv)
{
    int idx = blockIdx.x*256 + threadIdx.x;
    if (idx >= M_PATCH*64) return;
    int d = idx & 63; int bp = idx >> 6;
    int p = bp % NP_, b = bp / NP_;
    const float* src = vw + (size_t)(b*N_ + 1 + p)*768 + d;
    float vh[12];
    #pragma unroll
    for (int h = 0; h < 12; h++) vh[h] = src[h*64];
    #pragma unroll
    for (int k = 0; k < 9; k++) {
        float s = 0.f;
        #pragma unroll
        for (int h = 0; h < 12; h++) s += vh[h]*SC[HP_OFF + h*9 + k];
        newv[((size_t)bp*9 + k)*64 + d] = s;
    }
}

__global__ __launch_bounds__(256) void c1pre_kernel(
    const float* __restrict__ newv, const float* __restrict__ SC, float* __restrict__ dst)
{
    int i = blockIdx.x*256 + threadIdx.x;
    if (i >= M_PATCH*64) return;
    int d = i & 63; int bp = i >> 6;
    dst[i] = newv[((size_t)bp*9 + 4)*64 + d] + SC[NVB_OFF + d*9 + 4];
}

__global__ __launch_bounds__(256) void c3pre_kernel(
    const float* __restrict__ newv, const float* __restrict__ SC, float* __restrict__ dst)
{
    int i = blockIdx.x*256 + threadIdx.x;
    if (i >= M_PATCH*64) return;
    int d = i & 63; int bij = i >> 6;
    int j = bij % 14; int bi = bij / 14; int irow = bi % 14; int b = bi / 14;
    float acc = SC[SVB_OFF + d];
    #pragma unroll
    for (int p = 0; p < 9; p++) {
        int h1 = p % 3, h2 = p / 3;
        int y = irow + h1 - 1, x = j + h2 - 1;
        if (y >= 0 && y < 14 && x >= 0 && x < 14)
            acc += newv[(((size_t)b*NP_ + y*14 + x)*9 + p)*64 + d];
    }
    dst[i] = acc;
}

// ---------------- BN ----------------
__global__ __launch_bounds__(256) void bnstat_kernel(
    const float* __restrict__ src, int nelem, float* __restrict__ partial)
{
    __shared__ float sd[256], sq[256];
    int tid = threadIdx.x;
    float s = 0.f, q = 0.f;
    int stride = gridDim.x * 256;
    for (int i = blockIdx.x*256 + tid; i < nelem; i += stride) {
        float v = src[i]; s += v; q += v*v;
    }
    sd[tid] = s; sq[tid] = q;
    __syncthreads();
    if (tid < 64) {
        float ts = sd[tid]+sd[tid+64]+sd[tid+128]+sd[tid+192];
        float tq = sq[tid]+sq[tid+64]+sq[tid+128]+sq[tid+192];
        partial[blockIdx.x*128 + tid]      = ts;
        partial[blockIdx.x*128 + 64 + tid] = tq;
    }
}

__global__ void bnreduce_kernel(const float* __restrict__ partial, int nblk, float* __restrict__ stats)
{
    int t = threadIdx.x;  // 128
    float s = 0.f;
    for (int i = 0; i < nblk; i++) s += partial[i*128 + t];
    stats[t] = s;
}

__global__ __launch_bounds__(256) void bnapply_kernel(
    float* __restrict__ buf, int nelem, const float* __restrict__ stats,
    const float* __restrict__ g, const float* __restrict__ bb, float invN)
{
    int i = blockIdx.x*256 + threadIdx.x;
    if (i >= nelem) return;
    int d = i & 63;
    float mean = stats[d]*invN;
    float var  = stats[64+d]*invN - mean*mean;
    float sc = rsqrtf(var + BN_EPS_) * g[d];
    float v = (buf[i] - mean)*sc + bb[d];
    buf[i] = fmaxf(v, 0.f);
}

// ---------------- W1/W3 ----------------
__global__ __launch_bounds__(256) void w13_kernel(
    const float* __restrict__ proj_w, const float* __restrict__ SC,
    float* __restrict__ W1, float* __restrict__ W3)
{
    int idx = blockIdx.x*256 + threadIdx.x;
    if (idx >= 768*64) return;
    int d = idx & 63, c = idx >> 6;
    float s1 = 0.f, s3 = 0.f;
    #pragma unroll
    for (int h = 0; h < 12; h++) {
        float pw = proj_w[(size_t)c*768 + h*64 + d];
        s1 += pw * SC[HP_OFF + h*9 + 4];
        s3 += pw * SC[HPROW_OFF + h];
    }
    W1[idx] = s1; W3[idx] = s3;
}

// ---------------- final blend ----------------
__global__ __launch_bounds__(256) void blend_kernel(
    const float* __restrict__ x, const float* __restrict__ pbuf,
    const float* __restrict__ c1o, const float* __restrict__ c3o,
    const float* __restrict__ SC, float* __restrict__ out)
{
    int i = blockIdx.x*256 + threadIdx.x;
    if (i >= OUT_MAIN) return;
    int cc = i % 768; int bn = i / 768; int n = bn % 197;
    float w0 = SC[0], w1 = SC[1], w2 = SC[2];
    float m = pbuf[i];
    float c1v, c3v;
    if (n == 0) { c1v = x[i]; c3v = x[i]; }
    else {
        size_t q = ((size_t)(bn - (bn/197) - 1))*768 + cc;
        c1v = c1o[q]; c3v = c3o[q];
    }
    out[i] = w0*m + w1*c3v + w2*c1v;
}

// ---------------- launch ----------------
extern "C" void kernel_launch(void* const* d_in, const int* in_sizes, int n_in,
                              void* d_out, int out_size, void* d_ws, size_t ws_size,
                              hipStream_t stream)
{
    const float* x        = (const float*)d_in[0];
    const float* uniforms = (const float*)d_in[1];
    const float* qk_w     = (const float*)d_in[2];
    const float* qk_b     = (const float*)d_in[3];
    const float* v_w      = (const float*)d_in[4];
    const float* v_b      = (const float*)d_in[5];
    const float* proj_w   = (const float*)d_in[6];
    const float* proj_b   = (const float*)d_in[7];
    const float* bn1_g    = (const float*)d_in[8];
    const float* bn1_b    = (const float*)d_in[9];
    const float* bn3_g    = (const float*)d_in[10];
    const float* bn3_b    = (const float*)d_in[11];
    const float* kth      = (const float*)d_in[12];
    const float* head_probs = (const float*)d_in[13];
    float* out = (float*)d_out;

    float* ws     = (float*)d_ws;
    float* qkbuf  = ws;                        // (B,N,1536)
    float* vw     = qkbuf + 19365888;          // (B,N,768)
    float* pbuf   = vw + 9682944;              // proj output / S chunk scratch
    float* SC     = pbuf + 9682944;
    // aliases (write-before-read each call):
    float* sbuf   = pbuf;                      // 192*39400 = 7,564,800 <= 9,682,944
    float* newv   = qkbuf;
    float* c1out  = qkbuf;
    float* c3out  = qkbuf + 9633792;
    float* c1buf  = vw;
    float* c3buf  = vw + 802816;
    float* msa    = out;                       // out as early scratch; blend rewrites
    float* W1     = SC + W1_OFF;
    float* W3     = SC + W3_OFF;
    float* stats  = SC + STATS_OFF;
    float* part   = SC + PART_OFF;

    prep_kernel<<<1, 256, 0, stream>>>(uniforms, kth, head_probs, v_b, SC, out + OUT_MAIN);

    gemm_xwt<true><<<dim3(24,197), 256, 0, stream>>>(x, qk_w, qk_b, qkbuf, M_TOK, 1536, 768);
    gemm_xwt<false><<<dim3(12,197), 256, 0, stream>>>(x, v_w, nullptr, vw, M_TOK, 768, 768);

    // attention in 4 chunks of 192 (b,h) batches
    for (int c = 0; c < 4; c++) {
        int bh0 = c * CHUNK_;
        sgemm_qk<<<dim3(4,4,CHUNK_), 256, 0, stream>>>(qkbuf, sbuf, bh0);
        softmax_kernel<<<dim3(CHUNK_,50), 256, 0, stream>>>(sbuf);
        pv_gemm<<<dim3(4,CHUNK_), 256, 0, stream>>>(sbuf, vw, v_b, msa, bh0);
    }

    // proj -> pbuf (sbuf dead from here)
    gemm_xwt<true><<<dim3(12,197), 256, 0, stream>>>(msa, proj_w, proj_b, pbuf, M_TOK, 768, 768);

    newv_kernel<<<3136, 256, 0, stream>>>(vw, SC, newv);

    c1pre_kernel<<<3136, 256, 0, stream>>>(newv, SC, c1buf);
    bnstat_kernel<<<256, 256, 0, stream>>>(c1buf, M_PATCH*64, part);
    bnreduce_kernel<<<1, 128, 0, stream>>>(part, 256, stats);
    bnapply_kernel<<<3136, 256, 0, stream>>>(c1buf, M_PATCH*64, stats, bn1_g, bn1_b, 1.0f/12544.0f);

    c3pre_kernel<<<3136, 256, 0, stream>>>(newv, SC, c3buf);
    bnstat_kernel<<<256, 256, 0, stream>>>(c3buf, M_PATCH*64, part);
    bnreduce_kernel<<<1, 128, 0, stream>>>(part, 256, stats);
    bnapply_kernel<<<3136, 256, 0, stream>>>(c3buf, M_PATCH*64, stats, bn3_g, bn3_b, 1.0f/12544.0f);

    w13_kernel<<<192, 256, 0, stream>>>(proj_w, SC, W1, W3);

    gemm_xwt<true><<<dim3(12,196), 256, 0, stream>>>(c1buf, W1, proj_b, c1out, M_PATCH, 768, 64);
    gemm_xwt<true><<<dim3(12,196), 256, 0, stream>>>(c3buf, W3, proj_b, c3out, M_PATCH, 768, 64);

    blend_kernel<<<37824, 256, 0, stream>>>(x, pbuf, c1out, c3out, SC, out);
}

// Round 5
// 1361.005 us; speedup vs baseline: 2.9357x; 2.9357x over previous
//
#include <hip/hip_runtime.h>
#include <cstdint>
#include <cstddef>

// ---------------- problem constants ----------------
#define B_    64
#define N_    197
#define DIM_  768
#define NH_   12
#define HD_   64
#define NP_   196
#define SCALE_ 0.125f
#define EPS_   1.1920929e-07f
#define BN_EPS_ 1e-5f
#define ALPHA_ 0.01f

#define M_TOK   (B_*N_)        // 12608
#define M_PATCH (B_*NP_)       // 12544
#define OUT_MAIN (M_TOK*DIM_)  // 9682944

#define SROW_ 256              // padded col stride of score rows (>= 255 so widest f4 store stays in-row)
#define CHUNK_ 192             // (b,h) batches per attention chunk
#define SBATCH_ (N_*SROW_)     // 50432 floats per batch; 192*50432 = 9,682,944 = pbuf size exactly

// scalar workspace layout (float offsets within SC)
#define W_OFF     0
#define HP_OFF    16
#define HPROW_OFF 128
#define NVB_OFF   144
#define SVB_OFF   720
#define STATS_OFF 784
#define W1_OFF    1024
#define W3_OFF    50176
#define PART_OFF  99328
#define SC_FLOATS 132096

// ---------------- prep ----------------
__global__ void prep_kernel(const float* __restrict__ uniforms, const float* __restrict__ kth,
                            const float* __restrict__ head_probs, const float* __restrict__ v_b,
                            float* __restrict__ SC, float* __restrict__ out_tail)
{
    int t = threadIdx.x;
    if (t == 0) {
        float ind[3];
        for (int i = 0; i < 3; i++) {
            float s = 1.f/(1.f + expf(-kth[i]));
            float p = fminf(fmaxf(s, EPS_), 1.f - EPS_);
            float u = fminf(fmaxf(uniforms[i], EPS_), 1.f - EPS_);
            float logit = logf(u) - log1pf(-u) + logf(p) - log1pf(-p);
            ind[i] = (logit > 0.f) ? 1.f : 0.f;
        }
        SC[W_OFF+0] = ind[2];
        SC[W_OFF+1] = ind[1]*(1.f-ind[2]);
        SC[W_OFF+2] = ind[0]*(1.f-ind[1])*(1.f-ind[2]);
        float kprod = 1.f;
        for (int i = 0; i < 3; i++) {
            float ktv = 1.f/(1.f + expf(-kth[i]));
            kprod *= (ktv > 0.5f) ? 1.f : 0.f;
            out_tail[i]   = kprod;
            out_tail[3+i] = ktv;
        }
    }
    if (t < 9) {
        float mx = -1e30f;
        for (int h = 0; h < 12; h++) mx = fmaxf(mx, head_probs[h*9+t]);
        float e[12]; float s = 0.f;
        for (int h = 0; h < 12; h++) { e[h] = expf((head_probs[h*9+t]-mx)/ALPHA_); s += e[h]; }
        for (int h = 0; h < 12; h++) SC[HP_OFF + h*9 + t] = e[h]/s;
    }
    __syncthreads();
    if (t < 12) {
        float s = 0.f;
        for (int k = 0; k < 9; k++) s += SC[HP_OFF + t*9 + k];
        SC[HPROW_OFF + t] = s;
    }
    if (t < 64) {
        float sv = 0.f;
        for (int k = 0; k < 9; k++) {
            float s = 0.f;
            for (int h = 0; h < 12; h++) s += v_b[h*64+t]*SC[HP_OFF + h*9 + k];
            SC[NVB_OFF + t*9 + k] = s;
            sv += s;
        }
        SC[SVB_OFF + t] = sv;
    }
}

// ---------------- generic GEMM: C[M x Nc] = A[M x K] @ W[Nc x K]^T (+bias) ----------------
#define GT 64
#define GK 16
template<bool BIAS>
__global__ __launch_bounds__(256) void gemm_xwt(
    const float* __restrict__ A, const float* __restrict__ W,
    const float* __restrict__ bias, float* __restrict__ C,
    int M, int Ncols, int K)
{
    __shared__ float As[GK][GT+4];
    __shared__ float Bs[GK][GT+4];
    const int tid = threadIdx.x;
    const int tx = tid & 15, ty = tid >> 4;
    const int m0 = blockIdx.y * GT, n0 = blockIdx.x * GT;
    float acc[4][4] = {};
    for (int k0 = 0; k0 < K; k0 += GK) {
        #pragma unroll
        for (int i = 0; i < 4; i++) {
            int r = ty + i*16;
            As[tx][r] = A[(size_t)(m0 + r)*K + (k0 + tx)];
            Bs[tx][r] = W[(size_t)(n0 + r)*K + (k0 + tx)];
        }
        __syncthreads();
        #pragma unroll
        for (int kk = 0; kk < GK; kk++) {
            const float4 a4 = *(const float4*)&As[kk][ty*4];
            const float4 b4 = *(const float4*)&Bs[kk][tx*4];
            const float a[4] = {a4.x, a4.y, a4.z, a4.w};
            const float b[4] = {b4.x, b4.y, b4.z, b4.w};
            #pragma unroll
            for (int i = 0; i < 4; i++)
                #pragma unroll
                for (int j = 0; j < 4; j++)
                    acc[i][j] += a[i]*b[j];
        }
        __syncthreads();
    }
    float4 bv = make_float4(0.f,0.f,0.f,0.f);
    if (BIAS) bv = *(const float4*)&bias[n0 + tx*4];
    #pragma unroll
    for (int i = 0; i < 4; i++) {
        int m = m0 + ty*4 + i;
        float4 o = make_float4(acc[i][0]+bv.x, acc[i][1]+bv.y, acc[i][2]+bv.z, acc[i][3]+bv.w);
        *(float4*)&C[(size_t)m*Ncols + n0 + tx*4] = o;
    }
}

// ---------------- batched S = Q K^T * SCALE ----------------
__global__ __launch_bounds__(256) void sgemm_qk(
    const float* __restrict__ qk, float* __restrict__ S, int bh0)
{
    __shared__ float As[16][68];
    __shared__ float Bs[16][68];
    const int tid = threadIdx.x;
    const int tx = tid & 15, ty = tid >> 4;
    const int n0 = blockIdx.x * 64, m0 = blockIdx.y * 64;
    const int bz = blockIdx.z;
    const int bh = bh0 + bz;
    const int b = bh / NH_, h = bh % NH_;
    const float* Abase = qk + (size_t)(b*N_)*1536 + h*64;        // Q
    const float* Bbase = Abase + 768;                            // K
    float acc[4][4] = {};
    for (int k0 = 0; k0 < 64; k0 += 16) {
        #pragma unroll
        for (int i = 0; i < 4; i++) {
            int r = ty + i*16;
            int ra = m0 + r; ra = (ra < N_) ? ra : (N_-1);
            int rb = n0 + r; rb = (rb < N_) ? rb : (N_-1);
            As[tx][r] = Abase[(size_t)ra*1536 + k0 + tx];
            Bs[tx][r] = Bbase[(size_t)rb*1536 + k0 + tx];
        }
        __syncthreads();
        #pragma unroll
        for (int kk = 0; kk < 16; kk++) {
            const float4 a4 = *(const float4*)&As[kk][ty*4];
            const float4 b4 = *(const float4*)&Bs[kk][tx*4];
            const float a[4] = {a4.x, a4.y, a4.z, a4.w};
            const float b[4] = {b4.x, b4.y, b4.z, b4.w};
            #pragma unroll
            for (int i = 0; i < 4; i++)
                #pragma unroll
                for (int j = 0; j < 4; j++)
                    acc[i][j] += a[i]*b[j];
        }
        __syncthreads();
    }
    // float4 stores; cols 197..255 are in-row padding (masked downstream)
    float* Sb = S + (size_t)bz*SBATCH_;
    #pragma unroll
    for (int i = 0; i < 4; i++) {
        int m = m0 + ty*4 + i;
        if (m >= N_) continue;   // stay within this batch's 197-row slab
        float4 o = make_float4(acc[i][0]*SCALE_, acc[i][1]*SCALE_,
                               acc[i][2]*SCALE_, acc[i][3]*SCALE_);
        *(float4*)&Sb[(size_t)m*SROW_ + n0 + tx*4] = o;
    }
}

// ---------------- softmax over score rows (wave per row) ----------------
__global__ __launch_bounds__(256) void softmax_kernel(float* __restrict__ S)
{
    const int bz = blockIdx.x;
    const int row = blockIdx.y*4 + (threadIdx.x >> 6);
    const int lane = threadIdx.x & 63;
    if (row >= N_) return;
    float* p = S + (size_t)bz*SBATCH_ + (size_t)row*SROW_;
    float v0 = (lane       < N_) ? p[lane]       : -1e30f;
    float v1 = (lane + 64  < N_) ? p[lane + 64]  : -1e30f;
    float v2 = (lane + 128 < N_) ? p[lane + 128] : -1e30f;
    float v3 = (lane + 192 < N_) ? p[lane + 192] : -1e30f;
    float mx = fmaxf(fmaxf(v0, v1), fmaxf(v2, v3));
    #pragma unroll
    for (int o = 32; o; o >>= 1) mx = fmaxf(mx, __shfl_xor(mx, o, 64));
    float e0 = (lane       < N_) ? __expf(v0 - mx) : 0.f;
    float e1 = (lane + 64  < N_) ? __expf(v1 - mx) : 0.f;
    float e2 = (lane + 128 < N_) ? __expf(v2 - mx) : 0.f;
    float e3 = (lane + 192 < N_) ? __expf(v3 - mx) : 0.f;
    float sum = e0 + e1 + e2 + e3;
    #pragma unroll
    for (int o = 32; o; o >>= 1) sum += __shfl_xor(sum, o, 64);
    float inv = 1.f / sum;
    if (lane       < N_) p[lane]       = e0 * inv;
    if (lane + 64  < N_) p[lane + 64]  = e1 * inv;
    if (lane + 128 < N_) p[lane + 128] = e2 * inv;
    if (lane + 192 < N_) p[lane + 192] = e3 * inv;
}

// ---------------- batched O = P V + v_b ----------------
__global__ __launch_bounds__(256) void pv_gemm(
    const float* __restrict__ S, const float* __restrict__ vw,
    const float* __restrict__ v_b, float* __restrict__ msa, int bh0)
{
    __shared__ float As[16][68];   // [k][n-row]
    __shared__ float Bs[16][68];   // [k][d]
    const int tid = threadIdx.x;
    const int tx = tid & 15, ty = tid >> 4;
    const int m0 = blockIdx.x * 64;
    const int bz = blockIdx.y;
    const int bh = bh0 + bz;
    const int b = bh / NH_, h = bh % NH_;
    const float* A  = S + (size_t)bz*SBATCH_;
    const float* Vb = vw + (size_t)(b*N_)*768 + h*64;
    const int kk_ld = tid >> 4;          // 0..15
    const int nn_ld = (tid & 15) * 4;    // 0..60
    float acc[4][4] = {};
    for (int k0 = 0; k0 < N_; k0 += 16) {
        #pragma unroll
        for (int i = 0; i < 4; i++) {
            int r = ty + i*16;
            int ra = m0 + r; ra = (ra < N_) ? ra : (N_-1);
            As[tx][r] = (k0 + tx < N_) ? A[(size_t)ra*SROW_ + k0 + tx] : 0.f;
        }
        {
            int kr = k0 + kk_ld;
            float4 v4 = make_float4(0.f, 0.f, 0.f, 0.f);
            if (kr < N_) v4 = *(const float4*)&Vb[(size_t)kr*768 + nn_ld];
            *(float4*)&Bs[kk_ld][nn_ld] = v4;
        }
        __syncthreads();
        #pragma unroll
        for (int kk = 0; kk < 16; kk++) {
            const float4 a4 = *(const float4*)&As[kk][ty*4];
            const float4 b4 = *(const float4*)&Bs[kk][tx*4];
            const float a[4] = {a4.x, a4.y, a4.z, a4.w};
            const float b[4] = {b4.x, b4.y, b4.z, b4.w};
            #pragma unroll
            for (int i = 0; i < 4; i++)
                #pragma unroll
                for (int j = 0; j < 4; j++)
                    acc[i][j] += a[i]*b[j];
        }
        __syncthreads();
    }
    const float4 bv = *(const float4*)&v_b[h*64 + tx*4];
    #pragma unroll
    for (int i = 0; i < 4; i++) {
        int n = m0 + ty*4 + i;
        if (n >= N_) continue;
        float* orow = msa + (size_t)(b*N_ + n)*768 + h*64;
        float4 o = make_float4(acc[i][0]+bv.x, acc[i][1]+bv.y, acc[i][2]+bv.z, acc[i][3]+bv.w);
        *(float4*)&orow[tx*4] = o;
    }
}

// ---------------- new_v ----------------
__global__ __launch_bounds__(256) void newv_kernel(
    const float* __restrict__ vw, const float* __restrict__ SC, float* __restrict__ newv)
{
    int idx = blockIdx.x*256 + threadIdx.x;
    if (idx >= M_PATCH*64) return;
    int d = idx & 63; int bp = idx >> 6;
    int p = bp % NP_, b = bp / NP_;
    const float* src = vw + (size_t)(b*N_ + 1 + p)*768 + d;
    float vh[12];
    #pragma unroll
    for (int h = 0; h < 12; h++) vh[h] = src[h*64];
    #pragma unroll
    for (int k = 0; k < 9; k++) {
        float s = 0.f;
        #pragma unroll
        for (int h = 0; h < 12; h++) s += vh[h]*SC[HP_OFF + h*9 + k];
        newv[((size_t)bp*9 + k)*64 + d] = s;
    }
}

__global__ __launch_bounds__(256) void c1pre_kernel(
    const float* __restrict__ newv, const float* __restrict__ SC, float* __restrict__ dst)
{
    int i = blockIdx.x*256 + threadIdx.x;
    if (i >= M_PATCH*64) return;
    int d = i & 63; int bp = i >> 6;
    dst[i] = newv[((size_t)bp*9 + 4)*64 + d] + SC[NVB_OFF + d*9 + 4];
}

__global__ __launch_bounds__(256) void c3pre_kernel(
    const float* __restrict__ newv, const float* __restrict__ SC, float* __restrict__ dst)
{
    int i = blockIdx.x*256 + threadIdx.x;
    if (i >= M_PATCH*64) return;
    int d = i & 63; int bij = i >> 6;
    int j = bij % 14; int bi = bij / 14; int irow = bi % 14; int b = bi / 14;
    float acc = SC[SVB_OFF + d];
    #pragma unroll
    for (int p = 0; p < 9; p++) {
        int h1 = p % 3, h2 = p / 3;
        int y = irow + h1 - 1, x = j + h2 - 1;
        if (y >= 0 && y < 14 && x >= 0 && x < 14)
            acc += newv[(((size_t)b*NP_ + y*14 + x)*9 + p)*64 + d];
    }
    dst[i] = acc;
}

// ---------------- BN ----------------
__global__ __launch_bounds__(256) void bnstat_kernel(
    const float* __restrict__ src, int nelem, float* __restrict__ partial)
{
    __shared__ float sd[256], sq[256];
    int tid = threadIdx.x;
    float s = 0.f, q = 0.f;
    int stride = gridDim.x * 256;
    for (int i = blockIdx.x*256 + tid; i < nelem; i += stride) {
        float v = src[i]; s += v; q += v*v;
    }
    sd[tid] = s; sq[tid] = q;
    __syncthreads();
    if (tid < 64) {
        float ts = sd[tid]+sd[tid+64]+sd[tid+128]+sd[tid+192];
        float tq = sq[tid]+sq[tid+64]+sq[tid+128]+sq[tid+192];
        partial[blockIdx.x*128 + tid]      = ts;
        partial[blockIdx.x*128 + 64 + tid] = tq;
    }
}

__global__ void bnreduce_kernel(const float* __restrict__ partial, int nblk, float* __restrict__ stats)
{
    int t = threadIdx.x;  // 128
    float s = 0.f;
    for (int i = 0; i < nblk; i++) s += partial[i*128 + t];
    stats[t] = s;
}

__global__ __launch_bounds__(256) void bnapply_kernel(
    float* __restrict__ buf, int nelem, const float* __restrict__ stats,
    const float* __restrict__ g, const float* __restrict__ bb, float invN)
{
    int i = blockIdx.x*256 + threadIdx.x;
    if (i >= nelem) return;
    int d = i & 63;
    float mean = stats[d]*invN;
    float var  = stats[64+d]*invN - mean*mean;
    float sc = rsqrtf(var + BN_EPS_) * g[d];
    float v = (buf[i] - mean)*sc + bb[d];
    buf[i] = fmaxf(v, 0.f);
}

// ---------------- W1/W3 ----------------
__global__ __launch_bounds__(256) void w13_kernel(
    const float* __restrict__ proj_w, const float* __restrict__ SC,
    float* __restrict__ W1, float* __restrict__ W3)
{
    int idx = blockIdx.x*256 + threadIdx.x;
    if (idx >= 768*64) return;
    int d = idx & 63, c = idx >> 6;
    float s1 = 0.f, s3 = 0.f;
    #pragma unroll
    for (int h = 0; h < 12; h++) {
        float pw = proj_w[(size_t)c*768 + h*64 + d];
        s1 += pw * SC[HP_OFF + h*9 + 4];
        s3 += pw * SC[HPROW_OFF + h];
    }
    W1[idx] = s1; W3[idx] = s3;
}

// ---------------- final blend ----------------
__global__ __launch_bounds__(256) void blend_kernel(
    const float* __restrict__ x, const float* __restrict__ pbuf,
    const float* __restrict__ c1o, const float* __restrict__ c3o,
    const float* __restrict__ SC, float* __restrict__ out)
{
    int i = blockIdx.x*256 + threadIdx.x;
    if (i >= OUT_MAIN) return;
    int cc = i % 768; int bn = i / 768; int n = bn % 197;
    float w0 = SC[0], w1 = SC[1], w2 = SC[2];
    float m = pbuf[i];
    float c1v, c3v;
    if (n == 0) { c1v = x[i]; c3v = x[i]; }
    else {
        size_t q = ((size_t)(bn - (bn/197) - 1))*768 + cc;
        c1v = c1o[q]; c3v = c3o[q];
    }
    out[i] = w0*m + w1*c3v + w2*c1v;
}

// ---------------- launch ----------------
extern "C" void kernel_launch(void* const* d_in, const int* in_sizes, int n_in,
                              void* d_out, int out_size, void* d_ws, size_t ws_size,
                              hipStream_t stream)
{
    const float* x        = (const float*)d_in[0];
    const float* uniforms = (const float*)d_in[1];
    const float* qk_w     = (const float*)d_in[2];
    const float* qk_b     = (const float*)d_in[3];
    const float* v_w      = (const float*)d_in[4];
    const float* v_b      = (const float*)d_in[5];
    const float* proj_w   = (const float*)d_in[6];
    const float* proj_b   = (const float*)d_in[7];
    const float* bn1_g    = (const float*)d_in[8];
    const float* bn1_b    = (const float*)d_in[9];
    const float* bn3_g    = (const float*)d_in[10];
    const float* bn3_b    = (const float*)d_in[11];
    const float* kth      = (const float*)d_in[12];
    const float* head_probs = (const float*)d_in[13];
    float* out = (float*)d_out;

    float* ws     = (float*)d_ws;
    float* qkbuf  = ws;                        // (B,N,1536)
    float* vw     = qkbuf + 19365888;          // (B,N,768)
    float* pbuf   = vw + 9682944;              // proj output / S chunk scratch
    float* SC     = pbuf + 9682944;
    // aliases (write-before-read each call):
    float* sbuf   = pbuf;                      // 192*50432 = 9,682,944 — exactly pbuf
    float* newv   = qkbuf;
    float* c1out  = qkbuf;
    float* c3out  = qkbuf + 9633792;
    float* c1buf  = vw;
    float* c3buf  = vw + 802816;
    float* msa    = out;                       // out as early scratch; blend rewrites
    float* W1     = SC + W1_OFF;
    float* W3     = SC + W3_OFF;
    float* stats  = SC + STATS_OFF;
    float* part   = SC + PART_OFF;

    prep_kernel<<<1, 256, 0, stream>>>(uniforms, kth, head_probs, v_b, SC, out + OUT_MAIN);

    gemm_xwt<true><<<dim3(24,197), 256, 0, stream>>>(x, qk_w, qk_b, qkbuf, M_TOK, 1536, 768);
    gemm_xwt<false><<<dim3(12,197), 256, 0, stream>>>(x, v_w, nullptr, vw, M_TOK, 768, 768);

    // attention in 4 chunks of 192 (b,h) batches
    for (int c = 0; c < 4; c++) {
        int bh0 = c * CHUNK_;
        sgemm_qk<<<dim3(4,4,CHUNK_), 256, 0, stream>>>(qkbuf, sbuf, bh0);
        softmax_kernel<<<dim3(CHUNK_,50), 256, 0, stream>>>(sbuf);
        pv_gemm<<<dim3(4,CHUNK_), 256, 0, stream>>>(sbuf, vw, v_b, msa, bh0);
    }

    // proj -> pbuf (sbuf dead from here)
    gemm_xwt<true><<<dim3(12,197), 256, 0, stream>>>(msa, proj_w, proj_b, pbuf, M_TOK, 768, 768);

    newv_kernel<<<3136, 256, 0, stream>>>(vw, SC, newv);

    c1pre_kernel<<<3136, 256, 0, stream>>>(newv, SC, c1buf);
    bnstat_kernel<<<256, 256, 0, stream>>>(c1buf, M_PATCH*64, part);
    bnreduce_kernel<<<1, 128, 0, stream>>>(part, 256, stats);
    bnapply_kernel<<<3136, 256, 0, stream>>>(c1buf, M_PATCH*64, stats, bn1_g, bn1_b, 1.0f/12544.0f);

    c3pre_kernel<<<3136, 256, 0, stream>>>(newv, SC, c3buf);
    bnstat_kernel<<<256, 256, 0, stream>>>(c3buf, M_PATCH*64, part);
    bnreduce_kernel<<<1, 128, 0, stream>>>(part, 256, stats);
    bnapply_kernel<<<3136, 256, 0, stream>>>(c3buf, M_PATCH*64, stats, bn3_g, bn3_b, 1.0f/12544.0f);

    w13_kernel<<<192, 256, 0, stream>>>(proj_w, SC, W1, W3);

    gemm_xwt<true><<<dim3(12,196), 256, 0, stream>>>(c1buf, W1, proj_b, c1out, M_PATCH, 768, 64);
    gemm_xwt<true><<<dim3(12,196), 256, 0, stream>>>(c3buf, W3, proj_b, c3out, M_PATCH, 768, 64);

    blend_kernel<<<37824, 256, 0, stream>>>(x, pbuf, c1out, c3out, SC, out);
}

// Round 6
// 813.562 us; speedup vs baseline: 4.9112x; 1.6729x over previous
//
#include <hip/hip_runtime.h>
#include <cstdint>
#include <cstddef>

// ---------------- problem constants ----------------
#define B_    64
#define N_    197
#define DIM_  768
#define NH_   12
#define HD_   64
#define NP_   196
#define SCALE_ 0.125f
#define EPS_   1.1920929e-07f
#define BN_EPS_ 1e-5f
#define ALPHA_ 0.01f

#define M_TOK   (B_*N_)        // 12608
#define M_PATCH (B_*NP_)       // 12544
#define OUT_MAIN (M_TOK*DIM_)  // 9682944

#define SROW_ 256
#define CHUNK_ 192
#define SBATCH_ (N_*SROW_)     // 50432

#define K2_ 1536               // doubled-K for split-bf16 GEMMs

// scalar workspace layout (float offsets within SC)
#define W_OFF     0
#define HP_OFF    16
#define HPROW_OFF 128
#define NVB_OFF   144
#define SVB_OFF   720
#define STATS_OFF 784
#define W1_OFF    1024
#define W3_OFF    50176
#define PART_OFF  99328
#define SC_FLOATS 132096

typedef short bf16x8_ __attribute__((ext_vector_type(8)));
typedef float f32x4_  __attribute__((ext_vector_type(4)));

// ---------------- prep ----------------
__global__ void prep_kernel(const float* __restrict__ uniforms, const float* __restrict__ kth,
                            const float* __restrict__ head_probs, const float* __restrict__ v_b,
                            float* __restrict__ SC, float* __restrict__ out_tail)
{
    int t = threadIdx.x;
    if (t == 0) {
        float ind[3];
        for (int i = 0; i < 3; i++) {
            float s = 1.f/(1.f + expf(-kth[i]));
            float p = fminf(fmaxf(s, EPS_), 1.f - EPS_);
            float u = fminf(fmaxf(uniforms[i], EPS_), 1.f - EPS_);
            float logit = logf(u) - log1pf(-u) + logf(p) - log1pf(-p);
            ind[i] = (logit > 0.f) ? 1.f : 0.f;
        }
        SC[W_OFF+0] = ind[2];
        SC[W_OFF+1] = ind[1]*(1.f-ind[2]);
        SC[W_OFF+2] = ind[0]*(1.f-ind[1])*(1.f-ind[2]);
        float kprod = 1.f;
        for (int i = 0; i < 3; i++) {
            float ktv = 1.f/(1.f + expf(-kth[i]));
            kprod *= (ktv > 0.5f) ? 1.f : 0.f;
            out_tail[i]   = kprod;
            out_tail[3+i] = ktv;
        }
    }
    if (t < 9) {
        float mx = -1e30f;
        for (int h = 0; h < 12; h++) mx = fmaxf(mx, head_probs[h*9+t]);
        float e[12]; float s = 0.f;
        for (int h = 0; h < 12; h++) { e[h] = expf((head_probs[h*9+t]-mx)/ALPHA_); s += e[h]; }
        for (int h = 0; h < 12; h++) SC[HP_OFF + h*9 + t] = e[h]/s;
    }
    __syncthreads();
    if (t < 12) {
        float s = 0.f;
        for (int k = 0; k < 9; k++) s += SC[HP_OFF + t*9 + k];
        SC[HPROW_OFF + t] = s;
    }
    if (t < 64) {
        float sv = 0.f;
        for (int k = 0; k < 9; k++) {
            float s = 0.f;
            for (int h = 0; h < 12; h++) s += v_b[h*64+t]*SC[HP_OFF + h*9 + k];
            SC[NVB_OFF + t*9 + k] = s;
            sv += s;
        }
        SC[SVB_OFF + t] = sv;
    }
}

// ---------------- fp32 -> bf16 conversions ----------------
__device__ __forceinline__ unsigned short bfr_(float f) {
    unsigned u = __float_as_uint(f);
    return (unsigned short)((u + 0x7FFFu + ((u >> 16) & 1u)) >> 16);
}

// out[2k] = bf16(x), out[2k+1] = bf16(x - hi)   (hi/lo interleave, packed as uint)
__global__ __launch_bounds__(256) void conv_hilo(const float* __restrict__ in,
                                                 unsigned int* __restrict__ out, int n4)
{
    int i = blockIdx.x*256 + threadIdx.x;
    if (i >= n4) return;
    float4 v = ((const float4*)in)[i];
    float f[4] = {v.x, v.y, v.z, v.w};
    unsigned r[4];
    #pragma unroll
    for (int j = 0; j < 4; j++) {
        unsigned short h = bfr_(f[j]);
        float hf = __uint_as_float((unsigned)h << 16);
        unsigned short l = bfr_(f[j] - hf);
        r[j] = (unsigned)h | ((unsigned)l << 16);
    }
    ((uint4*)out)[i] = make_uint4(r[0], r[1], r[2], r[3]);
}

// out[2k] = out[2k+1] = bf16(w)
__global__ __launch_bounds__(256) void conv_dup(const float* __restrict__ in,
                                                unsigned int* __restrict__ out, int n4)
{
    int i = blockIdx.x*256 + threadIdx.x;
    if (i >= n4) return;
    float4 v = ((const float4*)in)[i];
    float f[4] = {v.x, v.y, v.z, v.w};
    unsigned r[4];
    #pragma unroll
    for (int j = 0; j < 4; j++) {
        unsigned short h = bfr_(f[j]);
        r[j] = (unsigned)h | ((unsigned)h << 16);
    }
    ((uint4*)out)[i] = make_uint4(r[0], r[1], r[2], r[3]);
}

// ---------------- MFMA GEMM: C[M x Nc](fp32) = A2[M x K2](bf16) @ W2[Nc x K2]^T + bias ----
// 128x128 tile, 4 waves (2x2), each wave 4x4 fragments of 16x16x32 MFMA.
template<bool BIAS>
__global__ __launch_bounds__(256) void gemm_mfma(
    const unsigned short* __restrict__ A2, const unsigned short* __restrict__ W2,
    const float* __restrict__ bias, float* __restrict__ C,
    int M, int Ncols)
{
    __shared__ unsigned short At[128][40];   // 80B rows: bank-friendly ds_read_b128
    __shared__ unsigned short Bt[128][40];
    const int tid = threadIdx.x;
    const int m0 = blockIdx.y * 128, n0 = blockIdx.x * 128;
    const int wave = tid >> 6, lane = tid & 63;
    const int wr = (wave >> 1) * 64, wc = (wave & 1) * 64;
    const int fr = lane & 15;    // frag row/col
    const int fq = lane >> 4;    // k-octet / c-row quad
    const int sr = tid >> 2;     // staging row 0..63
    const int ss = (tid & 3) * 8;// staging ushort offset 0/8/16/24

    f32x4_ acc[4][4] = {};

    int ar0 = m0 + sr;        ar0 = (ar0 < M) ? ar0 : (M-1);
    int ar1 = m0 + 64 + sr;   ar1 = (ar1 < M) ? ar1 : (M-1);
    const size_t arow0 = (size_t)ar0 * K2_;
    const size_t arow1 = (size_t)ar1 * K2_;
    const size_t brow0 = (size_t)(n0 + sr) * K2_;
    const size_t brow1 = (size_t)(n0 + 64 + sr) * K2_;

    for (int k0 = 0; k0 < K2_; k0 += 32) {
        uint4 ra0 = *(const uint4*)(A2 + arow0 + k0 + ss);
        uint4 ra1 = *(const uint4*)(A2 + arow1 + k0 + ss);
        uint4 rb0 = *(const uint4*)(W2 + brow0 + k0 + ss);
        uint4 rb1 = *(const uint4*)(W2 + brow1 + k0 + ss);
        __syncthreads();   // previous iteration's frag reads complete
        *(uint4*)&At[sr][ss]      = ra0;
        *(uint4*)&At[64 + sr][ss] = ra1;
        *(uint4*)&Bt[sr][ss]      = rb0;
        *(uint4*)&Bt[64 + sr][ss] = rb1;
        __syncthreads();
        bf16x8_ a[4], b[4];
        #pragma unroll
        for (int i = 0; i < 4; i++) {
            a[i] = *(const bf16x8_*)&At[wr + i*16 + fr][fq*8];
            b[i] = *(const bf16x8_*)&Bt[wc + i*16 + fr][fq*8];
        }
        #pragma unroll
        for (int mi = 0; mi < 4; mi++)
            #pragma unroll
            for (int ni = 0; ni < 4; ni++)
                acc[mi][ni] = __builtin_amdgcn_mfma_f32_16x16x32_bf16(a[mi], b[ni], acc[mi][ni], 0, 0, 0);
    }

    float bv[4];
    #pragma unroll
    for (int ni = 0; ni < 4; ni++)
        bv[ni] = BIAS ? bias[n0 + wc + ni*16 + fr] : 0.f;
    #pragma unroll
    for (int mi = 0; mi < 4; mi++) {
        #pragma unroll
        for (int j = 0; j < 4; j++) {
            int row = m0 + wr + mi*16 + fq*4 + j;
            if (row < M) {
                float* crow = C + (size_t)row * Ncols + n0 + wc;
                #pragma unroll
                for (int ni = 0; ni < 4; ni++)
                    crow[ni*16 + fr] = acc[mi][ni][j] + bv[ni];
            }
        }
    }
}

// ---------------- fp32 GEMM (kept for K=64 branch GEMMs) ----------------
#define GT 64
#define GK 16
template<bool BIAS>
__global__ __launch_bounds__(256) void gemm_xwt(
    const float* __restrict__ A, const float* __restrict__ W,
    const float* __restrict__ bias, float* __restrict__ C,
    int M, int Ncols, int K)
{
    __shared__ float As[GK][GT+4];
    __shared__ float Bs[GK][GT+4];
    const int tid = threadIdx.x;
    const int tx = tid & 15, ty = tid >> 4;
    const int m0 = blockIdx.y * GT, n0 = blockIdx.x * GT;
    float acc[4][4] = {};
    for (int k0 = 0; k0 < K; k0 += GK) {
        #pragma unroll
        for (int i = 0; i < 4; i++) {
            int r = ty + i*16;
            As[tx][r] = A[(size_t)(m0 + r)*K + (k0 + tx)];
            Bs[tx][r] = W[(size_t)(n0 + r)*K + (k0 + tx)];
        }
        __syncthreads();
        #pragma unroll
        for (int kk = 0; kk < GK; kk++) {
            const float4 a4 = *(const float4*)&As[kk][ty*4];
            const float4 b4 = *(const float4*)&Bs[kk][tx*4];
            const float a[4] = {a4.x, a4.y, a4.z, a4.w};
            const float b[4] = {b4.x, b4.y, b4.z, b4.w};
            #pragma unroll
            for (int i = 0; i < 4; i++)
                #pragma unroll
                for (int j = 0; j < 4; j++)
                    acc[i][j] += a[i]*b[j];
        }
        __syncthreads();
    }
    float4 bv = make_float4(0.f,0.f,0.f,0.f);
    if (BIAS) bv = *(const float4*)&bias[n0 + tx*4];
    #pragma unroll
    for (int i = 0; i < 4; i++) {
        int m = m0 + ty*4 + i;
        float4 o = make_float4(acc[i][0]+bv.x, acc[i][1]+bv.y, acc[i][2]+bv.z, acc[i][3]+bv.w);
        *(float4*)&C[(size_t)m*Ncols + n0 + tx*4] = o;
    }
}

// ---------------- batched S = Q K^T * SCALE ----------------
__global__ __launch_bounds__(256) void sgemm_qk(
    const float* __restrict__ qk, float* __restrict__ S, int bh0)
{
    __shared__ float As[16][68];
    __shared__ float Bs[16][68];
    const int tid = threadIdx.x;
    const int tx = tid & 15, ty = tid >> 4;
    const int n0 = blockIdx.x * 64, m0 = blockIdx.y * 64;
    const int bz = blockIdx.z;
    const int bh = bh0 + bz;
    const int b = bh / NH_, h = bh % NH_;
    const float* Abase = qk + (size_t)(b*N_)*1536 + h*64;
    const float* Bbase = Abase + 768;
    float acc[4][4] = {};
    for (int k0 = 0; k0 < 64; k0 += 16) {
        #pragma unroll
        for (int i = 0; i < 4; i++) {
            int r = ty + i*16;
            int ra = m0 + r; ra = (ra < N_) ? ra : (N_-1);
            int rb = n0 + r; rb = (rb < N_) ? rb : (N_-1);
            As[tx][r] = Abase[(size_t)ra*1536 + k0 + tx];
            Bs[tx][r] = Bbase[(size_t)rb*1536 + k0 + tx];
        }
        __syncthreads();
        #pragma unroll
        for (int kk = 0; kk < 16; kk++) {
            const float4 a4 = *(const float4*)&As[kk][ty*4];
            const float4 b4 = *(const float4*)&Bs[kk][tx*4];
            const float a[4] = {a4.x, a4.y, a4.z, a4.w};
            const float b[4] = {b4.x, b4.y, b4.z, b4.w};
            #pragma unroll
            for (int i = 0; i < 4; i++)
                #pragma unroll
                for (int j = 0; j < 4; j++)
                    acc[i][j] += a[i]*b[j];
        }
        __syncthreads();
    }
    float* Sb = S + (size_t)bz*SBATCH_;
    #pragma unroll
    for (int i = 0; i < 4; i++) {
        int m = m0 + ty*4 + i;
        if (m >= N_) continue;
        float4 o = make_float4(acc[i][0]*SCALE_, acc[i][1]*SCALE_,
                               acc[i][2]*SCALE_, acc[i][3]*SCALE_);
        *(float4*)&Sb[(size_t)m*SROW_ + n0 + tx*4] = o;
    }
}

// ---------------- softmax over score rows ----------------
__global__ __launch_bounds__(256) void softmax_kernel(float* __restrict__ S)
{
    const int bz = blockIdx.x;
    const int row = blockIdx.y*4 + (threadIdx.x >> 6);
    const int lane = threadIdx.x & 63;
    if (row >= N_) return;
    float* p = S + (size_t)bz*SBATCH_ + (size_t)row*SROW_;
    float v0 = (lane       < N_) ? p[lane]       : -1e30f;
    float v1 = (lane + 64  < N_) ? p[lane + 64]  : -1e30f;
    float v2 = (lane + 128 < N_) ? p[lane + 128] : -1e30f;
    float v3 = (lane + 192 < N_) ? p[lane + 192] : -1e30f;
    float mx = fmaxf(fmaxf(v0, v1), fmaxf(v2, v3));
    #pragma unroll
    for (int o = 32; o; o >>= 1) mx = fmaxf(mx, __shfl_xor(mx, o, 64));
    float e0 = (lane       < N_) ? __expf(v0 - mx) : 0.f;
    float e1 = (lane + 64  < N_) ? __expf(v1 - mx) : 0.f;
    float e2 = (lane + 128 < N_) ? __expf(v2 - mx) : 0.f;
    float e3 = (lane + 192 < N_) ? __expf(v3 - mx) : 0.f;
    float sum = e0 + e1 + e2 + e3;
    #pragma unroll
    for (int o = 32; o; o >>= 1) sum += __shfl_xor(sum, o, 64);
    float inv = 1.f / sum;
    if (lane       < N_) p[lane]       = e0 * inv;
    if (lane + 64  < N_) p[lane + 64]  = e1 * inv;
    if (lane + 128 < N_) p[lane + 128] = e2 * inv;
    if (lane + 192 < N_) p[lane + 192] = e3 * inv;
}

// ---------------- batched O = P V + v_b ----------------
__global__ __launch_bounds__(256) void pv_gemm(
    const float* __restrict__ S, const float* __restrict__ vw,
    const float* __restrict__ v_b, float* __restrict__ msa, int bh0)
{
    __shared__ float As[16][68];
    __shared__ float Bs[16][68];
    const int tid = threadIdx.x;
    const int tx = tid & 15, ty = tid >> 4;
    const int m0 = blockIdx.x * 64;
    const int bz = blockIdx.y;
    const int bh = bh0 + bz;
    const int b = bh / NH_, h = bh % NH_;
    const float* A  = S + (size_t)bz*SBATCH_;
    const float* Vb = vw + (size_t)(b*N_)*768 + h*64;
    const int kk_ld = tid >> 4;
    const int nn_ld = (tid & 15) * 4;
    float acc[4][4] = {};
    for (int k0 = 0; k0 < N_; k0 += 16) {
        #pragma unroll
        for (int i = 0; i < 4; i++) {
            int r = ty + i*16;
            int ra = m0 + r; ra = (ra < N_) ? ra : (N_-1);
            As[tx][r] = (k0 + tx < N_) ? A[(size_t)ra*SROW_ + k0 + tx] : 0.f;
        }
        {
            int kr = k0 + kk_ld;
            float4 v4 = make_float4(0.f, 0.f, 0.f, 0.f);
            if (kr < N_) v4 = *(const float4*)&Vb[(size_t)kr*768 + nn_ld];
            *(float4*)&Bs[kk_ld][nn_ld] = v4;
        }
        __syncthreads();
        #pragma unroll
        for (int kk = 0; kk < 16; kk++) {
            const float4 a4 = *(const float4*)&As[kk][ty*4];
            const float4 b4 = *(const float4*)&Bs[kk][tx*4];
            const float a[4] = {a4.x, a4.y, a4.z, a4.w};
            const float b[4] = {b4.x, b4.y, b4.z, b4.w};
            #pragma unroll
            for (int i = 0; i < 4; i++)
                #pragma unroll
                for (int j = 0; j < 4; j++)
                    acc[i][j] += a[i]*b[j];
        }
        __syncthreads();
    }
    const float4 bv = *(const float4*)&v_b[h*64 + tx*4];
    #pragma unroll
    for (int i = 0; i < 4; i++) {
        int n = m0 + ty*4 + i;
        if (n >= N_) continue;
        float* orow = msa + (size_t)(b*N_ + n)*768 + h*64;
        float4 o = make_float4(acc[i][0]+bv.x, acc[i][1]+bv.y, acc[i][2]+bv.z, acc[i][3]+bv.w);
        *(float4*)&orow[tx*4] = o;
    }
}

// ---------------- new_v ----------------
__global__ __launch_bounds__(256) void newv_kernel(
    const float* __restrict__ vw, const float* __restrict__ SC, float* __restrict__ newv)
{
    int idx = blockIdx.x*256 + threadIdx.x;
    if (idx >= M_PATCH*64) return;
    int d = idx & 63; int bp = idx >> 6;
    int p = bp % NP_, b = bp / NP_;
    const float* src = vw + (size_t)(b*N_ + 1 + p)*768 + d;
    float vh[12];
    #pragma unroll
    for (int h = 0; h < 12; h++) vh[h] = src[h*64];
    #pragma unroll
    for (int k = 0; k < 9; k++) {
        float s = 0.f;
        #pragma unroll
        for (int h = 0; h < 12; h++) s += vh[h]*SC[HP_OFF + h*9 + k];
        newv[((size_t)bp*9 + k)*64 + d] = s;
    }
}

__global__ __launch_bounds__(256) void c1pre_kernel(
    const float* __restrict__ newv, const float* __restrict__ SC, float* __restrict__ dst)
{
    int i = blockIdx.x*256 + threadIdx.x;
    if (i >= M_PATCH*64) return;
    int d = i & 63; int bp = i >> 6;
    dst[i] = newv[((size_t)bp*9 + 4)*64 + d] + SC[NVB_OFF + d*9 + 4];
}

__global__ __launch_bounds__(256) void c3pre_kernel(
    const float* __restrict__ newv, const float* __restrict__ SC, float* __restrict__ dst)
{
    int i = blockIdx.x*256 + threadIdx.x;
    if (i >= M_PATCH*64) return;
    int d = i & 63; int bij = i >> 6;
    int j = bij % 14; int bi = bij / 14; int irow = bi % 14; int b = bi / 14;
    float acc = SC[SVB_OFF + d];
    #pragma unroll
    for (int p = 0; p < 9; p++) {
        int h1 = p % 3, h2 = p / 3;
        int y = irow + h1 - 1, x = j + h2 - 1;
        if (y >= 0 && y < 14 && x >= 0 && x < 14)
            acc += newv[(((size_t)b*NP_ + y*14 + x)*9 + p)*64 + d];
    }
    dst[i] = acc;
}

// ---------------- BN ----------------
__global__ __launch_bounds__(256) void bnstat_kernel(
    const float* __restrict__ src, int nelem, float* __restrict__ partial)
{
    __shared__ float sd[256], sq[256];
    int tid = threadIdx.x;
    float s = 0.f, q = 0.f;
    int stride = gridDim.x * 256;
    for (int i = blockIdx.x*256 + tid; i < nelem; i += stride) {
        float v = src[i]; s += v; q += v*v;
    }
    sd[tid] = s; sq[tid] = q;
    __syncthreads();
    if (tid < 64) {
        float ts = sd[tid]+sd[tid+64]+sd[tid+128]+sd[tid+192];
        float tq = sq[tid]+sq[tid+64]+sq[tid+128]+sq[tid+192];
        partial[blockIdx.x*128 + tid]      = ts;
        partial[blockIdx.x*128 + 64 + tid] = tq;
    }
}

__global__ void bnreduce_kernel(const float* __restrict__ partial, int nblk, float* __restrict__ stats)
{
    int t = threadIdx.x;  // 128
    float s = 0.f;
    for (int i = 0; i < nblk; i++) s += partial[i*128 + t];
    stats[t] = s;
}

__global__ __launch_bounds__(256) void bnapply_kernel(
    float* __restrict__ buf, int nelem, const float* __restrict__ stats,
    const float* __restrict__ g, const float* __restrict__ bb, float invN)
{
    int i = blockIdx.x*256 + threadIdx.x;
    if (i >= nelem) return;
    int d = i & 63;
    float mean = stats[d]*invN;
    float var  = stats[64+d]*invN - mean*mean;
    float sc = rsqrtf(var + BN_EPS_) * g[d];
    float v = (buf[i] - mean)*sc + bb[d];
    buf[i] = fmaxf(v, 0.f);
}

// ---------------- W1/W3 ----------------
__global__ __launch_bounds__(256) void w13_kernel(
    const float* __restrict__ proj_w, const float* __restrict__ SC,
    float* __restrict__ W1, float* __restrict__ W3)
{
    int idx = blockIdx.x*256 + threadIdx.x;
    if (idx >= 768*64) return;
    int d = idx & 63, c = idx >> 6;
    float s1 = 0.f, s3 = 0.f;
    #pragma unroll
    for (int h = 0; h < 12; h++) {
        float pw = proj_w[(size_t)c*768 + h*64 + d];
        s1 += pw * SC[HP_OFF + h*9 + 4];
        s3 += pw * SC[HPROW_OFF + h];
    }
    W1[idx] = s1; W3[idx] = s3;
}

// ---------------- final blend ----------------
__global__ __launch_bounds__(256) void blend_kernel(
    const float* __restrict__ x, const float* __restrict__ pbuf,
    const float* __restrict__ c1o, const float* __restrict__ c3o,
    const float* __restrict__ SC, float* __restrict__ out)
{
    int i = blockIdx.x*256 + threadIdx.x;
    if (i >= OUT_MAIN) return;
    int cc = i % 768; int bn = i / 768; int n = bn % 197;
    float w0 = SC[0], w1 = SC[1], w2 = SC[2];
    float m = pbuf[i];
    float c1v, c3v;
    if (n == 0) { c1v = x[i]; c3v = x[i]; }
    else {
        size_t q = ((size_t)(bn - (bn/197) - 1))*768 + cc;
        c1v = c1o[q]; c3v = c3o[q];
    }
    out[i] = w0*m + w1*c3v + w2*c1v;
}

// ---------------- launch ----------------
extern "C" void kernel_launch(void* const* d_in, const int* in_sizes, int n_in,
                              void* d_out, int out_size, void* d_ws, size_t ws_size,
                              hipStream_t stream)
{
    const float* x        = (const float*)d_in[0];
    const float* uniforms = (const float*)d_in[1];
    const float* qk_w     = (const float*)d_in[2];
    const float* qk_b     = (const float*)d_in[3];
    const float* v_w      = (const float*)d_in[4];
    const float* v_b      = (const float*)d_in[5];
    const float* proj_w   = (const float*)d_in[6];
    const float* proj_b   = (const float*)d_in[7];
    const float* bn1_g    = (const float*)d_in[8];
    const float* bn1_b    = (const float*)d_in[9];
    const float* bn3_g    = (const float*)d_in[10];
    const float* bn3_b    = (const float*)d_in[11];
    const float* kth      = (const float*)d_in[12];
    const float* head_probs = (const float*)d_in[13];
    float* out = (float*)d_out;

    // ws regions (float offsets); every alias written-in-full before read each call
    float* ws     = (float*)d_ws;
    float* qkbuf  = ws;                        // R1 [0, 19365888): qk fp32 (g_qk -> attn)
    float* vw     = ws + 19365888;             // R2 [.., +9682944): v fp32 (g_v -> newv)
    float* R3     = ws + 29048832;             // R3 [.., +9682944): x2 -> sbuf -> pbuf
    float* SC     = ws + 38731776;             // [.., +132096)
    // R3 phases:
    unsigned short* x2 = (unsigned short*)R3;  // bf16 hi/lo of x (dead after g_v)
    float* sbuf   = R3;                        // attention scores (dead after attn)
    float* pbuf   = R3;                        // proj output (g_proj -> blend)
    // R1 phases after attention:
    unsigned short* msa2 = (unsigned short*)qkbuf;             // [0, 9682944) float-slots
    unsigned short* pjw2 = (unsigned short*)(ws + 9682944);    // [9682944, +589824)
    float* newv   = qkbuf;                     // 7.2M (after g_proj)
    float* c1out  = qkbuf;
    float* c3out  = qkbuf + 9633792;
    float* c1buf  = vw;
    float* c3buf  = vw + 802816;
    // d_out phases: qkw2/vw2 (pre-attn) -> msa fp32 scratch (attn) -> final (blend)
    unsigned short* qkw2 = (unsigned short*)out;               // 2,359,296 ushorts
    unsigned short* vw2  = (unsigned short*)(out + 1179648);   // 1,179,648 ushorts
    float* msa    = out;
    float* W1     = SC + W1_OFF;
    float* W3     = SC + W3_OFF;
    float* stats  = SC + STATS_OFF;
    float* part   = SC + PART_OFF;

    prep_kernel<<<1, 256, 0, stream>>>(uniforms, kth, head_probs, v_b, SC, out + OUT_MAIN);

    // bf16 conversions: x (hi/lo), qk_w & v_w (dup)
    conv_hilo<<<9456, 256, 0, stream>>>(x, (unsigned int*)x2, 2420736);
    conv_dup<<<1152, 256, 0, stream>>>(qk_w, (unsigned int*)qkw2, 294912);
    conv_dup<<<576, 256, 0, stream>>>(v_w, (unsigned int*)vw2, 147456);

    // qk = x @ qk_w^T + qk_b ; v_weight = x @ v_w^T   (MFMA, split-bf16)
    gemm_mfma<true><<<dim3(12,99), 256, 0, stream>>>(x2, qkw2, qk_b, qkbuf, M_TOK, 1536);
    gemm_mfma<false><<<dim3(6,99), 256, 0, stream>>>(x2, vw2, nullptr, vw, M_TOK, 768);

    // attention (fp32), 4 chunks; writes msa into d_out scratch (kills qkw2/vw2, x2)
    for (int c = 0; c < 4; c++) {
        int bh0 = c * CHUNK_;
        sgemm_qk<<<dim3(4,4,CHUNK_), 256, 0, stream>>>(qkbuf, sbuf, bh0);
        softmax_kernel<<<dim3(CHUNK_,50), 256, 0, stream>>>(sbuf);
        pv_gemm<<<dim3(4,CHUNK_), 256, 0, stream>>>(sbuf, vw, v_b, msa, bh0);
    }

    // proj (MFMA): convert msa -> msa2 (into dead qkbuf), proj_w -> pjw2
    conv_hilo<<<9456, 256, 0, stream>>>(msa, (unsigned int*)msa2, 2420736);
    conv_dup<<<576, 256, 0, stream>>>(proj_w, (unsigned int*)pjw2, 147456);
    gemm_mfma<true><<<dim3(6,99), 256, 0, stream>>>(msa2, pjw2, proj_b, pbuf, M_TOK, 768);

    // conv branches (unchanged)
    newv_kernel<<<3136, 256, 0, stream>>>(vw, SC, newv);

    c1pre_kernel<<<3136, 256, 0, stream>>>(newv, SC, c1buf);
    bnstat_kernel<<<256, 256, 0, stream>>>(c1buf, M_PATCH*64, part);
    bnreduce_kernel<<<1, 128, 0, stream>>>(part, 256, stats);
    bnapply_kernel<<<3136, 256, 0, stream>>>(c1buf, M_PATCH*64, stats, bn1_g, bn1_b, 1.0f/12544.0f);

    c3pre_kernel<<<3136, 256, 0, stream>>>(newv, SC, c3buf);
    bnstat_kernel<<<256, 256, 0, stream>>>(c3buf, M_PATCH*64, part);
    bnreduce_kernel<<<1, 128, 0, stream>>>(part, 256, stats);
    bnapply_kernel<<<3136, 256, 0, stream>>>(c3buf, M_PATCH*64, stats, bn3_g, bn3_b, 1.0f/12544.0f);

    w13_kernel<<<192, 256, 0, stream>>>(proj_w, SC, W1, W3);

    gemm_xwt<true><<<dim3(12,196), 256, 0, stream>>>(c1buf, W1, proj_b, c1out, M_PATCH, 768, 64);
    gemm_xwt<true><<<dim3(12,196), 256, 0, stream>>>(c3buf, W3, proj_b, c3out, M_PATCH, 768, 64);

    blend_kernel<<<37824, 256, 0, stream>>>(x, pbuf, c1out, c3out, SC, out);
}

// Round 7
// 576.901 us; speedup vs baseline: 6.9259x; 1.4102x over previous
//
#include <hip/hip_runtime.h>
#include <cstdint>
#include <cstddef>

// ---------------- problem constants ----------------
#define B_    64
#define N_    197
#define DIM_  768
#define NH_   12
#define HD_   64
#define NP_   196
#define SCALE_ 0.125f
#define EPS_   1.1920929e-07f
#define BN_EPS_ 1e-5f
#define ALPHA_ 0.01f

#define M_TOK   (B_*N_)        // 12608
#define M_PATCH (B_*NP_)       // 12544
#define OUT_MAIN (M_TOK*DIM_)  // 9682944

#define K2_ 1536               // doubled-K for split-bf16 GEMMs

// scalar workspace layout (float offsets within SC)
#define W_OFF     0
#define HP_OFF    16
#define HPROW_OFF 128
#define NVB_OFF   144
#define SVB_OFF   720
#define STATS_OFF 784
#define W1_OFF    1024
#define W3_OFF    50176
#define PART_OFF  99328
#define SC_FLOATS 132096

typedef short bf16x8_ __attribute__((ext_vector_type(8)));
typedef float f32x4_  __attribute__((ext_vector_type(4)));

// ---------------- prep ----------------
__global__ void prep_kernel(const float* __restrict__ uniforms, const float* __restrict__ kth,
                            const float* __restrict__ head_probs, const float* __restrict__ v_b,
                            float* __restrict__ SC, float* __restrict__ out_tail)
{
    int t = threadIdx.x;
    if (t == 0) {
        float ind[3];
        for (int i = 0; i < 3; i++) {
            float s = 1.f/(1.f + expf(-kth[i]));
            float p = fminf(fmaxf(s, EPS_), 1.f - EPS_);
            float u = fminf(fmaxf(uniforms[i], EPS_), 1.f - EPS_);
            float logit = logf(u) - log1pf(-u) + logf(p) - log1pf(-p);
            ind[i] = (logit > 0.f) ? 1.f : 0.f;
        }
        SC[W_OFF+0] = ind[2];
        SC[W_OFF+1] = ind[1]*(1.f-ind[2]);
        SC[W_OFF+2] = ind[0]*(1.f-ind[1])*(1.f-ind[2]);
        float kprod = 1.f;
        for (int i = 0; i < 3; i++) {
            float ktv = 1.f/(1.f + expf(-kth[i]));
            kprod *= (ktv > 0.5f) ? 1.f : 0.f;
            out_tail[i]   = kprod;
            out_tail[3+i] = ktv;
        }
    }
    if (t < 9) {
        float mx = -1e30f;
        for (int h = 0; h < 12; h++) mx = fmaxf(mx, head_probs[h*9+t]);
        float e[12]; float s = 0.f;
        for (int h = 0; h < 12; h++) { e[h] = expf((head_probs[h*9+t]-mx)/ALPHA_); s += e[h]; }
        for (int h = 0; h < 12; h++) SC[HP_OFF + h*9 + t] = e[h]/s;
    }
    __syncthreads();
    if (t < 12) {
        float s = 0.f;
        for (int k = 0; k < 9; k++) s += SC[HP_OFF + t*9 + k];
        SC[HPROW_OFF + t] = s;
    }
    if (t < 64) {
        float sv = 0.f;
        for (int k = 0; k < 9; k++) {
            float s = 0.f;
            for (int h = 0; h < 12; h++) s += v_b[h*64+t]*SC[HP_OFF + h*9 + k];
            SC[NVB_OFF + t*9 + k] = s;
            sv += s;
        }
        SC[SVB_OFF + t] = sv;
    }
}

// ---------------- fp32 -> bf16 helpers ----------------
__device__ __forceinline__ unsigned short bfr_(float f) {
    unsigned u = __float_as_uint(f);
    return (unsigned short)((u + 0x7FFFu + ((u >> 16) & 1u)) >> 16);
}

__global__ __launch_bounds__(256) void conv_hilo(const float* __restrict__ in,
                                                 unsigned int* __restrict__ out, int n4)
{
    int i = blockIdx.x*256 + threadIdx.x;
    if (i >= n4) return;
    float4 v = ((const float4*)in)[i];
    float f[4] = {v.x, v.y, v.z, v.w};
    unsigned r[4];
    #pragma unroll
    for (int j = 0; j < 4; j++) {
        unsigned short h = bfr_(f[j]);
        float hf = __uint_as_float((unsigned)h << 16);
        unsigned short l = bfr_(f[j] - hf);
        r[j] = (unsigned)h | ((unsigned)l << 16);
    }
    ((uint4*)out)[i] = make_uint4(r[0], r[1], r[2], r[3]);
}

__global__ __launch_bounds__(256) void conv_dup(const float* __restrict__ in,
                                                unsigned int* __restrict__ out, int n4)
{
    int i = blockIdx.x*256 + threadIdx.x;
    if (i >= n4) return;
    float4 v = ((const float4*)in)[i];
    float f[4] = {v.x, v.y, v.z, v.w};
    unsigned r[4];
    #pragma unroll
    for (int j = 0; j < 4; j++) {
        unsigned short h = bfr_(f[j]);
        r[j] = (unsigned)h | ((unsigned)h << 16);
    }
    ((uint4*)out)[i] = make_uint4(r[0], r[1], r[2], r[3]);
}

// ---------------- merged qk+v GEMM (split-bf16 MFMA) ----------------
// A2[M][1536] bf16 hi/lo, W2[2304][1536] bf16 dup.
// cols 0..1535 -> qkbf bf16 (+qk_b); cols 1536..2303 -> vw fp32 + vbfT bf16 transposed.
__global__ __launch_bounds__(256) void gemm_qkv(
    const unsigned short* __restrict__ A2, const unsigned short* __restrict__ W2,
    const float* __restrict__ qk_b,
    unsigned short* __restrict__ qkbf, float* __restrict__ vw,
    unsigned short* __restrict__ vbfT)
{
    __shared__ unsigned short At[128][40];
    __shared__ unsigned short Bt[128][40];
    // bijective XCD swizzle (m204): nwg = 1782
    const int nwg = 1782;
    int q = nwg >> 3, rr = nwg & 7;
    int xcd = blockIdx.x & 7, idx = blockIdx.x >> 3;
    int s = (xcd < rr) ? xcd*(q+1) + idx : rr*(q+1) + (xcd - rr)*q + idx;
    const int n0 = (s % 18) * 128, m0 = (s / 18) * 128;
    const int tid = threadIdx.x;
    const int wave = tid >> 6, lane = tid & 63;
    const int wr = (wave >> 1)*64, wc = (wave & 1)*64;
    const int fr = lane & 15, fq = lane >> 4;
    const int sr = tid >> 2, ss = (tid & 3)*8;

    f32x4_ acc[4][4] = {};
    int ar0 = m0 + sr;      if (ar0 > M_TOK-1) ar0 = M_TOK-1;
    int ar1 = m0 + 64 + sr; if (ar1 > M_TOK-1) ar1 = M_TOK-1;
    const size_t arow0 = (size_t)ar0*K2_, arow1 = (size_t)ar1*K2_;
    const size_t brow0 = (size_t)(n0+sr)*K2_, brow1 = (size_t)(n0+64+sr)*K2_;

    uint4 ra0 = *(const uint4*)(A2 + arow0 + ss);
    uint4 ra1 = *(const uint4*)(A2 + arow1 + ss);
    uint4 rb0 = *(const uint4*)(W2 + brow0 + ss);
    uint4 rb1 = *(const uint4*)(W2 + brow1 + ss);
    for (int k0 = 0; k0 < K2_; k0 += 32) {
        __syncthreads();
        *(uint4*)&At[sr][ss]    = ra0;
        *(uint4*)&At[64+sr][ss] = ra1;
        *(uint4*)&Bt[sr][ss]    = rb0;
        *(uint4*)&Bt[64+sr][ss] = rb1;
        __syncthreads();
        if (k0 + 32 < K2_) {
            ra0 = *(const uint4*)(A2 + arow0 + k0 + 32 + ss);
            ra1 = *(const uint4*)(A2 + arow1 + k0 + 32 + ss);
            rb0 = *(const uint4*)(W2 + brow0 + k0 + 32 + ss);
            rb1 = *(const uint4*)(W2 + brow1 + k0 + 32 + ss);
        }
        bf16x8_ a[4], bb[4];
        #pragma unroll
        for (int i = 0; i < 4; i++) {
            a[i]  = *(const bf16x8_*)&At[wr + i*16 + fr][fq*8];
            bb[i] = *(const bf16x8_*)&Bt[wc + i*16 + fr][fq*8];
        }
        #pragma unroll
        for (int mi = 0; mi < 4; mi++)
            #pragma unroll
            for (int ni = 0; ni < 4; ni++)
                acc[mi][ni] = __builtin_amdgcn_mfma_f32_16x16x32_bf16(a[mi], bb[ni], acc[mi][ni], 0, 0, 0);
    }

    if (n0 < 1536) {
        float bv[4];
        #pragma unroll
        for (int ni = 0; ni < 4; ni++) bv[ni] = qk_b[n0 + wc + ni*16 + fr];
        #pragma unroll
        for (int mi = 0; mi < 4; mi++) {
            #pragma unroll
            for (int j = 0; j < 4; j++) {
                int row = m0 + wr + mi*16 + fq*4 + j;
                if (row < M_TOK) {
                    unsigned short* crow = qkbf + (size_t)row*1536 + n0 + wc;
                    #pragma unroll
                    for (int ni = 0; ni < 4; ni++)
                        crow[ni*16 + fr] = bfr_(acc[mi][ni][j] + bv[ni]);
                }
            }
        }
    } else {
        const int v0 = n0 - 1536;
        #pragma unroll
        for (int mi = 0; mi < 4; mi++) {
            #pragma unroll
            for (int j = 0; j < 4; j++) {
                int row = m0 + wr + mi*16 + fq*4 + j;
                if (row < M_TOK) {
                    int bq = row / N_;
                    int cc = row - bq*N_;
                    float* vrow = vw + (size_t)row*768 + v0 + wc;
                    #pragma unroll
                    for (int ni = 0; ni < 4; ni++) {
                        float val = acc[mi][ni][j];
                        int vcol = v0 + wc + ni*16 + fr;
                        vrow[ni*16 + fr] = val;
                        int hh = vcol >> 6, dd = vcol & 63;
                        vbfT[((size_t)(bq*NH_ + hh)*64 + dd)*224 + cc] = bfr_(val);
                    }
                }
            }
        }
    }
}

// ---------------- proj GEMM (split-bf16 MFMA, fp32 out + bias) ----------------
__global__ __launch_bounds__(256) void gemm_proj(
    const unsigned short* __restrict__ A2, const unsigned short* __restrict__ W2,
    const float* __restrict__ bias, float* __restrict__ C, int M, int Ncols, int NBX)
{
    __shared__ unsigned short At[128][40];
    __shared__ unsigned short Bt[128][40];
    const int nwg = gridDim.x;
    int q = nwg >> 3, rr = nwg & 7;
    int xcd = blockIdx.x & 7, idx = blockIdx.x >> 3;
    int s = (xcd < rr) ? xcd*(q+1) + idx : rr*(q+1) + (xcd - rr)*q + idx;
    const int n0 = (s % NBX) * 128, m0 = (s / NBX) * 128;
    const int tid = threadIdx.x;
    const int wave = tid >> 6, lane = tid & 63;
    const int wr = (wave >> 1)*64, wc = (wave & 1)*64;
    const int fr = lane & 15, fq = lane >> 4;
    const int sr = tid >> 2, ss = (tid & 3)*8;

    f32x4_ acc[4][4] = {};
    int ar0 = m0 + sr;      if (ar0 > M-1) ar0 = M-1;
    int ar1 = m0 + 64 + sr; if (ar1 > M-1) ar1 = M-1;
    const size_t arow0 = (size_t)ar0*K2_, arow1 = (size_t)ar1*K2_;
    const size_t brow0 = (size_t)(n0+sr)*K2_, brow1 = (size_t)(n0+64+sr)*K2_;

    uint4 ra0 = *(const uint4*)(A2 + arow0 + ss);
    uint4 ra1 = *(const uint4*)(A2 + arow1 + ss);
    uint4 rb0 = *(const uint4*)(W2 + brow0 + ss);
    uint4 rb1 = *(const uint4*)(W2 + brow1 + ss);
    for (int k0 = 0; k0 < K2_; k0 += 32) {
        __syncthreads();
        *(uint4*)&At[sr][ss]    = ra0;
        *(uint4*)&At[64+sr][ss] = ra1;
        *(uint4*)&Bt[sr][ss]    = rb0;
        *(uint4*)&Bt[64+sr][ss] = rb1;
        __syncthreads();
        if (k0 + 32 < K2_) {
            ra0 = *(const uint4*)(A2 + arow0 + k0 + 32 + ss);
            ra1 = *(const uint4*)(A2 + arow1 + k0 + 32 + ss);
            rb0 = *(const uint4*)(W2 + brow0 + k0 + 32 + ss);
            rb1 = *(const uint4*)(W2 + brow1 + k0 + 32 + ss);
        }
        bf16x8_ a[4], bb[4];
        #pragma unroll
        for (int i = 0; i < 4; i++) {
            a[i]  = *(const bf16x8_*)&At[wr + i*16 + fr][fq*8];
            bb[i] = *(const bf16x8_*)&Bt[wc + i*16 + fr][fq*8];
        }
        #pragma unroll
        for (int mi = 0; mi < 4; mi++)
            #pragma unroll
            for (int ni = 0; ni < 4; ni++)
                acc[mi][ni] = __builtin_amdgcn_mfma_f32_16x16x32_bf16(a[mi], bb[ni], acc[mi][ni], 0, 0, 0);
    }

    float bv[4];
    #pragma unroll
    for (int ni = 0; ni < 4; ni++) bv[ni] = bias[n0 + wc + ni*16 + fr];
    #pragma unroll
    for (int mi = 0; mi < 4; mi++) {
        #pragma unroll
        for (int j = 0; j < 4; j++) {
            int row = m0 + wr + mi*16 + fq*4 + j;
            if (row < M) {
                float* crow = C + (size_t)row * Ncols + n0 + wc;
                #pragma unroll
                for (int ni = 0; ni < 4; ni++)
                    crow[ni*16 + fr] = acc[mi][ni][j] + bv[ni];
            }
        }
    }
}

// ---------------- fused flash attention (bf16 MFMA) ----------------
// One block per (b,h). S^T = mfma(K,Q); O^T = mfma(V^T, P): softmax stats lane-local.
__global__ __launch_bounds__(256) void flash_attn(
    const unsigned short* __restrict__ qkbf,
    const unsigned short* __restrict__ vbfT,
    const float* __restrict__ v_b,
    unsigned int* __restrict__ msa2)
{
    __shared__ unsigned short Kb[224][64];   // K rows, XOR-swizzled 16B chunks
    __shared__ unsigned short Vt[64][256];   // V^T rows (c-padded), swizzled
    const int bh = blockIdx.x;
    const int b = bh / NH_, h = bh % NH_;
    const int tid = threadIdx.x;
    const int wv = tid >> 6, lane = tid & 63;
    const int fr = lane & 15, fq = lane >> 4;

    {   // K fill: rows c (zero for c>=197), chunk ^= (c&7)
        const unsigned short* Kg = qkbf + (size_t)(b*N_)*1536 + 768 + h*64;
        int r = tid >> 3; const int ch = tid & 7;
        #pragma unroll
        for (int rnd = 0; rnd < 7; rnd++, r += 32) {
            uint4 val = make_uint4(0u,0u,0u,0u);
            if (r < N_) val = *(const uint4*)(Kg + (size_t)r*1536 + ch*8);
            *(uint4*)&Kb[r][(ch ^ (r & 7))*8] = val;
        }
    }
    {   // V^T fill: rows d, 32 chunks (zero for c>=197), chunk ^= (d&7)
        const unsigned short* Vg = vbfT + (size_t)bh*(64*224);
        #pragma unroll
        for (int rnd = 0; rnd < 8; rnd++) {
            int job = rnd*256 + tid;
            int d = job >> 5, ch = job & 31;
            uint4 val = make_uint4(0u,0u,0u,0u);
            if (ch < 24) val = *(const uint4*)(Vg + (size_t)d*224 + ch*8);
            else if (ch == 24) {
                val = *(const uint4*)(Vg + (size_t)d*224 + 192);
                val.z &= 0xFFFFu; val.w = 0u;   // zero c=197..199
            }
            *(uint4*)&Vt[d][(ch ^ (d & 7))*8] = val;
        }
    }
    // Q fragments (global, clamped rows)
    bf16x8_ qf[4][2];
    #pragma unroll
    for (int nf = 0; nf < 4; nf++) {
        int qr = wv*64 + nf*16 + fr; if (qr > N_-1) qr = N_-1;
        const unsigned short* Qg = qkbf + (size_t)(b*N_ + qr)*1536 + h*64;
        qf[nf][0] = *(const bf16x8_*)(Qg + fq*8);
        qf[nf][1] = *(const bf16x8_*)(Qg + 32 + fq*8);
    }
    __syncthreads();

    f32x4_ o[4][4];   // o[df][nf]: lane holds O[q=16nf+fr][d=16df+fq*4+jj]
    #pragma unroll
    for (int i = 0; i < 4; i++)
        #pragma unroll
        for (int j2 = 0; j2 < 4; j2++) { o[i][j2][0]=0.f; o[i][j2][1]=0.f; o[i][j2][2]=0.f; o[i][j2][3]=0.f; }
    float m_[4] = {-1e30f,-1e30f,-1e30f,-1e30f};
    float l_[4] = {0.f,0.f,0.f,0.f};

    for (int t = 0; t < 14; t++) {
        const int krow = t*16 + fr;
        bf16x8_ kf0 = *(const bf16x8_*)&Kb[krow][( fq      ^ (fr & 7))*8];
        bf16x8_ kf1 = *(const bf16x8_*)&Kb[krow][((fq + 4) ^ (fr & 7))*8];
        f32x4_ st[4];
        #pragma unroll
        for (int nf = 0; nf < 4; nf++) {
            f32x4_ z = {0.f,0.f,0.f,0.f};
            z = __builtin_amdgcn_mfma_f32_16x16x32_bf16(kf0, qf[nf][0], z, 0,0,0);
            z = __builtin_amdgcn_mfma_f32_16x16x32_bf16(kf1, qf[nf][1], z, 0,0,0);
            st[nf] = z;
        }
        const int cbase = t*16 + fq*4;
        float p[4][4];
        #pragma unroll
        for (int nf = 0; nf < 4; nf++) {
            #pragma unroll
            for (int jj = 0; jj < 4; jj++)
                st[nf][jj] = (cbase + jj < N_) ? st[nf][jj]*SCALE_ : -1e30f;
            float tm = fmaxf(fmaxf(st[nf][0],st[nf][1]), fmaxf(st[nf][2],st[nf][3]));
            tm = fmaxf(tm, __shfl_xor(tm, 16));
            tm = fmaxf(tm, __shfl_xor(tm, 32));
            float mn = fmaxf(m_[nf], tm);
            float sc = __expf(m_[nf] - mn);
            float ps = 0.f;
            #pragma unroll
            for (int jj = 0; jj < 4; jj++) {
                float e = __expf(st[nf][jj] - mn);
                p[nf][jj] = e; ps += e;
            }
            ps += __shfl_xor(ps, 16);
            ps += __shfl_xor(ps, 32);
            l_[nf] = l_[nf]*sc + ps;
            m_[nf] = mn;
            #pragma unroll
            for (int df = 0; df < 4; df++) {
                o[df][nf][0]*=sc; o[df][nf][1]*=sc; o[df][nf][2]*=sc; o[df][nf][3]*=sc;
            }
        }
        // P as B-operand (k = fq*8+tt); only fq<2 supply nonzero (tile is 16 wide)
        bf16x8_ pa[4];
        const bool half = (fq < 2);
        #pragma unroll
        for (int nf = 0; nf < 4; nf++) {
            #pragma unroll
            for (int tt = 0; tt < 8; tt++) {
                int src = fr + 16*((fq & 1)*2 + (tt >> 2));
                float v = __shfl(p[nf][tt & 3], src);
                pa[nf][tt] = half ? (short)bfr_(v) : (short)0;
            }
        }
        #pragma unroll
        for (int df = 0; df < 4; df++) {
            bf16x8_ vf = *(const bf16x8_*)&Vt[df*16 + fr][((t*2 + fq) ^ (fr & 7))*8];
            #pragma unroll
            for (int nf = 0; nf < 4; nf++)
                o[df][nf] = __builtin_amdgcn_mfma_f32_16x16x32_bf16(vf, pa[nf], o[df][nf], 0,0,0);
        }
    }
    // epilogue: normalize, add v_b, split hi/lo bf16, store uint4
    #pragma unroll
    for (int nf = 0; nf < 4; nf++) {
        int qr = wv*64 + nf*16 + fr;
        if (qr >= N_) continue;
        float inv = 1.f / l_[nf];
        unsigned int* orow = msa2 + ((size_t)(b*N_ + qr)*768 + h*64);
        #pragma unroll
        for (int df = 0; df < 4; df++) {
            const float4 vb4 = *(const float4*)&v_b[h*64 + df*16 + fq*4];
            float vals[4] = { o[df][nf][0]*inv + vb4.x, o[df][nf][1]*inv + vb4.y,
                              o[df][nf][2]*inv + vb4.z, o[df][nf][3]*inv + vb4.w };
            uint4 w;
            unsigned wout[4];
            #pragma unroll
            for (int jj = 0; jj < 4; jj++) {
                unsigned short hi = bfr_(vals[jj]);
                float hf = __uint_as_float((unsigned)hi << 16);
                wout[jj] = (unsigned)hi | ((unsigned)bfr_(vals[jj] - hf) << 16);
            }
            w.x = wout[0]; w.y = wout[1]; w.z = wout[2]; w.w = wout[3];
            *(uint4*)(orow + df*16 + fq*4) = w;
        }
    }
}

// ---------------- fp32 GEMM (K=64 branch GEMMs) ----------------
#define GT 64
#define GK 16
template<bool BIAS>
__global__ __launch_bounds__(256) void gemm_xwt(
    const float* __restrict__ A, const float* __restrict__ W,
    const float* __restrict__ bias, float* __restrict__ C,
    int M, int Ncols, int K)
{
    __shared__ float As[GK][GT+4];
    __shared__ float Bs[GK][GT+4];
    const int tid = threadIdx.x;
    const int tx = tid & 15, ty = tid >> 4;
    const int m0 = blockIdx.y * GT, n0 = blockIdx.x * GT;
    float acc[4][4] = {};
    for (int k0 = 0; k0 < K; k0 += GK) {
        #pragma unroll
        for (int i = 0; i < 4; i++) {
            int r = ty + i*16;
            As[tx][r] = A[(size_t)(m0 + r)*K + (k0 + tx)];
            Bs[tx][r] = W[(size_t)(n0 + r)*K + (k0 + tx)];
        }
        __syncthreads();
        #pragma unroll
        for (int kk = 0; kk < GK; kk++) {
            const float4 a4 = *(const float4*)&As[kk][ty*4];
            const float4 b4 = *(const float4*)&Bs[kk][tx*4];
            const float a[4] = {a4.x, a4.y, a4.z, a4.w};
            const float b[4] = {b4.x, b4.y, b4.z, b4.w};
            #pragma unroll
            for (int i = 0; i < 4; i++)
                #pragma unroll
                for (int j = 0; j < 4; j++)
                    acc[i][j] += a[i]*b[j];
        }
        __syncthreads();
    }
    float4 bv = make_float4(0.f,0.f,0.f,0.f);
    if (BIAS) bv = *(const float4*)&bias[n0 + tx*4];
    #pragma unroll
    for (int i = 0; i < 4; i++) {
        int m = m0 + ty*4 + i;
        float4 o = make_float4(acc[i][0]+bv.x, acc[i][1]+bv.y, acc[i][2]+bv.z, acc[i][3]+bv.w);
        *(float4*)&C[(size_t)m*Ncols + n0 + tx*4] = o;
    }
}

// ---------------- new_v ----------------
__global__ __launch_bounds__(256) void newv_kernel(
    const float* __restrict__ vw, const float* __restrict__ SC, float* __restrict__ newv)
{
    int idx = blockIdx.x*256 + threadIdx.x;
    if (idx >= M_PATCH*64) return;
    int d = idx & 63; int bp = idx >> 6;
    int p = bp % NP_, b = bp / NP_;
    const float* src = vw + (size_t)(b*N_ + 1 + p)*768 + d;
    float vh[12];
    #pragma unroll
    for (int h = 0; h < 12; h++) vh[h] = src[h*64];
    #pragma unroll
    for (int k = 0; k < 9; k++) {
        float s = 0.f;
        #pragma unroll
        for (int h = 0; h < 12; h++) s += vh[h]*SC[HP_OFF + h*9 + k];
        newv[((size_t)bp*9 + k)*64 + d] = s;
    }
}

__global__ __launch_bounds__(256) void c1pre_kernel(
    const float* __restrict__ newv, const float* __restrict__ SC, float* __restrict__ dst)
{
    int i = blockIdx.x*256 + threadIdx.x;
    if (i >= M_PATCH*64) return;
    int d = i & 63; int bp = i >> 6;
    dst[i] = newv[((size_t)bp*9 + 4)*64 + d] + SC[NVB_OFF + d*9 + 4];
}

__global__ __launch_bounds__(256) void c3pre_kernel(
    const float* __restrict__ newv, const float* __restrict__ SC, float* __restrict__ dst)
{
    int i = blockIdx.x*256 + threadIdx.x;
    if (i >= M_PATCH*64) return;
    int d = i & 63; int bij = i >> 6;
    int j = bij % 14; int bi = bij / 14; int irow = bi % 14; int b = bi / 14;
    float acc = SC[SVB_OFF + d];
    #pragma unroll
    for (int p = 0; p < 9; p++) {
        int h1 = p % 3, h2 = p / 3;
        int y = irow + h1 - 1, x = j + h2 - 1;
        if (y >= 0 && y < 14 && x >= 0 && x < 14)
            acc += newv[(((size_t)b*NP_ + y*14 + x)*9 + p)*64 + d];
    }
    dst[i] = acc;
}

// ---------------- BN ----------------
__global__ __launch_bounds__(256) void bnstat_kernel(
    const float* __restrict__ src, int nelem, float* __restrict__ partial)
{
    __shared__ float sd[256], sq[256];
    int tid = threadIdx.x;
    float s = 0.f, q = 0.f;
    int stride = gridDim.x * 256;
    for (int i = blockIdx.x*256 + tid; i < nelem; i += stride) {
        float v = src[i]; s += v; q += v*v;
    }
    sd[tid] = s; sq[tid] = q;
    __syncthreads();
    if (tid < 64) {
        float ts = sd[tid]+sd[tid+64]+sd[tid+128]+sd[tid+192];
        float tq = sq[tid]+sq[tid+64]+sq[tid+128]+sq[tid+192];
        partial[blockIdx.x*128 + tid]      = ts;
        partial[blockIdx.x*128 + 64 + tid] = tq;
    }
}

__global__ void bnreduce_kernel(const float* __restrict__ partial, int nblk, float* __restrict__ stats)
{
    int t = threadIdx.x;  // 128
    float s = 0.f;
    for (int i = 0; i < nblk; i++) s += partial[i*128 + t];
    stats[t] = s;
}

__global__ __launch_bounds__(256) void bnapply_kernel(
    float* __restrict__ buf, int nelem, const float* __restrict__ stats,
    const float* __restrict__ g, const float* __restrict__ bb, float invN)
{
    int i = blockIdx.x*256 + threadIdx.x;
    if (i >= nelem) return;
    int d = i & 63;
    float mean = stats[d]*invN;
    float var  = stats[64+d]*invN - mean*mean;
    float sc = rsqrtf(var + BN_EPS_) * g[d];
    float v = (buf[i] - mean)*sc + bb[d];
    buf[i] = fmaxf(v, 0.f);
}

// ---------------- W1/W3 ----------------
__global__ __launch_bounds__(256) void w13_kernel(
    const float* __restrict__ proj_w, const float* __restrict__ SC,
    float* __restrict__ W1, float* __restrict__ W3)
{
    int idx = blockIdx.x*256 + threadIdx.x;
    if (idx >= 768*64) return;
    int d = idx & 63, c = idx >> 6;
    float s1 = 0.f, s3 = 0.f;
    #pragma unroll
    for (int h = 0; h < 12; h++) {
        float pw = proj_w[(size_t)c*768 + h*64 + d];
        s1 += pw * SC[HP_OFF + h*9 + 4];
        s3 += pw * SC[HPROW_OFF + h];
    }
    W1[idx] = s1; W3[idx] = s3;
}

// ---------------- final blend (pbuf aliases out; per-thread read-then-write) ----------------
__global__ __launch_bounds__(256) void blend_kernel(
    const float* __restrict__ x, const float* pbuf,
    const float* __restrict__ c1o, const float* __restrict__ c3o,
    const float* __restrict__ SC, float* out)
{
    int i = blockIdx.x*256 + threadIdx.x;
    if (i >= OUT_MAIN) return;
    int cc = i % 768; int bn = i / 768; int n = bn % 197;
    float w0 = SC[0], w1 = SC[1], w2 = SC[2];
    float m = pbuf[i];
    float c1v, c3v;
    if (n == 0) { c1v = x[i]; c3v = x[i]; }
    else {
        size_t q = ((size_t)(bn - (bn/197) - 1))*768 + cc;
        c1v = c1o[q]; c3v = c3o[q];
    }
    out[i] = w0*m + w1*c3v + w2*c1v;
}

// ---------------- launch ----------------
extern "C" void kernel_launch(void* const* d_in, const int* in_sizes, int n_in,
                              void* d_out, int out_size, void* d_ws, size_t ws_size,
                              hipStream_t stream)
{
    const float* x        = (const float*)d_in[0];
    const float* uniforms = (const float*)d_in[1];
    const float* qk_w     = (const float*)d_in[2];
    const float* qk_b     = (const float*)d_in[3];
    const float* v_w      = (const float*)d_in[4];
    const float* v_b      = (const float*)d_in[5];
    const float* proj_w   = (const float*)d_in[6];
    const float* proj_b   = (const float*)d_in[7];
    const float* bn1_g    = (const float*)d_in[8];
    const float* bn1_b    = (const float*)d_in[9];
    const float* bn3_g    = (const float*)d_in[10];
    const float* bn3_b    = (const float*)d_in[11];
    const float* kth      = (const float*)d_in[12];
    const float* head_probs = (const float*)d_in[13];
    float* out = (float*)d_out;

    // ws regions (float offsets); every alias written-in-full before read each call
    float* ws = (float*)d_ws;
    float* R1 = ws;                     // 19,365,888 floats
    float* vw = ws + 19365888;          //  9,682,944 floats (fp32 v_weight)
    float* R3 = ws + 29048832;          //  9,682,944 floats
    float* SC = ws + 38731776;          //    132,096 floats
    // R1 phases: qkbf+vbfT (gemm_qkv -> flash) ; then pjw2 / newv / c1out / c3out
    unsigned short* qkbf = (unsigned short*)R1;                     // 19,365,888 ushorts
    unsigned short* vbfT = (unsigned short*)R1 + 19365888;          // 11,010,048 ushorts
    unsigned int*   pjw2 = (unsigned int*)(ws + 15187968);          // proj_w dup (after vbfT)
    float* newv  = R1;                  // 7,225,344 floats (after proj consumed nothing here)
    float* c1out = R1;                  // 9,633,792 floats (after newv last read)
    float* c3out = R1 + 9633792;        // 9,633,792 floats
    float* c1buf = vw;                  // alias vw after its last read
    float* c3buf = vw + 802816;
    // R3 phases: x2 (conv -> gemm_qkv) ; then msa2 (flash -> proj)
    unsigned int* x2   = (unsigned int*)R3;
    unsigned int* msa2 = (unsigned int*)R3;
    // d_out phases: W2 (conv -> gemm_qkv) ; then pbuf (proj -> blend) ; final out
    unsigned int* W2a = (unsigned int*)out;                 // qk_w dup: 1,179,648 uints
    unsigned int* W2b = (unsigned int*)out + 1179648;       // v_w dup:    589,824 uints
    float* pbuf = out;
    float* W1    = SC + W1_OFF;
    float* W3    = SC + W3_OFF;
    float* stats = SC + STATS_OFF;
    float* part  = SC + PART_OFF;

    prep_kernel<<<1, 256, 0, stream>>>(uniforms, kth, head_probs, v_b, SC, out + OUT_MAIN);

    // conversions
    conv_hilo<<<9456, 256, 0, stream>>>(x, x2, 2420736);
    conv_dup<<<1152, 256, 0, stream>>>(qk_w, W2a, 294912);
    conv_dup<<<576, 256, 0, stream>>>(v_w, W2b, 147456);

    // merged qk+v GEMM -> qkbf (bf16), vw (fp32), vbfT (bf16 transposed)
    gemm_qkv<<<1782, 256, 0, stream>>>(x2 ? (const unsigned short*)x2 : nullptr,
                                       (const unsigned short*)W2a, qk_b,
                                       qkbf, vw, (unsigned short*)vbfT);

    // fused attention -> msa2 (split-bf16, overwrites x2 region)
    flash_attn<<<768, 256, 0, stream>>>(qkbf, (const unsigned short*)vbfT, v_b, msa2);

    // proj: msa2 @ proj_w^T + proj_b -> pbuf (d_out)
    conv_dup<<<576, 256, 0, stream>>>(proj_w, pjw2, 147456);
    gemm_proj<<<594, 256, 0, stream>>>((const unsigned short*)msa2, (const unsigned short*)pjw2,
                                       proj_b, pbuf, M_TOK, 768, 6);

    // conv branches (fp32, unchanged)
    newv_kernel<<<3136, 256, 0, stream>>>(vw, SC, newv);

    c1pre_kernel<<<3136, 256, 0, stream>>>(newv, SC, c1buf);
    bnstat_kernel<<<256, 256, 0, stream>>>(c1buf, M_PATCH*64, part);
    bnreduce_kernel<<<1, 128, 0, stream>>>(part, 256, stats);
    bnapply_kernel<<<3136, 256, 0, stream>>>(c1buf, M_PATCH*64, stats, bn1_g, bn1_b, 1.0f/12544.0f);

    c3pre_kernel<<<3136, 256, 0, stream>>>(newv, SC, c3buf);
    bnstat_kernel<<<256, 256, 0, stream>>>(c3buf, M_PATCH*64, part);
    bnreduce_kernel<<<1, 128, 0, stream>>>(part, 256, stats);
    bnapply_kernel<<<3136, 256, 0, stream>>>(c3buf, M_PATCH*64, stats, bn3_g, bn3_b, 1.0f/12544.0f);

    w13_kernel<<<192, 256, 0, stream>>>(proj_w, SC, W1, W3);

    gemm_xwt<true><<<dim3(12,196), 256, 0, stream>>>(c1buf, W1, proj_b, c1out, M_PATCH, 768, 64);
    gemm_xwt<true><<<dim3(12,196), 256, 0, stream>>>(c3buf, W3, proj_b, c3out, M_PATCH, 768, 64);

    blend_kernel<<<37824, 256, 0, stream>>>(x, pbuf, c1out, c3out, SC, out);
}

// Round 8
// 560.443 us; speedup vs baseline: 7.1293x; 1.0294x over previous
//
#include <hip/hip_runtime.h>
#include <cstdint>
#include <cstddef>

// ---------------- problem constants ----------------
#define B_    64
#define N_    197
#define DIM_  768
#define NH_   12
#define HD_   64
#define NP_   196
#define SCALE_ 0.125f
#define EPS_   1.1920929e-07f
#define BN_EPS_ 1e-5f
#define ALPHA_ 0.01f

#define M_TOK   (B_*N_)        // 12608
#define M_PATCH (B_*NP_)       // 12544
#define OUT_MAIN (M_TOK*DIM_)  // 9682944

#define K2_ 1536               // doubled-K for split-bf16 GEMMs

// scalar workspace layout (float offsets within SC)
#define W_OFF     0
#define HP_OFF    16
#define HPROW_OFF 128
#define NVB_OFF   144
#define SVB_OFF   720
#define STATS_OFF 784
#define W1_OFF    1024
#define W3_OFF    50176
#define PART_OFF  99328
#define SC_FLOATS 132096

typedef short bf16x8_ __attribute__((ext_vector_type(8)));
typedef float f32x4_  __attribute__((ext_vector_type(4)));

// ---------------- prep ----------------
__global__ void prep_kernel(const float* __restrict__ uniforms, const float* __restrict__ kth,
                            const float* __restrict__ head_probs, const float* __restrict__ v_b,
                            float* __restrict__ SC, float* __restrict__ out_tail)
{
    int t = threadIdx.x;
    if (t == 0) {
        float ind[3];
        for (int i = 0; i < 3; i++) {
            float s = 1.f/(1.f + expf(-kth[i]));
            float p = fminf(fmaxf(s, EPS_), 1.f - EPS_);
            float u = fminf(fmaxf(uniforms[i], EPS_), 1.f - EPS_);
            float logit = logf(u) - log1pf(-u) + logf(p) - log1pf(-p);
            ind[i] = (logit > 0.f) ? 1.f : 0.f;
        }
        SC[W_OFF+0] = ind[2];
        SC[W_OFF+1] = ind[1]*(1.f-ind[2]);
        SC[W_OFF+2] = ind[0]*(1.f-ind[1])*(1.f-ind[2]);
        float kprod = 1.f;
        for (int i = 0; i < 3; i++) {
            float ktv = 1.f/(1.f + expf(-kth[i]));
            kprod *= (ktv > 0.5f) ? 1.f : 0.f;
            out_tail[i]   = kprod;
            out_tail[3+i] = ktv;
        }
    }
    if (t < 9) {
        float mx = -1e30f;
        for (int h = 0; h < 12; h++) mx = fmaxf(mx, head_probs[h*9+t]);
        float e[12]; float s = 0.f;
        for (int h = 0; h < 12; h++) { e[h] = expf((head_probs[h*9+t]-mx)/ALPHA_); s += e[h]; }
        for (int h = 0; h < 12; h++) SC[HP_OFF + h*9 + t] = e[h]/s;
    }
    __syncthreads();
    if (t < 12) {
        float s = 0.f;
        for (int k = 0; k < 9; k++) s += SC[HP_OFF + t*9 + k];
        SC[HPROW_OFF + t] = s;
    }
    if (t < 64) {
        float sv = 0.f;
        for (int k = 0; k < 9; k++) {
            float s = 0.f;
            for (int h = 0; h < 12; h++) s += v_b[h*64+t]*SC[HP_OFF + h*9 + k];
            SC[NVB_OFF + t*9 + k] = s;
            sv += s;
        }
        SC[SVB_OFF + t] = sv;
    }
}

// ---------------- fp32 -> bf16 helpers ----------------
__device__ __forceinline__ unsigned short bfr_(float f) {
    unsigned u = __float_as_uint(f);
    return (unsigned short)((u + 0x7FFFu + ((u >> 16) & 1u)) >> 16);
}

__global__ __launch_bounds__(256) void conv_hilo(const float* __restrict__ in,
                                                 unsigned int* __restrict__ out, int n4)
{
    int i = blockIdx.x*256 + threadIdx.x;
    if (i >= n4) return;
    float4 v = ((const float4*)in)[i];
    float f[4] = {v.x, v.y, v.z, v.w};
    unsigned r[4];
    #pragma unroll
    for (int j = 0; j < 4; j++) {
        unsigned short h = bfr_(f[j]);
        float hf = __uint_as_float((unsigned)h << 16);
        unsigned short l = bfr_(f[j] - hf);
        r[j] = (unsigned)h | ((unsigned)l << 16);
    }
    ((uint4*)out)[i] = make_uint4(r[0], r[1], r[2], r[3]);
}

__global__ __launch_bounds__(256) void conv_dup(const float* __restrict__ in,
                                                unsigned int* __restrict__ out, int n4)
{
    int i = blockIdx.x*256 + threadIdx.x;
    if (i >= n4) return;
    float4 v = ((const float4*)in)[i];
    float f[4] = {v.x, v.y, v.z, v.w};
    unsigned r[4];
    #pragma unroll
    for (int j = 0; j < 4; j++) {
        unsigned short h = bfr_(f[j]);
        r[j] = (unsigned)h | ((unsigned)h << 16);
    }
    ((uint4*)out)[i] = make_uint4(r[0], r[1], r[2], r[3]);
}

// ---- global_load_lds staging helper macro-ish (linear LDS [128][32] ushorts) ----
// LDS slot (row r, chunk c=lane&3) receives global k-chunk (c ^ (r&3)); read side XORs back.
#define STAGE_TILE(LDSBUF, GBASE, ROWCLAMP)                                              \
    {                                                                                    \
        _Pragma("unroll")                                                                \
        for (int i_ = 0; i_ < 2; i_++) {                                                 \
            int r_ = wave*32 + i_*16 + (lane >> 2);                                      \
            int gr_ = ROWCLAMP(r_);                                                      \
            const unsigned short* gp_ = (GBASE) + (size_t)gr_*K2_ + k0                   \
                                        + (((lane & 3) ^ (r_ & 3)) * 8);                 \
            __builtin_amdgcn_global_load_lds(                                            \
                (const __attribute__((address_space(1))) unsigned int*)gp_,              \
                (__attribute__((address_space(3))) unsigned int*)&LDSBUF[(wave*32 + i_*16)*32], \
                16, 0, 0);                                                               \
        }                                                                                \
    }

// ---------------- merged qk+v GEMM (split-bf16 MFMA, global_load_lds staging) ----------------
__global__ __launch_bounds__(256) void gemm_qkv(
    const unsigned short* __restrict__ A2, const unsigned short* __restrict__ W2,
    const float* __restrict__ qk_b,
    unsigned short* __restrict__ qkbf, float* __restrict__ vw,
    unsigned short* __restrict__ vbfT)
{
    __shared__ unsigned short At[128*32];   // 8 KB, linear 64B rows
    __shared__ unsigned short Bt[128*32];
    const int nwg = 1782;
    int q = nwg >> 3, rr = nwg & 7;
    int xcd = blockIdx.x & 7, idx = blockIdx.x >> 3;
    int s = (xcd < rr) ? xcd*(q+1) + idx : rr*(q+1) + (xcd - rr)*q + idx;
    const int n0 = (s % 18) * 128, m0 = (s / 18) * 128;
    const int tid = threadIdx.x;
    const int wave = tid >> 6, lane = tid & 63;
    const int wr = (wave >> 1)*64, wc = (wave & 1)*64;
    const int fr = lane & 15, fq = lane >> 4;
    const int xk = (fq ^ (fr & 3)) * 8;

    f32x4_ acc[4][4] = {};

    #define CLA_(r) ((m0 + (r) < M_TOK) ? (m0 + (r)) : (M_TOK-1))
    #define CLB_(r) (n0 + (r))
    for (int k0 = 0; k0 < K2_; k0 += 32) {
        STAGE_TILE(At, A2, CLA_)
        STAGE_TILE(Bt, W2, CLB_)
        __syncthreads();
        bf16x8_ a[4], bb[4];
        #pragma unroll
        for (int i = 0; i < 4; i++) {
            a[i]  = *(const bf16x8_*)&At[(wr + i*16 + fr)*32 + xk];
            bb[i] = *(const bf16x8_*)&Bt[(wc + i*16 + fr)*32 + xk];
        }
        #pragma unroll
        for (int mi = 0; mi < 4; mi++)
            #pragma unroll
            for (int ni = 0; ni < 4; ni++)
                acc[mi][ni] = __builtin_amdgcn_mfma_f32_16x16x32_bf16(a[mi], bb[ni], acc[mi][ni], 0, 0, 0);
        __syncthreads();
    }
    #undef CLA_
    #undef CLB_

    if (n0 < 1536) {
        float bv[4];
        #pragma unroll
        for (int ni = 0; ni < 4; ni++) bv[ni] = qk_b[n0 + wc + ni*16 + fr];
        #pragma unroll
        for (int mi = 0; mi < 4; mi++) {
            #pragma unroll
            for (int j = 0; j < 4; j++) {
                int row = m0 + wr + mi*16 + fq*4 + j;
                if (row < M_TOK) {
                    unsigned short* crow = qkbf + (size_t)row*1536 + n0 + wc;
                    #pragma unroll
                    for (int ni = 0; ni < 4; ni++)
                        crow[ni*16 + fr] = bfr_(acc[mi][ni][j] + bv[ni]);
                }
            }
        }
    } else {
        const int v0 = n0 - 1536;
        #pragma unroll
        for (int mi = 0; mi < 4; mi++) {
            #pragma unroll
            for (int j = 0; j < 4; j++) {
                int row = m0 + wr + mi*16 + fq*4 + j;
                if (row < M_TOK) {
                    int bq = row / N_;
                    int cc = row - bq*N_;
                    float* vrow = vw + (size_t)row*768 + v0 + wc;
                    #pragma unroll
                    for (int ni = 0; ni < 4; ni++) {
                        float val = acc[mi][ni][j];
                        int vcol = v0 + wc + ni*16 + fr;
                        vrow[ni*16 + fr] = val;
                        int hh = vcol >> 6, dd = vcol & 63;
                        vbfT[((size_t)(bq*NH_ + hh)*64 + dd)*224 + cc] = bfr_(val);
                    }
                }
            }
        }
    }
}

// ---------------- proj GEMM (split-bf16 MFMA, global_load_lds staging) ----------------
__global__ __launch_bounds__(256) void gemm_proj(
    const unsigned short* __restrict__ A2, const unsigned short* __restrict__ W2,
    const float* __restrict__ bias, float* __restrict__ C, int M, int Ncols, int NBX)
{
    __shared__ unsigned short At[128*32];
    __shared__ unsigned short Bt[128*32];
    const int nwg = gridDim.x;
    int q = nwg >> 3, rr = nwg & 7;
    int xcd = blockIdx.x & 7, idx = blockIdx.x >> 3;
    int s = (xcd < rr) ? xcd*(q+1) + idx : rr*(q+1) + (xcd - rr)*q + idx;
    const int n0 = (s % NBX) * 128, m0 = (s / NBX) * 128;
    const int tid = threadIdx.x;
    const int wave = tid >> 6, lane = tid & 63;
    const int wr = (wave >> 1)*64, wc = (wave & 1)*64;
    const int fr = lane & 15, fq = lane >> 4;
    const int xk = (fq ^ (fr & 3)) * 8;

    f32x4_ acc[4][4] = {};

    #define CLA_(r) ((m0 + (r) < M) ? (m0 + (r)) : (M-1))
    #define CLB_(r) (n0 + (r))
    for (int k0 = 0; k0 < K2_; k0 += 32) {
        STAGE_TILE(At, A2, CLA_)
        STAGE_TILE(Bt, W2, CLB_)
        __syncthreads();
        bf16x8_ a[4], bb[4];
        #pragma unroll
        for (int i = 0; i < 4; i++) {
            a[i]  = *(const bf16x8_*)&At[(wr + i*16 + fr)*32 + xk];
            bb[i] = *(const bf16x8_*)&Bt[(wc + i*16 + fr)*32 + xk];
        }
        #pragma unroll
        for (int mi = 0; mi < 4; mi++)
            #pragma unroll
            for (int ni = 0; ni < 4; ni++)
                acc[mi][ni] = __builtin_amdgcn_mfma_f32_16x16x32_bf16(a[mi], bb[ni], acc[mi][ni], 0, 0, 0);
        __syncthreads();
    }
    #undef CLA_
    #undef CLB_

    float bv[4];
    #pragma unroll
    for (int ni = 0; ni < 4; ni++) bv[ni] = bias[n0 + wc + ni*16 + fr];
    #pragma unroll
    for (int mi = 0; mi < 4; mi++) {
        #pragma unroll
        for (int j = 0; j < 4; j++) {
            int row = m0 + wr + mi*16 + fq*4 + j;
            if (row < M) {
                float* crow = C + (size_t)row * Ncols + n0 + wc;
                #pragma unroll
                for (int ni = 0; ni < 4; ni++)
                    crow[ni*16 + fr] = acc[mi][ni][j] + bv[ni];
            }
        }
    }
}

// ---------------- fused flash attention (bf16 MFMA) ----------------
__global__ __launch_bounds__(256) void flash_attn(
    const unsigned short* __restrict__ qkbf,
    const unsigned short* __restrict__ vbfT,
    const float* __restrict__ v_b,
    unsigned int* __restrict__ msa2)
{
    __shared__ unsigned short Kb[224][64];
    __shared__ unsigned short Vt[64][256];
    const int bh = blockIdx.x;
    const int b = bh / NH_, h = bh % NH_;
    const int tid = threadIdx.x;
    const int wv = tid >> 6, lane = tid & 63;
    const int fr = lane & 15, fq = lane >> 4;

    {
        const unsigned short* Kg = qkbf + (size_t)(b*N_)*1536 + 768 + h*64;
        int r = tid >> 3; const int ch = tid & 7;
        #pragma unroll
        for (int rnd = 0; rnd < 7; rnd++, r += 32) {
            uint4 val = make_uint4(0u,0u,0u,0u);
            if (r < N_) val = *(const uint4*)(Kg + (size_t)r*1536 + ch*8);
            *(uint4*)&Kb[r][(ch ^ (r & 7))*8] = val;
        }
    }
    {
        const unsigned short* Vg = vbfT + (size_t)bh*(64*224);
        #pragma unroll
        for (int rnd = 0; rnd < 8; rnd++) {
            int job = rnd*256 + tid;
            int d = job >> 5, ch = job & 31;
            uint4 val = make_uint4(0u,0u,0u,0u);
            if (ch < 24) val = *(const uint4*)(Vg + (size_t)d*224 + ch*8);
            else if (ch == 24) {
                val = *(const uint4*)(Vg + (size_t)d*224 + 192);
                val.z &= 0xFFFFu; val.w = 0u;
            }
            *(uint4*)&Vt[d][(ch ^ (d & 7))*8] = val;
        }
    }
    bf16x8_ qf[4][2];
    #pragma unroll
    for (int nf = 0; nf < 4; nf++) {
        int qr = wv*64 + nf*16 + fr; if (qr > N_-1) qr = N_-1;
        const unsigned short* Qg = qkbf + (size_t)(b*N_ + qr)*1536 + h*64;
        qf[nf][0] = *(const bf16x8_*)(Qg + fq*8);
        qf[nf][1] = *(const bf16x8_*)(Qg + 32 + fq*8);
    }
    __syncthreads();

    f32x4_ o[4][4];
    #pragma unroll
    for (int i = 0; i < 4; i++)
        #pragma unroll
        for (int j2 = 0; j2 < 4; j2++) { o[i][j2][0]=0.f; o[i][j2][1]=0.f; o[i][j2][2]=0.f; o[i][j2][3]=0.f; }
    float m_[4] = {-1e30f,-1e30f,-1e30f,-1e30f};
    float l_[4] = {0.f,0.f,0.f,0.f};

    for (int t = 0; t < 14; t++) {
        const int krow = t*16 + fr;
        bf16x8_ kf0 = *(const bf16x8_*)&Kb[krow][( fq      ^ (fr & 7))*8];
        bf16x8_ kf1 = *(const bf16x8_*)&Kb[krow][((fq + 4) ^ (fr & 7))*8];
        f32x4_ st[4];
        #pragma unroll
        for (int nf = 0; nf < 4; nf++) {
            f32x4_ z = {0.f,0.f,0.f,0.f};
            z = __builtin_amdgcn_mfma_f32_16x16x32_bf16(kf0, qf[nf][0], z, 0,0,0);
            z = __builtin_amdgcn_mfma_f32_16x16x32_bf16(kf1, qf[nf][1], z, 0,0,0);
            st[nf] = z;
        }
        const int cbase = t*16 + fq*4;
        float p[4][4];
        #pragma unroll
        for (int nf = 0; nf < 4; nf++) {
            #pragma unroll
            for (int jj = 0; jj < 4; jj++)
                st[nf][jj] = (cbase + jj < N_) ? st[nf][jj]*SCALE_ : -1e30f;
            float tm = fmaxf(fmaxf(st[nf][0],st[nf][1]), fmaxf(st[nf][2],st[nf][3]));
            tm = fmaxf(tm, __shfl_xor(tm, 16));
            tm = fmaxf(tm, __shfl_xor(tm, 32));
            float mn = fmaxf(m_[nf], tm);
            float sc = __expf(m_[nf] - mn);
            float ps = 0.f;
            #pragma unroll
            for (int jj = 0; jj < 4; jj++) {
                float e = __expf(st[nf][jj] - mn);
                p[nf][jj] = e; ps += e;
            }
            ps += __shfl_xor(ps, 16);
            ps += __shfl_xor(ps, 32);
            l_[nf] = l_[nf]*sc + ps;
            m_[nf] = mn;
            #pragma unroll
            for (int df = 0; df < 4; df++) {
                o[df][nf][0]*=sc; o[df][nf][1]*=sc; o[df][nf][2]*=sc; o[df][nf][3]*=sc;
            }
        }
        bf16x8_ pa[4];
        const bool half = (fq < 2);
        #pragma unroll
        for (int nf = 0; nf < 4; nf++) {
            #pragma unroll
            for (int tt = 0; tt < 8; tt++) {
                int src = fr + 16*((fq & 1)*2 + (tt >> 2));
                float v = __shfl(p[nf][tt & 3], src);
                pa[nf][tt] = half ? (short)bfr_(v) : (short)0;
            }
        }
        #pragma unroll
        for (int df = 0; df < 4; df++) {
            bf16x8_ vf = *(const bf16x8_*)&Vt[df*16 + fr][((t*2 + fq) ^ (fr & 7))*8];
            #pragma unroll
            for (int nf = 0; nf < 4; nf++)
                o[df][nf] = __builtin_amdgcn_mfma_f32_16x16x32_bf16(vf, pa[nf], o[df][nf], 0,0,0);
        }
    }
    #pragma unroll
    for (int nf = 0; nf < 4; nf++) {
        int qr = wv*64 + nf*16 + fr;
        if (qr >= N_) continue;
        float inv = 1.f / l_[nf];
        unsigned int* orow = msa2 + ((size_t)(b*N_ + qr)*768 + h*64);
        #pragma unroll
        for (int df = 0; df < 4; df++) {
            const float4 vb4 = *(const float4*)&v_b[h*64 + df*16 + fq*4];
            float vals[4] = { o[df][nf][0]*inv + vb4.x, o[df][nf][1]*inv + vb4.y,
                              o[df][nf][2]*inv + vb4.z, o[df][nf][3]*inv + vb4.w };
            uint4 w;
            unsigned wout[4];
            #pragma unroll
            for (int jj = 0; jj < 4; jj++) {
                unsigned short hi = bfr_(vals[jj]);
                float hf = __uint_as_float((unsigned)hi << 16);
                wout[jj] = (unsigned)hi | ((unsigned)bfr_(vals[jj] - hf) << 16);
            }
            w.x = wout[0]; w.y = wout[1]; w.z = wout[2]; w.w = wout[3];
            *(uint4*)(orow + df*16 + fq*4) = w;
        }
    }
}

// ---------------- fp32 GEMM (K=64 branch GEMMs) ----------------
#define GT 64
#define GK 16
template<bool BIAS>
__global__ __launch_bounds__(256) void gemm_xwt(
    const float* __restrict__ A, const float* __restrict__ W,
    const float* __restrict__ bias, float* __restrict__ C,
    int M, int Ncols, int K)
{
    __shared__ float As[GK][GT+4];
    __shared__ float Bs[GK][GT+4];
    const int tid = threadIdx.x;
    const int tx = tid & 15, ty = tid >> 4;
    const int m0 = blockIdx.y * GT, n0 = blockIdx.x * GT;
    float acc[4][4] = {};
    for (int k0 = 0; k0 < K; k0 += GK) {
        #pragma unroll
        for (int i = 0; i < 4; i++) {
            int r = ty + i*16;
            As[tx][r] = A[(size_t)(m0 + r)*K + (k0 + tx)];
            Bs[tx][r] = W[(size_t)(n0 + r)*K + (k0 + tx)];
        }
        __syncthreads();
        #pragma unroll
        for (int kk = 0; kk < GK; kk++) {
            const float4 a4 = *(const float4*)&As[kk][ty*4];
            const float4 b4 = *(const float4*)&Bs[kk][tx*4];
            const float a[4] = {a4.x, a4.y, a4.z, a4.w};
            const float b[4] = {b4.x, b4.y, b4.z, b4.w};
            #pragma unroll
            for (int i = 0; i < 4; i++)
                #pragma unroll
                for (int j = 0; j < 4; j++)
                    acc[i][j] += a[i]*b[j];
        }
        __syncthreads();
    }
    float4 bv = make_float4(0.f,0.f,0.f,0.f);
    if (BIAS) bv = *(const float4*)&bias[n0 + tx*4];
    #pragma unroll
    for (int i = 0; i < 4; i++) {
        int m = m0 + ty*4 + i;
        float4 o = make_float4(acc[i][0]+bv.x, acc[i][1]+bv.y, acc[i][2]+bv.z, acc[i][3]+bv.w);
        *(float4*)&C[(size_t)m*Ncols + n0 + tx*4] = o;
    }
}

// ---------------- new_v ----------------
__global__ __launch_bounds__(256) void newv_kernel(
    const float* __restrict__ vw, const float* __restrict__ SC, float* __restrict__ newv)
{
    int idx = blockIdx.x*256 + threadIdx.x;
    if (idx >= M_PATCH*64) return;
    int d = idx & 63; int bp = idx >> 6;
    int p = bp % NP_, b = bp / NP_;
    const float* src = vw + (size_t)(b*N_ + 1 + p)*768 + d;
    float vh[12];
    #pragma unroll
    for (int h = 0; h < 12; h++) vh[h] = src[h*64];
    #pragma unroll
    for (int k = 0; k < 9; k++) {
        float s = 0.f;
        #pragma unroll
        for (int h = 0; h < 12; h++) s += vh[h]*SC[HP_OFF + h*9 + k];
        newv[((size_t)bp*9 + k)*64 + d] = s;
    }
}

__global__ __launch_bounds__(256) void c1pre_kernel(
    const float* __restrict__ newv, const float* __restrict__ SC, float* __restrict__ dst)
{
    int i = blockIdx.x*256 + threadIdx.x;
    if (i >= M_PATCH*64) return;
    int d = i & 63; int bp = i >> 6;
    dst[i] = newv[((size_t)bp*9 + 4)*64 + d] + SC[NVB_OFF + d*9 + 4];
}

__global__ __launch_bounds__(256) void c3pre_kernel(
    const float* __restrict__ newv, const float* __restrict__ SC, float* __restrict__ dst)
{
    int i = blockIdx.x*256 + threadIdx.x;
    if (i >= M_PATCH*64) return;
    int d = i & 63; int bij = i >> 6;
    int j = bij % 14; int bi = bij / 14; int irow = bi % 14; int b = bi / 14;
    float acc = SC[SVB_OFF + d];
    #pragma unroll
    for (int p = 0; p < 9; p++) {
        int h1 = p % 3, h2 = p / 3;
        int y = irow + h1 - 1, x = j + h2 - 1;
        if (y >= 0 && y < 14 && x >= 0 && x < 14)
            acc += newv[(((size_t)b*NP_ + y*14 + x)*9 + p)*64 + d];
    }
    dst[i] = acc;
}

// ---------------- BN ----------------
__global__ __launch_bounds__(256) void bnstat_kernel(
    const float* __restrict__ src, int nelem, float* __restrict__ partial)
{
    __shared__ float sd[256], sq[256];
    int tid = threadIdx.x;
    float s = 0.f, q = 0.f;
    int stride = gridDim.x * 256;
    for (int i = blockIdx.x*256 + tid; i < nelem; i += stride) {
        float v = src[i]; s += v; q += v*v;
    }
    sd[tid] = s; sq[tid] = q;
    __syncthreads();
    if (tid < 64) {
        float ts = sd[tid]+sd[tid+64]+sd[tid+128]+sd[tid+192];
        float tq = sq[tid]+sq[tid+64]+sq[tid+128]+sq[tid+192];
        partial[blockIdx.x*128 + tid]      = ts;
        partial[blockIdx.x*128 + 64 + tid] = tq;
    }
}

__global__ void bnreduce_kernel(const float* __restrict__ partial, int nblk, float* __restrict__ stats)
{
    int t = threadIdx.x;  // 128
    float s = 0.f;
    for (int i = 0; i < nblk; i++) s += partial[i*128 + t];
    stats[t] = s;
}

__global__ __launch_bounds__(256) void bnapply_kernel(
    float* __restrict__ buf, int nelem, const float* __restrict__ stats,
    const float* __restrict__ g, const float* __restrict__ bb, float invN)
{
    int i = blockIdx.x*256 + threadIdx.x;
    if (i >= nelem) return;
    int d = i & 63;
    float mean = stats[d]*invN;
    float var  = stats[64+d]*invN - mean*mean;
    float sc = rsqrtf(var + BN_EPS_) * g[d];
    float v = (buf[i] - mean)*sc + bb[d];
    buf[i] = fmaxf(v, 0.f);
}

// ---------------- W1/W3 ----------------
__global__ __launch_bounds__(256) void w13_kernel(
    const float* __restrict__ proj_w, const float* __restrict__ SC,
    float* __restrict__ W1, float* __restrict__ W3)
{
    int idx = blockIdx.x*256 + threadIdx.x;
    if (idx >= 768*64) return;
    int d = idx & 63, c = idx >> 6;
    float s1 = 0.f, s3 = 0.f;
    #pragma unroll
    for (int h = 0; h < 12; h++) {
        float pw = proj_w[(size_t)c*768 + h*64 + d];
        s1 += pw * SC[HP_OFF + h*9 + 4];
        s3 += pw * SC[HPROW_OFF + h];
    }
    W1[idx] = s1; W3[idx] = s3;
}

// ---------------- final blend ----------------
__global__ __launch_bounds__(256) void blend_kernel(
    const float* __restrict__ x, const float* pbuf,
    const float* __restrict__ c1o, const float* __restrict__ c3o,
    const float* __restrict__ SC, float* out)
{
    int i = blockIdx.x*256 + threadIdx.x;
    if (i >= OUT_MAIN) return;
    int cc = i % 768; int bn = i / 768; int n = bn % 197;
    float w0 = SC[0], w1 = SC[1], w2 = SC[2];
    float m = pbuf[i];
    float c1v, c3v;
    if (n == 0) { c1v = x[i]; c3v = x[i]; }
    else {
        size_t q = ((size_t)(bn - (bn/197) - 1))*768 + cc;
        c1v = c1o[q]; c3v = c3o[q];
    }
    out[i] = w0*m + w1*c3v + w2*c1v;
}

// ---------------- launch ----------------
extern "C" void kernel_launch(void* const* d_in, const int* in_sizes, int n_in,
                              void* d_out, int out_size, void* d_ws, size_t ws_size,
                              hipStream_t stream)
{
    const float* x        = (const float*)d_in[0];
    const float* uniforms = (const float*)d_in[1];
    const float* qk_w     = (const float*)d_in[2];
    const float* qk_b     = (const float*)d_in[3];
    const float* v_w      = (const float*)d_in[4];
    const float* v_b      = (const float*)d_in[5];
    const float* proj_w   = (const float*)d_in[6];
    const float* proj_b   = (const float*)d_in[7];
    const float* bn1_g    = (const float*)d_in[8];
    const float* bn1_b    = (const float*)d_in[9];
    const float* bn3_g    = (const float*)d_in[10];
    const float* bn3_b    = (const float*)d_in[11];
    const float* kth      = (const float*)d_in[12];
    const float* head_probs = (const float*)d_in[13];
    float* out = (float*)d_out;

    float* ws = (float*)d_ws;
    float* R1 = ws;                     // 19,365,888 floats
    float* vw = ws + 19365888;          //  9,682,944 floats (fp32 v_weight)
    float* R3 = ws + 29048832;          //  9,682,944 floats
    float* SC = ws + 38731776;          //    132,096 floats
    unsigned short* qkbf = (unsigned short*)R1;
    unsigned short* vbfT = (unsigned short*)R1 + 19365888;
    unsigned int*   pjw2 = (unsigned int*)(ws + 15187968);
    float* newv  = R1;
    float* c1out = R1;
    float* c3out = R1 + 9633792;
    float* c1buf = vw;
    float* c3buf = vw + 802816;
    unsigned int* x2   = (unsigned int*)R3;
    unsigned int* msa2 = (unsigned int*)R3;
    unsigned int* W2a = (unsigned int*)out;
    unsigned int* W2b = (unsigned int*)out + 1179648;
    float* pbuf = out;
    float* W1    = SC + W1_OFF;
    float* W3    = SC + W3_OFF;
    float* stats = SC + STATS_OFF;
    float* part  = SC + PART_OFF;

    prep_kernel<<<1, 256, 0, stream>>>(uniforms, kth, head_probs, v_b, SC, out + OUT_MAIN);

    conv_hilo<<<9456, 256, 0, stream>>>(x, x2, 2420736);
    conv_dup<<<1152, 256, 0, stream>>>(qk_w, W2a, 294912);
    conv_dup<<<576, 256, 0, stream>>>(v_w, W2b, 147456);

    gemm_qkv<<<1782, 256, 0, stream>>>((const unsigned short*)x2,
                                       (const unsigned short*)W2a, qk_b,
                                       qkbf, vw, (unsigned short*)vbfT);

    flash_attn<<<768, 256, 0, stream>>>(qkbf, (const unsigned short*)vbfT, v_b, msa2);

    conv_dup<<<576, 256, 0, stream>>>(proj_w, pjw2, 147456);
    gemm_proj<<<594, 256, 0, stream>>>((const unsigned short*)msa2, (const unsigned short*)pjw2,
                                       proj_b, pbuf, M_TOK, 768, 6);

    newv_kernel<<<3136, 256, 0, stream>>>(vw, SC, newv);

    c1pre_kernel<<<3136, 256, 0, stream>>>(newv, SC, c1buf);
    bnstat_kernel<<<256, 256, 0, stream>>>(c1buf, M_PATCH*64, part);
    bnreduce_kernel<<<1, 128, 0, stream>>>(part, 256, stats);
    bnapply_kernel<<<3136, 256, 0, stream>>>(c1buf, M_PATCH*64, stats, bn1_g, bn1_b, 1.0f/12544.0f);

    c3pre_kernel<<<3136, 256, 0, stream>>>(newv, SC, c3buf);
    bnstat_kernel<<<256, 256, 0, stream>>>(c3buf, M_PATCH*64, part);
    bnreduce_kernel<<<1, 128, 0, stream>>>(part, 256, stats);
    bnapply_kernel<<<3136, 256, 0, stream>>>(c3buf, M_PATCH*64, stats, bn3_g, bn3_b, 1.0f/12544.0f);

    w13_kernel<<<192, 256, 0, stream>>>(proj_w, SC, W1, W3);

    gemm_xwt<true><<<dim3(12,196), 256, 0, stream>>>(c1buf, W1, proj_b, c1out, M_PATCH, 768, 64);
    gemm_xwt<true><<<dim3(12,196), 256, 0, stream>>>(c3buf, W3, proj_b, c3out, M_PATCH, 768, 64);

    blend_kernel<<<37824, 256, 0, stream>>>(x, pbuf, c1out, c3out, SC, out);
}

// Round 9
// 456.015 us; speedup vs baseline: 8.7619x; 1.2290x over previous
//
#include <hip/hip_runtime.h>
#include <cstdint>
#include <cstddef>

// ---------------- problem constants ----------------
#define B_    64
#define N_    197
#define DIM_  768
#define NH_   12
#define HD_   64
#define NP_   196
#define SCALE_ 0.125f
#define EPS_   1.1920929e-07f
#define BN_EPS_ 1e-5f
#define ALPHA_ 0.01f

#define M_TOK   (B_*N_)        // 12608
#define M_PATCH (B_*NP_)       // 12544
#define OUT_MAIN (M_TOK*DIM_)  // 9682944

#define K2_ 768                // single-bf16 GEMM K

// scalar workspace layout (float offsets within SC)
#define W_OFF     0
#define HP_OFF    16
#define HPROW_OFF 128
#define NVB_OFF   144
#define SVB_OFF   720
#define STATS_OFF 784
#define W1_OFF    1024
#define W3_OFF    50176
#define PART_OFF  99328
#define SC_FLOATS 132096

typedef short bf16x8_ __attribute__((ext_vector_type(8)));
typedef float f32x4_  __attribute__((ext_vector_type(4)));

// ---------------- prep ----------------
__global__ void prep_kernel(const float* __restrict__ uniforms, const float* __restrict__ kth,
                            const float* __restrict__ head_probs, const float* __restrict__ v_b,
                            float* __restrict__ SC, float* __restrict__ out_tail)
{
    int t = threadIdx.x;
    if (t == 0) {
        float ind[3];
        for (int i = 0; i < 3; i++) {
            float s = 1.f/(1.f + expf(-kth[i]));
            float p = fminf(fmaxf(s, EPS_), 1.f - EPS_);
            float u = fminf(fmaxf(uniforms[i], EPS_), 1.f - EPS_);
            float logit = logf(u) - log1pf(-u) + logf(p) - log1pf(-p);
            ind[i] = (logit > 0.f) ? 1.f : 0.f;
        }
        SC[W_OFF+0] = ind[2];
        SC[W_OFF+1] = ind[1]*(1.f-ind[2]);
        SC[W_OFF+2] = ind[0]*(1.f-ind[1])*(1.f-ind[2]);
        float kprod = 1.f;
        for (int i = 0; i < 3; i++) {
            float ktv = 1.f/(1.f + expf(-kth[i]));
            kprod *= (ktv > 0.5f) ? 1.f : 0.f;
            out_tail[i]   = kprod;
            out_tail[3+i] = ktv;
        }
    }
    if (t < 9) {
        float mx = -1e30f;
        for (int h = 0; h < 12; h++) mx = fmaxf(mx, head_probs[h*9+t]);
        float e[12]; float s = 0.f;
        for (int h = 0; h < 12; h++) { e[h] = expf((head_probs[h*9+t]-mx)/ALPHA_); s += e[h]; }
        for (int h = 0; h < 12; h++) SC[HP_OFF + h*9 + t] = e[h]/s;
    }
    __syncthreads();
    if (t < 12) {
        float s = 0.f;
        for (int k = 0; k < 9; k++) s += SC[HP_OFF + t*9 + k];
        SC[HPROW_OFF + t] = s;
    }
    if (t < 64) {
        float sv = 0.f;
        for (int k = 0; k < 9; k++) {
            float s = 0.f;
            for (int h = 0; h < 12; h++) s += v_b[h*64+t]*SC[HP_OFF + h*9 + k];
            SC[NVB_OFF + t*9 + k] = s;
            sv += s;
        }
        SC[SVB_OFF + t] = sv;
    }
}

// ---------------- fp32 -> bf16 (RNE) ----------------
__device__ __forceinline__ unsigned short bfr_(float f) {
    unsigned u = __float_as_uint(f);
    return (unsigned short)((u + 0x7FFFu + ((u >> 16) & 1u)) >> 16);
}

// 8 floats -> 8 packed bf16 per thread
__global__ __launch_bounds__(256) void conv_hi(const float* __restrict__ in,
                                               unsigned int* __restrict__ out, int n8)
{
    int i = blockIdx.x*256 + threadIdx.x;
    if (i >= n8) return;
    float4 a = ((const float4*)in)[2*i];
    float4 b = ((const float4*)in)[2*i+1];
    unsigned r0 = (unsigned)bfr_(a.x) | ((unsigned)bfr_(a.y) << 16);
    unsigned r1 = (unsigned)bfr_(a.z) | ((unsigned)bfr_(a.w) << 16);
    unsigned r2 = (unsigned)bfr_(b.x) | ((unsigned)bfr_(b.y) << 16);
    unsigned r3 = (unsigned)bfr_(b.z) | ((unsigned)bfr_(b.w) << 16);
    ((uint4*)out)[i] = make_uint4(r0, r1, r2, r3);
}

// ---- global_load_lds staging (linear LDS [128][32] ushorts, XOR-swizzled src+read) ----
#define STAGE_TILE(LDSBUF, GBASE, ROWCLAMP)                                              \
    {                                                                                    \
        _Pragma("unroll")                                                                \
        for (int i_ = 0; i_ < 2; i_++) {                                                 \
            int r_ = wave*32 + i_*16 + (lane >> 2);                                      \
            int gr_ = ROWCLAMP(r_);                                                      \
            const unsigned short* gp_ = (GBASE) + (size_t)gr_*K2_ + k0                   \
                                        + (((lane & 3) ^ (r_ & 3)) * 8);                 \
            __builtin_amdgcn_global_load_lds(                                            \
                (const __attribute__((address_space(1))) unsigned int*)gp_,              \
                (__attribute__((address_space(3))) unsigned int*)&LDSBUF[(wave*32 + i_*16)*32], \
                16, 0, 0);                                                               \
        }                                                                                \
    }

// ---------------- merged qk+v GEMM (bf16 MFMA) ----------------
__global__ __launch_bounds__(256) void gemm_qkv(
    const unsigned short* __restrict__ A2, const unsigned short* __restrict__ W2,
    const float* __restrict__ qk_b,
    unsigned short* __restrict__ qkbf, float* __restrict__ vw,
    unsigned short* __restrict__ vbfT)
{
    __shared__ unsigned short At[128*32];
    __shared__ unsigned short Bt[128*32];
    const int nwg = 1782;
    int q = nwg >> 3, rr = nwg & 7;
    int xcd = blockIdx.x & 7, idx = blockIdx.x >> 3;
    int s = (xcd < rr) ? xcd*(q+1) + idx : rr*(q+1) + (xcd - rr)*q + idx;
    const int n0 = (s % 18) * 128, m0 = (s / 18) * 128;
    const int tid = threadIdx.x;
    const int wave = tid >> 6, lane = tid & 63;
    const int wr = (wave >> 1)*64, wc = (wave & 1)*64;
    const int fr = lane & 15, fq = lane >> 4;
    const int xk = (fq ^ (fr & 3)) * 8;

    f32x4_ acc[4][4] = {};

    #define CLA_(r) ((m0 + (r) < M_TOK) ? (m0 + (r)) : (M_TOK-1))
    #define CLB_(r) (n0 + (r))
    for (int k0 = 0; k0 < K2_; k0 += 32) {
        STAGE_TILE(At, A2, CLA_)
        STAGE_TILE(Bt, W2, CLB_)
        __syncthreads();
        bf16x8_ a[4], bb[4];
        #pragma unroll
        for (int i = 0; i < 4; i++) {
            a[i]  = *(const bf16x8_*)&At[(wr + i*16 + fr)*32 + xk];
            bb[i] = *(const bf16x8_*)&Bt[(wc + i*16 + fr)*32 + xk];
        }
        #pragma unroll
        for (int mi = 0; mi < 4; mi++)
            #pragma unroll
            for (int ni = 0; ni < 4; ni++)
                acc[mi][ni] = __builtin_amdgcn_mfma_f32_16x16x32_bf16(a[mi], bb[ni], acc[mi][ni], 0, 0, 0);
        __syncthreads();
    }
    #undef CLA_
    #undef CLB_

    if (n0 < 1536) {
        float bv[4];
        #pragma unroll
        for (int ni = 0; ni < 4; ni++) bv[ni] = qk_b[n0 + wc + ni*16 + fr];
        #pragma unroll
        for (int mi = 0; mi < 4; mi++) {
            #pragma unroll
            for (int j = 0; j < 4; j++) {
                int row = m0 + wr + mi*16 + fq*4 + j;
                if (row < M_TOK) {
                    unsigned short* crow = qkbf + (size_t)row*1536 + n0 + wc;
                    #pragma unroll
                    for (int ni = 0; ni < 4; ni++)
                        crow[ni*16 + fr] = bfr_(acc[mi][ni][j] + bv[ni]);
                }
            }
        }
    } else {
        const int v0 = n0 - 1536;
        #pragma unroll
        for (int mi = 0; mi < 4; mi++) {
            #pragma unroll
            for (int j = 0; j < 4; j++) {
                int row = m0 + wr + mi*16 + fq*4 + j;
                if (row < M_TOK) {
                    int bq = row / N_;
                    int cc = row - bq*N_;
                    float* vrow = vw + (size_t)row*768 + v0 + wc;
                    #pragma unroll
                    for (int ni = 0; ni < 4; ni++) {
                        float val = acc[mi][ni][j];
                        int vcol = v0 + wc + ni*16 + fr;
                        vrow[ni*16 + fr] = val;
                        int hh = vcol >> 6, dd = vcol & 63;
                        vbfT[((size_t)(bq*NH_ + hh)*64 + dd)*224 + cc] = bfr_(val);
                    }
                }
            }
        }
    }
}

// ---------------- proj GEMM (bf16 MFMA) + fused blend epilogue ----------------
__global__ __launch_bounds__(256) void gemm_proj(
    const unsigned short* __restrict__ A2, const unsigned short* __restrict__ W2,
    const float* __restrict__ bias,
    const float* __restrict__ x, const float* __restrict__ c1o,
    const float* __restrict__ c3o, const float* __restrict__ SC,
    float* __restrict__ out)
{
    __shared__ unsigned short At[128*32];
    __shared__ unsigned short Bt[128*32];
    const int nwg = gridDim.x;
    int q = nwg >> 3, rr = nwg & 7;
    int xcd = blockIdx.x & 7, idx = blockIdx.x >> 3;
    int s = (xcd < rr) ? xcd*(q+1) + idx : rr*(q+1) + (xcd - rr)*q + idx;
    const int n0 = (s % 6) * 128, m0 = (s / 6) * 128;
    const int tid = threadIdx.x;
    const int wave = tid >> 6, lane = tid & 63;
    const int wr = (wave >> 1)*64, wc = (wave & 1)*64;
    const int fr = lane & 15, fq = lane >> 4;
    const int xk = (fq ^ (fr & 3)) * 8;

    f32x4_ acc[4][4] = {};

    #define CLA_(r) ((m0 + (r) < M_TOK) ? (m0 + (r)) : (M_TOK-1))
    #define CLB_(r) (n0 + (r))
    for (int k0 = 0; k0 < K2_; k0 += 32) {
        STAGE_TILE(At, A2, CLA_)
        STAGE_TILE(Bt, W2, CLB_)
        __syncthreads();
        bf16x8_ a[4], bb[4];
        #pragma unroll
        for (int i = 0; i < 4; i++) {
            a[i]  = *(const bf16x8_*)&At[(wr + i*16 + fr)*32 + xk];
            bb[i] = *(const bf16x8_*)&Bt[(wc + i*16 + fr)*32 + xk];
        }
        #pragma unroll
        for (int mi = 0; mi < 4; mi++)
            #pragma unroll
            for (int ni = 0; ni < 4; ni++)
                acc[mi][ni] = __builtin_amdgcn_mfma_f32_16x16x32_bf16(a[mi], bb[ni], acc[mi][ni], 0, 0, 0);
        __syncthreads();
    }
    #undef CLA_
    #undef CLB_

    const float w0 = SC[0], w1 = SC[1], w2 = SC[2];
    float bv[4];
    #pragma unroll
    for (int ni = 0; ni < 4; ni++) bv[ni] = bias[n0 + wc + ni*16 + fr];
    #pragma unroll
    for (int mi = 0; mi < 4; mi++) {
        #pragma unroll
        for (int j = 0; j < 4; j++) {
            int row = m0 + wr + mi*16 + fq*4 + j;
            if (row < M_TOK) {
                int b = row / N_;
                int n = row - b*N_;
                float* orow = out + (size_t)row*768 + n0 + wc;
                if (n == 0) {
                    const float* xr = x + (size_t)row*768 + n0 + wc;
                    #pragma unroll
                    for (int ni = 0; ni < 4; ni++) {
                        float m = acc[mi][ni][j] + bv[ni];
                        float xv = xr[ni*16 + fr];
                        orow[ni*16 + fr] = w0*m + w1*xv + w2*xv;
                    }
                } else {
                    size_t qb = ((size_t)(row - b - 1))*768 + n0 + wc;
                    #pragma unroll
                    for (int ni = 0; ni < 4; ni++) {
                        float m = acc[mi][ni][j] + bv[ni];
                        orow[ni*16 + fr] = w0*m + w1*c3o[qb + ni*16 + fr] + w2*c1o[qb + ni*16 + fr];
                    }
                }
            }
        }
    }
}

// ---------------- fused flash attention (bf16 MFMA) ----------------
__global__ __launch_bounds__(256) void flash_attn(
    const unsigned short* __restrict__ qkbf,
    const unsigned short* __restrict__ vbfT,
    const float* __restrict__ v_b,
    unsigned short* __restrict__ msa2)
{
    __shared__ unsigned short Kb[224][64];
    __shared__ unsigned short Vt[64][256];
    const int bh = blockIdx.x;
    const int b = bh / NH_, h = bh % NH_;
    const int tid = threadIdx.x;
    const int wv = tid >> 6, lane = tid & 63;
    const int fr = lane & 15, fq = lane >> 4;

    {
        const unsigned short* Kg = qkbf + (size_t)(b*N_)*1536 + 768 + h*64;
        int r = tid >> 3; const int ch = tid & 7;
        #pragma unroll
        for (int rnd = 0; rnd < 7; rnd++, r += 32) {
            uint4 val = make_uint4(0u,0u,0u,0u);
            if (r < N_) val = *(const uint4*)(Kg + (size_t)r*1536 + ch*8);
            *(uint4*)&Kb[r][(ch ^ (r & 7))*8] = val;
        }
    }
    {
        const unsigned short* Vg = vbfT + (size_t)bh*(64*224);
        #pragma unroll
        for (int rnd = 0; rnd < 8; rnd++) {
            int job = rnd*256 + tid;
            int d = job >> 5, ch = job & 31;
            uint4 val = make_uint4(0u,0u,0u,0u);
            if (ch < 24) val = *(const uint4*)(Vg + (size_t)d*224 + ch*8);
            else if (ch == 24) {
                val = *(const uint4*)(Vg + (size_t)d*224 + 192);
                val.z &= 0xFFFFu; val.w = 0u;
            }
            *(uint4*)&Vt[d][(ch ^ (d & 7))*8] = val;
        }
    }
    bf16x8_ qf[4][2];
    #pragma unroll
    for (int nf = 0; nf < 4; nf++) {
        int qr = wv*64 + nf*16 + fr; if (qr > N_-1) qr = N_-1;
        const unsigned short* Qg = qkbf + (size_t)(b*N_ + qr)*1536 + h*64;
        qf[nf][0] = *(const bf16x8_*)(Qg + fq*8);
        qf[nf][1] = *(const bf16x8_*)(Qg + 32 + fq*8);
    }
    __syncthreads();

    f32x4_ o[4][4];
    #pragma unroll
    for (int i = 0; i < 4; i++)
        #pragma unroll
        for (int j2 = 0; j2 < 4; j2++) { o[i][j2][0]=0.f; o[i][j2][1]=0.f; o[i][j2][2]=0.f; o[i][j2][3]=0.f; }
    float m_[4] = {-1e30f,-1e30f,-1e30f,-1e30f};
    float l_[4] = {0.f,0.f,0.f,0.f};

    for (int t = 0; t < 14; t++) {
        const int krow = t*16 + fr;
        bf16x8_ kf0 = *(const bf16x8_*)&Kb[krow][( fq      ^ (fr & 7))*8];
        bf16x8_ kf1 = *(const bf16x8_*)&Kb[krow][((fq + 4) ^ (fr & 7))*8];
        f32x4_ st[4];
        #pragma unroll
        for (int nf = 0; nf < 4; nf++) {
            f32x4_ z = {0.f,0.f,0.f,0.f};
            z = __builtin_amdgcn_mfma_f32_16x16x32_bf16(kf0, qf[nf][0], z, 0,0,0);
            z = __builtin_amdgcn_mfma_f32_16x16x32_bf16(kf1, qf[nf][1], z, 0,0,0);
            st[nf] = z;
        }
        const int cbase = t*16 + fq*4;
        float p[4][4];
        #pragma unroll
        for (int nf = 0; nf < 4; nf++) {
            #pragma unroll
            for (int jj = 0; jj < 4; jj++)
                st[nf][jj] = (cbase + jj < N_) ? st[nf][jj]*SCALE_ : -1e30f;
            float tm = fmaxf(fmaxf(st[nf][0],st[nf][1]), fmaxf(st[nf][2],st[nf][3]));
            tm = fmaxf(tm, __shfl_xor(tm, 16));
            tm = fmaxf(tm, __shfl_xor(tm, 32));
            float mn = fmaxf(m_[nf], tm);
            float sc = __expf(m_[nf] - mn);
            float ps = 0.f;
            #pragma unroll
            for (int jj = 0; jj < 4; jj++) {
                float e = __expf(st[nf][jj] - mn);
                p[nf][jj] = e; ps += e;
            }
            ps += __shfl_xor(ps, 16);
            ps += __shfl_xor(ps, 32);
            l_[nf] = l_[nf]*sc + ps;
            m_[nf] = mn;
            #pragma unroll
            for (int df = 0; df < 4; df++) {
                o[df][nf][0]*=sc; o[df][nf][1]*=sc; o[df][nf][2]*=sc; o[df][nf][3]*=sc;
            }
        }
        bf16x8_ pa[4];
        const bool half = (fq < 2);
        #pragma unroll
        for (int nf = 0; nf < 4; nf++) {
            #pragma unroll
            for (int tt = 0; tt < 8; tt++) {
                int src = fr + 16*((fq & 1)*2 + (tt >> 2));
                float v = __shfl(p[nf][tt & 3], src);
                pa[nf][tt] = half ? (short)bfr_(v) : (short)0;
            }
        }
        #pragma unroll
        for (int df = 0; df < 4; df++) {
            bf16x8_ vf = *(const bf16x8_*)&Vt[df*16 + fr][((t*2 + fq) ^ (fr & 7))*8];
            #pragma unroll
            for (int nf = 0; nf < 4; nf++)
                o[df][nf] = __builtin_amdgcn_mfma_f32_16x16x32_bf16(vf, pa[nf], o[df][nf], 0,0,0);
        }
    }
    // epilogue: normalize, add v_b, store bf16 (uint2 per df)
    #pragma unroll
    for (int nf = 0; nf < 4; nf++) {
        int qr = wv*64 + nf*16 + fr;
        if (qr >= N_) continue;
        float inv = 1.f / l_[nf];
        unsigned short* orow = msa2 + (size_t)(b*N_ + qr)*768 + h*64;
        #pragma unroll
        for (int df = 0; df < 4; df++) {
            const float4 vb4 = *(const float4*)&v_b[h*64 + df*16 + fq*4];
            unsigned u0 = (unsigned)bfr_(o[df][nf][0]*inv + vb4.x)
                        | ((unsigned)bfr_(o[df][nf][1]*inv + vb4.y) << 16);
            unsigned u1 = (unsigned)bfr_(o[df][nf][2]*inv + vb4.z)
                        | ((unsigned)bfr_(o[df][nf][3]*inv + vb4.w) << 16);
            uint2 w; w.x = u0; w.y = u1;
            *(uint2*)(orow + df*16 + fq*4) = w;
        }
    }
}

// ---------------- fp32 GEMM (K=64 branch GEMMs) ----------------
#define GT 64
#define GK 16
template<bool BIAS>
__global__ __launch_bounds__(256) void gemm_xwt(
    const float* __restrict__ A, const float* __restrict__ W,
    const float* __restrict__ bias, float* __restrict__ C,
    int M, int Ncols, int K)
{
    __shared__ float As[GK][GT+4];
    __shared__ float Bs[GK][GT+4];
    const int tid = threadIdx.x;
    const int tx = tid & 15, ty = tid >> 4;
    const int m0 = blockIdx.y * GT, n0 = blockIdx.x * GT;
    float acc[4][4] = {};
    for (int k0 = 0; k0 < K; k0 += GK) {
        #pragma unroll
        for (int i = 0; i < 4; i++) {
            int r = ty + i*16;
            As[tx][r] = A[(size_t)(m0 + r)*K + (k0 + tx)];
            Bs[tx][r] = W[(size_t)(n0 + r)*K + (k0 + tx)];
        }
        __syncthreads();
        #pragma unroll
        for (int kk = 0; kk < GK; kk++) {
            const float4 a4 = *(const float4*)&As[kk][ty*4];
            const float4 b4 = *(const float4*)&Bs[kk][tx*4];
            const float a[4] = {a4.x, a4.y, a4.z, a4.w};
            const float b[4] = {b4.x, b4.y, b4.z, b4.w};
            #pragma unroll
            for (int i = 0; i < 4; i++)
                #pragma unroll
                for (int j = 0; j < 4; j++)
                    acc[i][j] += a[i]*b[j];
        }
        __syncthreads();
    }
    float4 bv = make_float4(0.f,0.f,0.f,0.f);
    if (BIAS) bv = *(const float4*)&bias[n0 + tx*4];
    #pragma unroll
    for (int i = 0; i < 4; i++) {
        int m = m0 + ty*4 + i;
        float4 o = make_float4(acc[i][0]+bv.x, acc[i][1]+bv.y, acc[i][2]+bv.z, acc[i][3]+bv.w);
        *(float4*)&C[(size_t)m*Ncols + n0 + tx*4] = o;
    }
}

// ---------------- new_v ----------------
__global__ __launch_bounds__(256) void newv_kernel(
    const float* __restrict__ vw, const float* __restrict__ SC, float* __restrict__ newv)
{
    int idx = blockIdx.x*256 + threadIdx.x;
    if (idx >= M_PATCH*64) return;
    int d = idx & 63; int bp = idx >> 6;
    int p = bp % NP_, b = bp / NP_;
    const float* src = vw + (size_t)(b*N_ + 1 + p)*768 + d;
    float vh[12];
    #pragma unroll
    for (int h = 0; h < 12; h++) vh[h] = src[h*64];
    #pragma unroll
    for (int k = 0; k < 9; k++) {
        float s = 0.f;
        #pragma unroll
        for (int h = 0; h < 12; h++) s += vh[h]*SC[HP_OFF + h*9 + k];
        newv[((size_t)bp*9 + k)*64 + d] = s;
    }
}

__global__ __launch_bounds__(256) void c1pre_kernel(
    const float* __restrict__ newv, const float* __restrict__ SC, float* __restrict__ dst)
{
    int i = blockIdx.x*256 + threadIdx.x;
    if (i >= M_PATCH*64) return;
    int d = i & 63; int bp = i >> 6;
    dst[i] = newv[((size_t)bp*9 + 4)*64 + d] + SC[NVB_OFF + d*9 + 4];
}

__global__ __launch_bounds__(256) void c3pre_kernel(
    const float* __restrict__ newv, const float* __restrict__ SC, float* __restrict__ dst)
{
    int i = blockIdx.x*256 + threadIdx.x;
    if (i >= M_PATCH*64) return;
    int d = i & 63; int bij = i >> 6;
    int j = bij % 14; int bi = bij / 14; int irow = bi % 14; int b = bi / 14;
    float acc = SC[SVB_OFF + d];
    #pragma unroll
    for (int p = 0; p < 9; p++) {
        int h1 = p % 3, h2 = p / 3;
        int y = irow + h1 - 1, x = j + h2 - 1;
        if (y >= 0 && y < 14 && x >= 0 && x < 14)
            acc += newv[(((size_t)b*NP_ + y*14 + x)*9 + p)*64 + d];
    }
    dst[i] = acc;
}

// ---------------- BN ----------------
__global__ __launch_bounds__(256) void bnstat_kernel(
    const float* __restrict__ src, int nelem, float* __restrict__ partial)
{
    __shared__ float sd[256], sq[256];
    int tid = threadIdx.x;
    float s = 0.f, q = 0.f;
    int stride = gridDim.x * 256;
    for (int i = blockIdx.x*256 + tid; i < nelem; i += stride) {
        float v = src[i]; s += v; q += v*v;
    }
    sd[tid] = s; sq[tid] = q;
    __syncthreads();
    if (tid < 64) {
        float ts = sd[tid]+sd[tid+64]+sd[tid+128]+sd[tid+192];
        float tq = sq[tid]+sq[tid+64]+sq[tid+128]+sq[tid+192];
        partial[blockIdx.x*128 + tid]      = ts;
        partial[blockIdx.x*128 + 64 + tid] = tq;
    }
}

__global__ void bnreduce_kernel(const float* __restrict__ partial, int nblk, float* __restrict__ stats)
{
    int t = threadIdx.x;  // 128
    float s = 0.f;
    for (int i = 0; i < nblk; i++) s += partial[i*128 + t];
    stats[t] = s;
}

__global__ __launch_bounds__(256) void bnapply_kernel(
    float* __restrict__ buf, int nelem, const float* __restrict__ stats,
    const float* __restrict__ g, const float* __restrict__ bb, float invN)
{
    int i = blockIdx.x*256 + threadIdx.x;
    if (i >= nelem) return;
    int d = i & 63;
    float mean = stats[d]*invN;
    float var  = stats[64+d]*invN - mean*mean;
    float sc = rsqrtf(var + BN_EPS_) * g[d];
    float v = (buf[i] - mean)*sc + bb[d];
    buf[i] = fmaxf(v, 0.f);
}

// ---------------- W1/W3 ----------------
__global__ __launch_bounds__(256) void w13_kernel(
    const float* __restrict__ proj_w, const float* __restrict__ SC,
    float* __restrict__ W1, float* __restrict__ W3)
{
    int idx = blockIdx.x*256 + threadIdx.x;
    if (idx >= 768*64) return;
    int d = idx & 63, c = idx >> 6;
    float s1 = 0.f, s3 = 0.f;
    #pragma unroll
    for (int h = 0; h < 12; h++) {
        float pw = proj_w[(size_t)c*768 + h*64 + d];
        s1 += pw * SC[HP_OFF + h*9 + 4];
        s3 += pw * SC[HPROW_OFF + h];
    }
    W1[idx] = s1; W3[idx] = s3;
}

// ---------------- launch ----------------
extern "C" void kernel_launch(void* const* d_in, const int* in_sizes, int n_in,
                              void* d_out, int out_size, void* d_ws, size_t ws_size,
                              hipStream_t stream)
{
    const float* x        = (const float*)d_in[0];
    const float* uniforms = (const float*)d_in[1];
    const float* qk_w     = (const float*)d_in[2];
    const float* qk_b     = (const float*)d_in[3];
    const float* v_w      = (const float*)d_in[4];
    const float* v_b      = (const float*)d_in[5];
    const float* proj_w   = (const float*)d_in[6];
    const float* proj_b   = (const float*)d_in[7];
    const float* bn1_g    = (const float*)d_in[8];
    const float* bn1_b    = (const float*)d_in[9];
    const float* bn3_g    = (const float*)d_in[10];
    const float* bn3_b    = (const float*)d_in[11];
    const float* kth      = (const float*)d_in[12];
    const float* head_probs = (const float*)d_in[13];
    float* out = (float*)d_out;

    // ws regions; every alias written-in-full before read each call
    float* ws = (float*)d_ws;
    float* R1 = ws;                     // 19,365,888 floats
    float* vw = ws + 19365888;          //  9,682,944 floats (fp32 v_weight)
    float* R3 = ws + 29048832;          //  9,682,944 floats
    float* SC = ws + 38731776;          //    132,096 floats
    // R1 phases: qkbf (bf16, 19.4M ushorts = floats [0, 9682944)) + vbfT (11.0M ushorts
    //   = floats [9682944, 15187968)) for gemm_qkv->flash; then newv/c1out/c3out.
    unsigned short* qkbf = (unsigned short*)R1;
    unsigned short* vbfT = (unsigned short*)R1 + 19365888;
    float* newv  = R1;                  // [0, 7225344)
    float* c1out = R1;                  // [0, 9633792)
    float* c3out = R1 + 9633792;        // [9633792, 19267584)
    float* c1buf = vw;
    float* c3buf = vw + 802816;
    // R3 phases: x2 bf16 (floats [0, 4841472)) -> msa2 bf16 (same) ; pjw2 at [6000000,+294912)
    unsigned int* x2    = (unsigned int*)R3;
    unsigned short* msa2 = (unsigned short*)R3;
    unsigned int* pjw2  = (unsigned int*)(R3 + 6000000);
    // d_out: W2 (qk_w bf16 then v_w bf16, contiguous rows) -> final out (gemm_proj fused blend)
    unsigned int* W2a = (unsigned int*)out;                 // 589,824 uints (1536x768 bf16)
    unsigned int* W2b = (unsigned int*)out + 589824;        // 294,912 uints (768x768 bf16)
    float* W1    = SC + W1_OFF;
    float* W3    = SC + W3_OFF;
    float* stats = SC + STATS_OFF;
    float* part  = SC + PART_OFF;

    prep_kernel<<<1, 256, 0, stream>>>(uniforms, kth, head_probs, v_b, SC, out + OUT_MAIN);

    // bf16 conversions (single hi)
    conv_hi<<<4728, 256, 0, stream>>>(x, x2, 1210368);
    conv_hi<<<576, 256, 0, stream>>>(qk_w, W2a, 147456);
    conv_hi<<<288, 256, 0, stream>>>(v_w, W2b, 73728);

    // merged qk+v GEMM -> qkbf (bf16), vw (fp32), vbfT (bf16 transposed)
    gemm_qkv<<<1782, 256, 0, stream>>>((const unsigned short*)x2,
                                       (const unsigned short*)W2a, qk_b,
                                       qkbf, vw, (unsigned short*)vbfT);

    // fused attention -> msa2 bf16 (overwrites x2)
    flash_attn<<<768, 256, 0, stream>>>(qkbf, (const unsigned short*)vbfT, v_b, msa2);

    // conv branches (must finish before gemm_proj's fused blend)
    newv_kernel<<<3136, 256, 0, stream>>>(vw, SC, newv);

    c1pre_kernel<<<3136, 256, 0, stream>>>(newv, SC, c1buf);
    bnstat_kernel<<<256, 256, 0, stream>>>(c1buf, M_PATCH*64, part);
    bnreduce_kernel<<<1, 128, 0, stream>>>(part, 256, stats);
    bnapply_kernel<<<3136, 256, 0, stream>>>(c1buf, M_PATCH*64, stats, bn1_g, bn1_b, 1.0f/12544.0f);

    c3pre_kernel<<<3136, 256, 0, stream>>>(newv, SC, c3buf);
    bnstat_kernel<<<256, 256, 0, stream>>>(c3buf, M_PATCH*64, part);
    bnreduce_kernel<<<1, 128, 0, stream>>>(part, 256, stats);
    bnapply_kernel<<<3136, 256, 0, stream>>>(c3buf, M_PATCH*64, stats, bn3_g, bn3_b, 1.0f/12544.0f);

    w13_kernel<<<192, 256, 0, stream>>>(proj_w, SC, W1, W3);

    gemm_xwt<true><<<dim3(12,196), 256, 0, stream>>>(c1buf, W1, proj_b, c1out, M_PATCH, 768, 64);
    gemm_xwt<true><<<dim3(12,196), 256, 0, stream>>>(c3buf, W3, proj_b, c3out, M_PATCH, 768, 64);

    // proj + fused blend -> out (overwrites W2a/W2b, dead since gemm_qkv)
    conv_hi<<<288, 256, 0, stream>>>(proj_w, pjw2, 73728);
    gemm_proj<<<594, 256, 0, stream>>>(msa2, (const unsigned short*)pjw2, proj_b,
                                       x, c1out, c3out, SC, out);
}

// Round 10
// 324.102 us; speedup vs baseline: 12.3280x; 1.4070x over previous
//
#include <hip/hip_runtime.h>
#include <cstdint>
#include <cstddef>

// ---------------- problem constants ----------------
#define B_    64
#define N_    197
#define DIM_  768
#define NH_   12
#define HD_   64
#define NP_   196
#define SCALE_ 0.125f
#define EPS_   1.1920929e-07f
#define BN_EPS_ 1e-5f
#define ALPHA_ 0.01f

#define M_TOK   (B_*N_)        // 12608
#define M_PATCH (B_*NP_)       // 12544
#define OUT_MAIN (M_TOK*DIM_)  // 9682944

#define K2_ 768                // single-bf16 GEMM K

// scalar workspace layout (float offsets within SC)
#define W_OFF     0
#define HP_OFF    16
#define HPROW_OFF 128
#define NVB_OFF   144
#define SVB_OFF   720
#define STATS_OFF 784          // 256 floats: sc1,off1,sc3,off3
#define WC_OFF    2048         // 768*128 combined branch weights
#define SC_FLOATS 132096

typedef short bf16x8_ __attribute__((ext_vector_type(8)));
typedef float f32x4_  __attribute__((ext_vector_type(4)));

// ---------------- prep ----------------
__global__ void prep_kernel(const float* __restrict__ uniforms, const float* __restrict__ kth,
                            const float* __restrict__ head_probs, const float* __restrict__ v_b,
                            float* __restrict__ SC, float* __restrict__ out_tail)
{
    int t = threadIdx.x;
    if (t == 0) {
        float ind[3];
        for (int i = 0; i < 3; i++) {
            float s = 1.f/(1.f + expf(-kth[i]));
            float p = fminf(fmaxf(s, EPS_), 1.f - EPS_);
            float u = fminf(fmaxf(uniforms[i], EPS_), 1.f - EPS_);
            float logit = logf(u) - log1pf(-u) + logf(p) - log1pf(-p);
            ind[i] = (logit > 0.f) ? 1.f : 0.f;
        }
        SC[W_OFF+0] = ind[2];
        SC[W_OFF+1] = ind[1]*(1.f-ind[2]);
        SC[W_OFF+2] = ind[0]*(1.f-ind[1])*(1.f-ind[2]);
        float kprod = 1.f;
        for (int i = 0; i < 3; i++) {
            float ktv = 1.f/(1.f + expf(-kth[i]));
            kprod *= (ktv > 0.5f) ? 1.f : 0.f;
            out_tail[i]   = kprod;
            out_tail[3+i] = ktv;
        }
    }
    if (t < 9) {
        float mx = -1e30f;
        for (int h = 0; h < 12; h++) mx = fmaxf(mx, head_probs[h*9+t]);
        float e[12]; float s = 0.f;
        for (int h = 0; h < 12; h++) { e[h] = expf((head_probs[h*9+t]-mx)/ALPHA_); s += e[h]; }
        for (int h = 0; h < 12; h++) SC[HP_OFF + h*9 + t] = e[h]/s;
    }
    __syncthreads();
    if (t < 12) {
        float s = 0.f;
        for (int k = 0; k < 9; k++) s += SC[HP_OFF + t*9 + k];
        SC[HPROW_OFF + t] = s;
    }
    if (t < 64) {
        float sv = 0.f;
        for (int k = 0; k < 9; k++) {
            float s = 0.f;
            for (int h = 0; h < 12; h++) s += v_b[h*64+t]*SC[HP_OFF + h*9 + k];
            SC[NVB_OFF + t*9 + k] = s;
            sv += s;
        }
        SC[SVB_OFF + t] = sv;
    }
}

// ---------------- fp32 -> bf16 (RNE) ----------------
__device__ __forceinline__ unsigned short bfr_(float f) {
    unsigned u = __float_as_uint(f);
    return (unsigned short)((u + 0x7FFFu + ((u >> 16) & 1u)) >> 16);
}
__device__ __forceinline__ float bf2f_(unsigned short u) {
    return __uint_as_float((unsigned)u << 16);
}

__global__ __launch_bounds__(256) void conv_hi(const float* __restrict__ in,
                                               unsigned int* __restrict__ out, int n8)
{
    int i = blockIdx.x*256 + threadIdx.x;
    if (i >= n8) return;
    float4 a = ((const float4*)in)[2*i];
    float4 b = ((const float4*)in)[2*i+1];
    unsigned r0 = (unsigned)bfr_(a.x) | ((unsigned)bfr_(a.y) << 16);
    unsigned r1 = (unsigned)bfr_(a.z) | ((unsigned)bfr_(a.w) << 16);
    unsigned r2 = (unsigned)bfr_(b.x) | ((unsigned)bfr_(b.y) << 16);
    unsigned r3 = (unsigned)bfr_(b.z) | ((unsigned)bfr_(b.w) << 16);
    ((uint4*)out)[i] = make_uint4(r0, r1, r2, r3);
}

// ---- global_load_lds staging (linear LDS [128][32] ushorts, XOR-swizzled src+read) ----
#define STAGE_TILE(LDSBUF, GBASE, ROWCLAMP)                                              \
    {                                                                                    \
        _Pragma("unroll")                                                                \
        for (int i_ = 0; i_ < 2; i_++) {                                                 \
            int r_ = wave*32 + i_*16 + (lane >> 2);                                      \
            int gr_ = ROWCLAMP(r_);                                                      \
            const unsigned short* gp_ = (GBASE) + (size_t)gr_*K2_ + k0                   \
                                        + (((lane & 3) ^ (r_ & 3)) * 8);                 \
            __builtin_amdgcn_global_load_lds(                                            \
                (const __attribute__((address_space(1))) unsigned int*)gp_,              \
                (__attribute__((address_space(3))) unsigned int*)&LDSBUF[(wave*32 + i_*16)*32], \
                16, 0, 0);                                                               \
        }                                                                                \
    }

// ---------------- merged qk+v GEMM (bf16 MFMA) ----------------
__global__ __launch_bounds__(256) void gemm_qkv(
    const unsigned short* __restrict__ A2, const unsigned short* __restrict__ W2,
    const float* __restrict__ qk_b,
    unsigned short* __restrict__ qkbf, unsigned short* __restrict__ vbf,
    unsigned short* __restrict__ vbfT)
{
    __shared__ unsigned short At[128*32];
    __shared__ unsigned short Bt[128*32];
    const int nwg = 1782;
    int q = nwg >> 3, rr = nwg & 7;
    int xcd = blockIdx.x & 7, idx = blockIdx.x >> 3;
    int s = (xcd < rr) ? xcd*(q+1) + idx : rr*(q+1) + (xcd - rr)*q + idx;
    const int n0 = (s % 18) * 128, m0 = (s / 18) * 128;
    const int tid = threadIdx.x;
    const int wave = tid >> 6, lane = tid & 63;
    const int wr = (wave >> 1)*64, wc = (wave & 1)*64;
    const int fr = lane & 15, fq = lane >> 4;
    const int xk = (fq ^ (fr & 3)) * 8;

    f32x4_ acc[4][4] = {};

    #define CLA_(r) ((m0 + (r) < M_TOK) ? (m0 + (r)) : (M_TOK-1))
    #define CLB_(r) (n0 + (r))
    for (int k0 = 0; k0 < K2_; k0 += 32) {
        STAGE_TILE(At, A2, CLA_)
        STAGE_TILE(Bt, W2, CLB_)
        __syncthreads();
        bf16x8_ a[4], bb[4];
        #pragma unroll
        for (int i = 0; i < 4; i++) {
            a[i]  = *(const bf16x8_*)&At[(wr + i*16 + fr)*32 + xk];
            bb[i] = *(const bf16x8_*)&Bt[(wc + i*16 + fr)*32 + xk];
        }
        #pragma unroll
        for (int mi = 0; mi < 4; mi++)
            #pragma unroll
            for (int ni = 0; ni < 4; ni++)
                acc[mi][ni] = __builtin_amdgcn_mfma_f32_16x16x32_bf16(a[mi], bb[ni], acc[mi][ni], 0, 0, 0);
        __syncthreads();
    }
    #undef CLA_
    #undef CLB_

    if (n0 < 1536) {
        float bv[4];
        #pragma unroll
        for (int ni = 0; ni < 4; ni++) bv[ni] = qk_b[n0 + wc + ni*16 + fr];
        #pragma unroll
        for (int mi = 0; mi < 4; mi++) {
            #pragma unroll
            for (int j = 0; j < 4; j++) {
                int row = m0 + wr + mi*16 + fq*4 + j;
                if (row < M_TOK) {
                    unsigned short* crow = qkbf + (size_t)row*1536 + n0 + wc;
                    #pragma unroll
                    for (int ni = 0; ni < 4; ni++)
                        crow[ni*16 + fr] = bfr_(acc[mi][ni][j] + bv[ni]);
                }
            }
        }
    } else {
        const int v0 = n0 - 1536;
        #pragma unroll
        for (int mi = 0; mi < 4; mi++) {
            #pragma unroll
            for (int j = 0; j < 4; j++) {
                int row = m0 + wr + mi*16 + fq*4 + j;
                if (row < M_TOK) {
                    int bq = row / N_;
                    int cc = row - bq*N_;
                    unsigned short* vrow = vbf + (size_t)row*768 + v0 + wc;
                    #pragma unroll
                    for (int ni = 0; ni < 4; ni++) {
                        unsigned short vb16 = bfr_(acc[mi][ni][j]);
                        int vcol = v0 + wc + ni*16 + fr;
                        vrow[ni*16 + fr] = vb16;
                        int hh = vcol >> 6, dd = vcol & 63;
                        vbfT[((size_t)(bq*NH_ + hh)*64 + dd)*224 + cc] = vb16;
                    }
                }
            }
        }
    }
}

// ---------------- proj GEMM (bf16 MFMA) + fused blend epilogue ----------------
__global__ __launch_bounds__(256) void gemm_proj(
    const unsigned short* __restrict__ A2, const unsigned short* __restrict__ W2,
    const float* __restrict__ bias,
    const float* __restrict__ x, const float* __restrict__ cb,
    const float* __restrict__ SC, float* __restrict__ out)
{
    __shared__ unsigned short At[128*32];
    __shared__ unsigned short Bt[128*32];
    const int nwg = gridDim.x;
    int q = nwg >> 3, rr = nwg & 7;
    int xcd = blockIdx.x & 7, idx = blockIdx.x >> 3;
    int s = (xcd < rr) ? xcd*(q+1) + idx : rr*(q+1) + (xcd - rr)*q + idx;
    const int n0 = (s % 6) * 128, m0 = (s / 6) * 128;
    const int tid = threadIdx.x;
    const int wave = tid >> 6, lane = tid & 63;
    const int wr = (wave >> 1)*64, wc = (wave & 1)*64;
    const int fr = lane & 15, fq = lane >> 4;
    const int xk = (fq ^ (fr & 3)) * 8;

    f32x4_ acc[4][4] = {};

    #define CLA_(r) ((m0 + (r) < M_TOK) ? (m0 + (r)) : (M_TOK-1))
    #define CLB_(r) (n0 + (r))
    for (int k0 = 0; k0 < K2_; k0 += 32) {
        STAGE_TILE(At, A2, CLA_)
        STAGE_TILE(Bt, W2, CLB_)
        __syncthreads();
        bf16x8_ a[4], bb[4];
        #pragma unroll
        for (int i = 0; i < 4; i++) {
            a[i]  = *(const bf16x8_*)&At[(wr + i*16 + fr)*32 + xk];
            bb[i] = *(const bf16x8_*)&Bt[(wc + i*16 + fr)*32 + xk];
        }
        #pragma unroll
        for (int mi = 0; mi < 4; mi++)
            #pragma unroll
            for (int ni = 0; ni < 4; ni++)
                acc[mi][ni] = __builtin_amdgcn_mfma_f32_16x16x32_bf16(a[mi], bb[ni], acc[mi][ni], 0, 0, 0);
        __syncthreads();
    }
    #undef CLA_
    #undef CLB_

    const float w0 = SC[0], w12 = SC[1] + SC[2];
    float bv[4];
    #pragma unroll
    for (int ni = 0; ni < 4; ni++) bv[ni] = bias[n0 + wc + ni*16 + fr];
    #pragma unroll
    for (int mi = 0; mi < 4; mi++) {
        #pragma unroll
        for (int j = 0; j < 4; j++) {
            int row = m0 + wr + mi*16 + fq*4 + j;
            if (row < M_TOK) {
                int b = row / N_;
                int n = row - b*N_;
                float* orow = out + (size_t)row*768 + n0 + wc;
                if (n == 0) {
                    const float* xr = x + (size_t)row*768 + n0 + wc;
                    #pragma unroll
                    for (int ni = 0; ni < 4; ni++) {
                        float m = acc[mi][ni][j] + bv[ni];
                        orow[ni*16 + fr] = w0*m + w12*xr[ni*16 + fr];
                    }
                } else {
                    size_t qb = ((size_t)(row - b - 1))*768 + n0 + wc;
                    #pragma unroll
                    for (int ni = 0; ni < 4; ni++) {
                        float m = acc[mi][ni][j] + bv[ni];
                        orow[ni*16 + fr] = w0*m + cb[qb + ni*16 + fr];
                    }
                }
            }
        }
    }
}

// ---------------- fused flash attention (bf16 MFMA) ----------------
__global__ __launch_bounds__(256) void flash_attn(
    const unsigned short* __restrict__ qkbf,
    const unsigned short* __restrict__ vbfT,
    const float* __restrict__ v_b,
    unsigned short* __restrict__ msa2)
{
    __shared__ unsigned short Kb[224][64];
    __shared__ unsigned short Vt[64][256];
    const int bh = blockIdx.x;
    const int b = bh / NH_, h = bh % NH_;
    const int tid = threadIdx.x;
    const int wv = tid >> 6, lane = tid & 63;
    const int fr = lane & 15, fq = lane >> 4;

    {
        const unsigned short* Kg = qkbf + (size_t)(b*N_)*1536 + 768 + h*64;
        int r = tid >> 3; const int ch = tid & 7;
        #pragma unroll
        for (int rnd = 0; rnd < 7; rnd++, r += 32) {
            uint4 val = make_uint4(0u,0u,0u,0u);
            if (r < N_) val = *(const uint4*)(Kg + (size_t)r*1536 + ch*8);
            *(uint4*)&Kb[r][(ch ^ (r & 7))*8] = val;
        }
    }
    {
        const unsigned short* Vg = vbfT + (size_t)bh*(64*224);
        #pragma unroll
        for (int rnd = 0; rnd < 8; rnd++) {
            int job = rnd*256 + tid;
            int d = job >> 5, ch = job & 31;
            uint4 val = make_uint4(0u,0u,0u,0u);
            if (ch < 24) val = *(const uint4*)(Vg + (size_t)d*224 + ch*8);
            else if (ch == 24) {
                val = *(const uint4*)(Vg + (size_t)d*224 + 192);
                val.z &= 0xFFFFu; val.w = 0u;
            }
            *(uint4*)&Vt[d][(ch ^ (d & 7))*8] = val;
        }
    }
    bf16x8_ qf[4][2];
    #pragma unroll
    for (int nf = 0; nf < 4; nf++) {
        int qr = wv*64 + nf*16 + fr; if (qr > N_-1) qr = N_-1;
        const unsigned short* Qg = qkbf + (size_t)(b*N_ + qr)*1536 + h*64;
        qf[nf][0] = *(const bf16x8_*)(Qg + fq*8);
        qf[nf][1] = *(const bf16x8_*)(Qg + 32 + fq*8);
    }
    __syncthreads();

    f32x4_ o[4][4];
    #pragma unroll
    for (int i = 0; i < 4; i++)
        #pragma unroll
        for (int j2 = 0; j2 < 4; j2++) { o[i][j2][0]=0.f; o[i][j2][1]=0.f; o[i][j2][2]=0.f; o[i][j2][3]=0.f; }
    float m_[4] = {-1e30f,-1e30f,-1e30f,-1e30f};
    float l_[4] = {0.f,0.f,0.f,0.f};

    for (int t = 0; t < 14; t++) {
        const int krow = t*16 + fr;
        bf16x8_ kf0 = *(const bf16x8_*)&Kb[krow][( fq      ^ (fr & 7))*8];
        bf16x8_ kf1 = *(const bf16x8_*)&Kb[krow][((fq + 4) ^ (fr & 7))*8];
        f32x4_ st[4];
        #pragma unroll
        for (int nf = 0; nf < 4; nf++) {
            f32x4_ z = {0.f,0.f,0.f,0.f};
            z = __builtin_amdgcn_mfma_f32_16x16x32_bf16(kf0, qf[nf][0], z, 0,0,0);
            z = __builtin_amdgcn_mfma_f32_16x16x32_bf16(kf1, qf[nf][1], z, 0,0,0);
            st[nf] = z;
        }
        const int cbase = t*16 + fq*4;
        float p[4][4];
        #pragma unroll
        for (int nf = 0; nf < 4; nf++) {
            #pragma unroll
            for (int jj = 0; jj < 4; jj++)
                st[nf][jj] = (cbase + jj < N_) ? st[nf][jj]*SCALE_ : -1e30f;
            float tm = fmaxf(fmaxf(st[nf][0],st[nf][1]), fmaxf(st[nf][2],st[nf][3]));
            tm = fmaxf(tm, __shfl_xor(tm, 16));
            tm = fmaxf(tm, __shfl_xor(tm, 32));
            float mn = fmaxf(m_[nf], tm);
            float sc = __expf(m_[nf] - mn);
            float ps = 0.f;
            #pragma unroll
            for (int jj = 0; jj < 4; jj++) {
                float e = __expf(st[nf][jj] - mn);
                p[nf][jj] = e; ps += e;
            }
            ps += __shfl_xor(ps, 16);
            ps += __shfl_xor(ps, 32);
            l_[nf] = l_[nf]*sc + ps;
            m_[nf] = mn;
            #pragma unroll
            for (int df = 0; df < 4; df++) {
                o[df][nf][0]*=sc; o[df][nf][1]*=sc; o[df][nf][2]*=sc; o[df][nf][3]*=sc;
            }
        }
        bf16x8_ pa[4];
        const bool half = (fq < 2);
        #pragma unroll
        for (int nf = 0; nf < 4; nf++) {
            #pragma unroll
            for (int tt = 0; tt < 8; tt++) {
                int src = fr + 16*((fq & 1)*2 + (tt >> 2));
                float v = __shfl(p[nf][tt & 3], src);
                pa[nf][tt] = half ? (short)bfr_(v) : (short)0;
            }
        }
        #pragma unroll
        for (int df = 0; df < 4; df++) {
            bf16x8_ vf = *(const bf16x8_*)&Vt[df*16 + fr][((t*2 + fq) ^ (fr & 7))*8];
            #pragma unroll
            for (int nf = 0; nf < 4; nf++)
                o[df][nf] = __builtin_amdgcn_mfma_f32_16x16x32_bf16(vf, pa[nf], o[df][nf], 0,0,0);
        }
    }
    #pragma unroll
    for (int nf = 0; nf < 4; nf++) {
        int qr = wv*64 + nf*16 + fr;
        if (qr >= N_) continue;
        float inv = 1.f / l_[nf];
        unsigned short* orow = msa2 + (size_t)(b*N_ + qr)*768 + h*64;
        #pragma unroll
        for (int df = 0; df < 4; df++) {
            const float4 vb4 = *(const float4*)&v_b[h*64 + df*16 + fq*4];
            unsigned u0 = (unsigned)bfr_(o[df][nf][0]*inv + vb4.x)
                        | ((unsigned)bfr_(o[df][nf][1]*inv + vb4.y) << 16);
            unsigned u1 = (unsigned)bfr_(o[df][nf][2]*inv + vb4.z)
                        | ((unsigned)bfr_(o[df][nf][3]*inv + vb4.w) << 16);
            uint2 w; w.x = u0; w.y = u1;
            *(uint2*)(orow + df*16 + fq*4) = w;
        }
    }
}

// ---------------- new_v (bf16 input) ----------------
__global__ __launch_bounds__(256) void newv_kernel(
    const unsigned short* __restrict__ vbf, const float* __restrict__ SC, float* __restrict__ newv)
{
    int idx = blockIdx.x*256 + threadIdx.x;
    if (idx >= M_PATCH*64) return;
    int d = idx & 63; int bp = idx >> 6;
    int p = bp % NP_, b = bp / NP_;
    const unsigned short* src = vbf + (size_t)(b*N_ + 1 + p)*768 + d;
    float vh[12];
    #pragma unroll
    for (int h = 0; h < 12; h++) vh[h] = bf2f_(src[h*64]);
    #pragma unroll
    for (int k = 0; k < 9; k++) {
        float s = 0.f;
        #pragma unroll
        for (int h = 0; h < 12; h++) s += vh[h]*SC[HP_OFF + h*9 + k];
        newv[((size_t)bp*9 + k)*64 + d] = s;
    }
}

// ---------------- fused c1pre + c3pre + BN partial stats ----------------
__global__ __launch_bounds__(256) void fuse13_kernel(
    const float* __restrict__ newv, const float* __restrict__ SC,
    float* __restrict__ c1buf, float* __restrict__ c3buf, float* __restrict__ part)
{
    __shared__ float sd1[256], sq1[256], sd3[256], sq3[256];
    int tid = threadIdx.x;
    float s1 = 0.f, q1 = 0.f, s3 = 0.f, q3 = 0.f;
    for (int i = blockIdx.x*256 + tid; i < M_PATCH*64; i += 65536) {
        int d = i & 63; int bij = i >> 6;
        int j = bij % 14; int bi = bij / 14; int irow = bi % 14; int b = bi / 14;
        float c1v = newv[((size_t)bij*9 + 4)*64 + d] + SC[NVB_OFF + d*9 + 4];
        float c3v = SC[SVB_OFF + d];
        #pragma unroll
        for (int p = 0; p < 9; p++) {
            int h1 = p % 3, h2 = p / 3;
            int y = irow + h1 - 1, xx = j + h2 - 1;
            if (y >= 0 && y < 14 && xx >= 0 && xx < 14)
                c3v += newv[(((size_t)b*NP_ + y*14 + xx)*9 + p)*64 + d];
        }
        c1buf[i] = c1v; c3buf[i] = c3v;
        s1 += c1v; q1 += c1v*c1v; s3 += c3v; q3 += c3v*c3v;
    }
    sd1[tid] = s1; sq1[tid] = q1; sd3[tid] = s3; sq3[tid] = q3;
    __syncthreads();
    if (tid < 64) {
        part[blockIdx.x*256 + tid]       = sd1[tid]+sd1[tid+64]+sd1[tid+128]+sd1[tid+192];
        part[blockIdx.x*256 + 64 + tid]  = sq1[tid]+sq1[tid+64]+sq1[tid+128]+sq1[tid+192];
        part[blockIdx.x*256 + 128 + tid] = sd3[tid]+sd3[tid+64]+sd3[tid+128]+sd3[tid+192];
        part[blockIdx.x*256 + 192 + tid] = sq3[tid]+sq3[tid+64]+sq3[tid+128]+sq3[tid+192];
    }
}

// ---------------- reduce both BN stats -> scale/offset pairs ----------------
__global__ void bnreduce2_kernel(const float* __restrict__ part,
                                 const float* __restrict__ g1, const float* __restrict__ b1,
                                 const float* __restrict__ g3, const float* __restrict__ b3,
                                 float* __restrict__ stats)
{
    __shared__ float red[256];
    int t = threadIdx.x;  // 256
    float s = 0.f;
    for (int i = 0; i < 256; i++) s += part[i*256 + t];
    red[t] = s;
    __syncthreads();
    const float invN = 1.0f/12544.0f;
    if (t < 64) {
        float mean = red[t]*invN;
        float var  = red[64+t]*invN - mean*mean;
        float sc = rsqrtf(var + BN_EPS_) * g1[t];
        stats[t]      = sc;
        stats[64+t]   = b1[t] - mean*sc;
    } else if (t < 128) {
        int d = t - 64;
        float mean = red[128+d]*invN;
        float var  = red[192+d]*invN - mean*mean;
        float sc = rsqrtf(var + BN_EPS_) * g3[d];
        stats[128+d]  = sc;
        stats[192+d]  = b3[d] - mean*sc;
    }
}

// ---------------- combined branch weights: Wc[c][0:64]=w2*W1, [64:128]=w1*W3 ----------------
__global__ __launch_bounds__(256) void w13_kernel(
    const float* __restrict__ proj_w, const float* __restrict__ SC, float* __restrict__ Wc)
{
    int idx = blockIdx.x*256 + threadIdx.x;
    if (idx >= 768*128) return;
    int d2 = idx & 127, c = idx >> 7;
    float s = 0.f;
    if (d2 < 64) {
        #pragma unroll
        for (int h = 0; h < 12; h++)
            s += proj_w[(size_t)c*768 + h*64 + d2] * SC[HP_OFF + h*9 + 4];
        s *= SC[2];   // w2 * W1
    } else {
        int dd = d2 - 64;
        #pragma unroll
        for (int h = 0; h < 12; h++)
            s += proj_w[(size_t)c*768 + h*64 + dd] * SC[HPROW_OFF + h];
        s *= SC[1];   // w1 * W3
    }
    Wc[idx] = s;
}

// ---------------- combined c1/c3 GEMM with inline BN+relu; outputs blended contribution ----
__global__ __launch_bounds__(256) void gemm_c13(
    const float* __restrict__ c1buf, const float* __restrict__ c3buf,
    const float* __restrict__ stats, const float* __restrict__ Wc,
    const float* __restrict__ proj_b, const float* __restrict__ SC,
    float* __restrict__ cblend)
{
    __shared__ float As[16][68];
    __shared__ float Bs[16][68];
    __shared__ float st[256];
    const int tid = threadIdx.x;
    const int tx = tid & 15, ty = tid >> 4;
    const int m0 = blockIdx.y * 64, n0 = blockIdx.x * 64;
    st[tid] = stats[tid];
    __syncthreads();
    float acc[4][4] = {};
    for (int k0 = 0; k0 < 128; k0 += 16) {
        int k = k0 + tx;
        #pragma unroll
        for (int i = 0; i < 4; i++) {
            int r = ty + i*16;
            float a;
            if (k < 64) {
                float v = c1buf[(size_t)(m0 + r)*64 + k];
                a = fmaxf(v*st[k] + st[64+k], 0.f);
            } else {
                int kk = k - 64;
                float v = c3buf[(size_t)(m0 + r)*64 + kk];
                a = fmaxf(v*st[128+kk] + st[192+kk], 0.f);
            }
            As[tx][r] = a;
            Bs[tx][r] = Wc[(size_t)(n0 + r)*128 + k];
        }
        __syncthreads();
        #pragma unroll
        for (int kk = 0; kk < 16; kk++) {
            const float4 a4 = *(const float4*)&As[kk][ty*4];
            const float4 b4 = *(const float4*)&Bs[kk][tx*4];
            const float a[4] = {a4.x, a4.y, a4.z, a4.w};
            const float b[4] = {b4.x, b4.y, b4.z, b4.w};
            #pragma unroll
            for (int i = 0; i < 4; i++)
                #pragma unroll
                for (int j = 0; j < 4; j++)
                    acc[i][j] += a[i]*b[j];
        }
        __syncthreads();
    }
    const float w12 = SC[1] + SC[2];
    const float4 pb4 = *(const float4*)&proj_b[n0 + tx*4];
    float4 bv = make_float4(w12*pb4.x, w12*pb4.y, w12*pb4.z, w12*pb4.w);
    #pragma unroll
    for (int i = 0; i < 4; i++) {
        int m = m0 + ty*4 + i;
        float4 o = make_float4(acc[i][0]+bv.x, acc[i][1]+bv.y, acc[i][2]+bv.z, acc[i][3]+bv.w);
        *(float4*)&cblend[(size_t)m*768 + n0 + tx*4] = o;
    }
}

// ---------------- launch ----------------
extern "C" void kernel_launch(void* const* d_in, const int* in_sizes, int n_in,
                              void* d_out, int out_size, void* d_ws, size_t ws_size,
                              hipStream_t stream)
{
    const float* x        = (const float*)d_in[0];
    const float* uniforms = (const float*)d_in[1];
    const float* qk_w     = (const float*)d_in[2];
    const float* qk_b     = (const float*)d_in[3];
    const float* v_w      = (const float*)d_in[4];
    const float* v_b      = (const float*)d_in[5];
    const float* proj_w   = (const float*)d_in[6];
    const float* proj_b   = (const float*)d_in[7];
    const float* bn1_g    = (const float*)d_in[8];
    const float* bn1_b    = (const float*)d_in[9];
    const float* bn3_g    = (const float*)d_in[10];
    const float* bn3_b    = (const float*)d_in[11];
    const float* kth      = (const float*)d_in[12];
    const float* head_probs = (const float*)d_in[13];
    float* out = (float*)d_out;

    // ws regions; every alias written-in-full (or written-then-read) in order each call
    float* ws = (float*)d_ws;
    float* R1 = ws;                     // 19,365,888 floats
    float* R2 = ws + 19365888;          //  9,682,944 floats
    float* R3 = ws + 29048832;          //  9,682,944 floats
    float* SC = ws + 38731776;          //    132,096 floats
    // R1: qkbf bf16 (floats [0,9682944)) + vbfT bf16 (floats [9682944,15187968)) -> flash;
    //     then newv [0,7225344) (after flash); then cblend [0,9633792) (after fuse13).
    unsigned short* qkbf = (unsigned short*)R1;
    unsigned short* vbfT = (unsigned short*)R1 + 19365888;
    float* newv   = R1;
    float* cblend = R1;
    // R2: vbf bf16 (floats [0,4841472)) -> newv; then c1buf/c3buf (after newv).
    unsigned short* vbf = (unsigned short*)R2;
    float* c1buf = R2;
    float* c3buf = R2 + 802816;
    // R3: x2 bf16 [0,4841472) -> msa2 bf16 (same); part at +5000000; pjw2 at +6000000.
    unsigned int*   x2   = (unsigned int*)R3;
    unsigned short* msa2 = (unsigned short*)R3;
    float* part = R3 + 5000000;
    unsigned int* pjw2 = (unsigned int*)(R3 + 6000000);
    // d_out: W2a/W2b bf16 weights (dead after gemm_qkv) -> final out.
    unsigned int* W2a = (unsigned int*)out;
    unsigned int* W2b = (unsigned int*)out + 589824;
    float* stats = SC + STATS_OFF;
    float* Wc    = SC + WC_OFF;

    prep_kernel<<<1, 256, 0, stream>>>(uniforms, kth, head_probs, v_b, SC, out + OUT_MAIN);

    conv_hi<<<4728, 256, 0, stream>>>(x, x2, 1210368);
    conv_hi<<<576, 256, 0, stream>>>(qk_w, W2a, 147456);
    conv_hi<<<288, 256, 0, stream>>>(v_w, W2b, 73728);

    gemm_qkv<<<1782, 256, 0, stream>>>((const unsigned short*)x2,
                                       (const unsigned short*)W2a, qk_b,
                                       qkbf, vbf, (unsigned short*)vbfT);

    flash_attn<<<768, 256, 0, stream>>>(qkbf, (const unsigned short*)vbfT, v_b, msa2);

    // conv branch chain (consolidated)
    newv_kernel<<<3136, 256, 0, stream>>>(vbf, SC, newv);
    fuse13_kernel<<<256, 256, 0, stream>>>(newv, SC, c1buf, c3buf, part);
    bnreduce2_kernel<<<1, 256, 0, stream>>>(part, bn1_g, bn1_b, bn3_g, bn3_b, stats);
    w13_kernel<<<384, 256, 0, stream>>>(proj_w, SC, Wc);
    gemm_c13<<<dim3(12,196), 256, 0, stream>>>(c1buf, c3buf, stats, Wc, proj_b, SC, cblend);

    // proj + fused blend -> out
    conv_hi<<<288, 256, 0, stream>>>(proj_w, pjw2, 73728);
    gemm_proj<<<594, 256, 0, stream>>>(msa2, (const unsigned short*)pjw2, proj_b,
                                       x, cblend, SC, out);
}

// Round 11
// 323.161 us; speedup vs baseline: 12.3639x; 1.0029x over previous
//
#include <hip/hip_runtime.h>
#include <cstdint>
#include <cstddef>

// ---------------- problem constants ----------------
#define B_    64
#define N_    197
#define DIM_  768
#define NH_   12
#define HD_   64
#define NP_   196
#define SCALE_ 0.125f
#define EPS_   1.1920929e-07f
#define BN_EPS_ 1e-5f
#define ALPHA_ 0.01f

#define M_TOK   (B_*N_)        // 12608
#define M_PATCH (B_*NP_)       // 12544
#define OUT_MAIN (M_TOK*DIM_)  // 9682944

#define K2_ 768                // single-bf16 GEMM K
#define NT_ 24                 // K2_/32 K-steps

// scalar workspace layout (float offsets within SC)
#define W_OFF     0
#define HP_OFF    16
#define HPROW_OFF 128
#define NVB_OFF   144
#define SVB_OFF   720
#define STATS_OFF 784          // 256 floats: sc1,off1,sc3,off3
#define WC_OFF    2048         // 768*128 combined branch weights
#define SC_FLOATS 132096

typedef short bf16x8_ __attribute__((ext_vector_type(8)));
typedef float f32x4_  __attribute__((ext_vector_type(4)));

// ---------------- prep ----------------
__global__ void prep_kernel(const float* __restrict__ uniforms, const float* __restrict__ kth,
                            const float* __restrict__ head_probs, const float* __restrict__ v_b,
                            float* __restrict__ SC, float* __restrict__ out_tail)
{
    int t = threadIdx.x;
    if (t == 0) {
        float ind[3];
        for (int i = 0; i < 3; i++) {
            float s = 1.f/(1.f + expf(-kth[i]));
            float p = fminf(fmaxf(s, EPS_), 1.f - EPS_);
            float u = fminf(fmaxf(uniforms[i], EPS_), 1.f - EPS_);
            float logit = logf(u) - log1pf(-u) + logf(p) - log1pf(-p);
            ind[i] = (logit > 0.f) ? 1.f : 0.f;
        }
        SC[W_OFF+0] = ind[2];
        SC[W_OFF+1] = ind[1]*(1.f-ind[2]);
        SC[W_OFF+2] = ind[0]*(1.f-ind[1])*(1.f-ind[2]);
        float kprod = 1.f;
        for (int i = 0; i < 3; i++) {
            float ktv = 1.f/(1.f + expf(-kth[i]));
            kprod *= (ktv > 0.5f) ? 1.f : 0.f;
            out_tail[i]   = kprod;
            out_tail[3+i] = ktv;
        }
    }
    if (t < 9) {
        float mx = -1e30f;
        for (int h = 0; h < 12; h++) mx = fmaxf(mx, head_probs[h*9+t]);
        float e[12]; float s = 0.f;
        for (int h = 0; h < 12; h++) { e[h] = expf((head_probs[h*9+t]-mx)/ALPHA_); s += e[h]; }
        for (int h = 0; h < 12; h++) SC[HP_OFF + h*9 + t] = e[h]/s;
    }
    __syncthreads();
    if (t < 12) {
        float s = 0.f;
        for (int k = 0; k < 9; k++) s += SC[HP_OFF + t*9 + k];
        SC[HPROW_OFF + t] = s;
    }
    if (t < 64) {
        float sv = 0.f;
        for (int k = 0; k < 9; k++) {
            float s = 0.f;
            for (int h = 0; h < 12; h++) s += v_b[h*64+t]*SC[HP_OFF + h*9 + k];
            SC[NVB_OFF + t*9 + k] = s;
            sv += s;
        }
        SC[SVB_OFF + t] = sv;
    }
}

// ---------------- fp32 -> bf16 (RNE) ----------------
__device__ __forceinline__ unsigned short bfr_(float f) {
    unsigned u = __float_as_uint(f);
    return (unsigned short)((u + 0x7FFFu + ((u >> 16) & 1u)) >> 16);
}
__device__ __forceinline__ float bf2f_(unsigned short u) {
    return __uint_as_float((unsigned)u << 16);
}

__global__ __launch_bounds__(256) void conv_hi(const float* __restrict__ in,
                                               unsigned int* __restrict__ out, int n8)
{
    int i = blockIdx.x*256 + threadIdx.x;
    if (i >= n8) return;
    float4 a = ((const float4*)in)[2*i];
    float4 b = ((const float4*)in)[2*i+1];
    unsigned r0 = (unsigned)bfr_(a.x) | ((unsigned)bfr_(a.y) << 16);
    unsigned r1 = (unsigned)bfr_(a.z) | ((unsigned)bfr_(a.w) << 16);
    unsigned r2 = (unsigned)bfr_(b.x) | ((unsigned)bfr_(b.y) << 16);
    unsigned r3 = (unsigned)bfr_(b.z) | ((unsigned)bfr_(b.w) << 16);
    ((uint4*)out)[i] = make_uint4(r0, r1, r2, r3);
}

// ---- global_load_lds staging into a given LDS buffer (linear [128][32] ushorts) ----
// LDS slot (row r, chunk c=lane&3) receives global k-chunk (c ^ (r&3)); read XORs back.
#define STAGE_TILE2(LDSPTR, GBASE, ROWCLAMP, KOFF)                                       \
    {                                                                                    \
        _Pragma("unroll")                                                                \
        for (int i_ = 0; i_ < 2; i_++) {                                                 \
            int r_ = wave*32 + i_*16 + (lane >> 2);                                      \
            int gr_ = ROWCLAMP(r_);                                                      \
            const unsigned short* gp_ = (GBASE) + (size_t)gr_*K2_ + (KOFF)               \
                                        + (((lane & 3) ^ (r_ & 3)) * 8);                 \
            __builtin_amdgcn_global_load_lds(                                            \
                (const __attribute__((address_space(1))) unsigned int*)gp_,              \
                (__attribute__((address_space(3))) unsigned int*)&(LDSPTR)[(wave*32 + i_*16)*32], \
                16, 0, 0);                                                               \
        }                                                                                \
    }

// ---------------- merged qk+v GEMM (bf16 MFMA, 2-phase dbuf pipeline) ----------------
__global__ __launch_bounds__(256) void gemm_qkv(
    const unsigned short* __restrict__ A2, const unsigned short* __restrict__ W2,
    const float* __restrict__ qk_b,
    unsigned short* __restrict__ qkbf, unsigned short* __restrict__ vbf,
    unsigned short* __restrict__ vbfT)
{
    __shared__ unsigned short At[2][128*32];
    __shared__ unsigned short Bt[2][128*32];
    const int nwg = 1782;
    int q = nwg >> 3, rr = nwg & 7;
    int xcd = blockIdx.x & 7, idx = blockIdx.x >> 3;
    int s = (xcd < rr) ? xcd*(q+1) + idx : rr*(q+1) + (xcd - rr)*q + idx;
    const int n0 = (s % 18) * 128, m0 = (s / 18) * 128;
    const int tid = threadIdx.x;
    const int wave = tid >> 6, lane = tid & 63;
    const int wr = (wave >> 1)*64, wc = (wave & 1)*64;
    const int fr = lane & 15, fq = lane >> 4;
    const int xk = (fq ^ (fr & 3)) * 8;

    f32x4_ acc[4][4] = {};

    #define CLA_(r) ((m0 + (r) < M_TOK) ? (m0 + (r)) : (M_TOK-1))
    #define CLB_(r) (n0 + (r))
    STAGE_TILE2(At[0], A2, CLA_, 0)
    STAGE_TILE2(Bt[0], W2, CLB_, 0)
    __syncthreads();
    for (int kt = 0; kt < NT_; kt++) {
        const int cur = kt & 1;
        if (kt + 1 < NT_) {
            STAGE_TILE2(At[cur^1], A2, CLA_, (kt+1)*32)
            STAGE_TILE2(Bt[cur^1], W2, CLB_, (kt+1)*32)
        }
        bf16x8_ a[4], bb[4];
        #pragma unroll
        for (int i = 0; i < 4; i++) {
            a[i]  = *(const bf16x8_*)&At[cur][(wr + i*16 + fr)*32 + xk];
            bb[i] = *(const bf16x8_*)&Bt[cur][(wc + i*16 + fr)*32 + xk];
        }
        #pragma unroll
        for (int mi = 0; mi < 4; mi++)
            #pragma unroll
            for (int ni = 0; ni < 4; ni++)
                acc[mi][ni] = __builtin_amdgcn_mfma_f32_16x16x32_bf16(a[mi], bb[ni], acc[mi][ni], 0, 0, 0);
        __syncthreads();
    }
    #undef CLA_
    #undef CLB_

    if (n0 < 1536) {
        float bv[4];
        #pragma unroll
        for (int ni = 0; ni < 4; ni++) bv[ni] = qk_b[n0 + wc + ni*16 + fr];
        #pragma unroll
        for (int mi = 0; mi < 4; mi++) {
            #pragma unroll
            for (int j = 0; j < 4; j++) {
                int row = m0 + wr + mi*16 + fq*4 + j;
                if (row < M_TOK) {
                    unsigned short* crow = qkbf + (size_t)row*1536 + n0 + wc;
                    #pragma unroll
                    for (int ni = 0; ni < 4; ni++)
                        crow[ni*16 + fr] = bfr_(acc[mi][ni][j] + bv[ni]);
                }
            }
        }
    } else {
        const int v0 = n0 - 1536;
        #pragma unroll
        for (int mi = 0; mi < 4; mi++) {
            #pragma unroll
            for (int j = 0; j < 4; j++) {
                int row = m0 + wr + mi*16 + fq*4 + j;
                if (row < M_TOK) {
                    int bq = row / N_;
                    int cc = row - bq*N_;
                    unsigned short* vrow = vbf + (size_t)row*768 + v0 + wc;
                    #pragma unroll
                    for (int ni = 0; ni < 4; ni++) {
                        unsigned short vb16 = bfr_(acc[mi][ni][j]);
                        int vcol = v0 + wc + ni*16 + fr;
                        vrow[ni*16 + fr] = vb16;
                        int hh = vcol >> 6, dd = vcol & 63;
                        vbfT[((size_t)(bq*NH_ + hh)*64 + dd)*224 + cc] = vb16;
                    }
                }
            }
        }
    }
}

// ---------------- proj GEMM (bf16 MFMA, 2-phase dbuf) + fused blend epilogue ----------------
__global__ __launch_bounds__(256) void gemm_proj(
    const unsigned short* __restrict__ A2, const unsigned short* __restrict__ W2,
    const float* __restrict__ bias,
    const float* __restrict__ x, const float* __restrict__ cb,
    const float* __restrict__ SC, float* __restrict__ out)
{
    __shared__ unsigned short At[2][128*32];
    __shared__ unsigned short Bt[2][128*32];
    const int nwg = gridDim.x;
    int q = nwg >> 3, rr = nwg & 7;
    int xcd = blockIdx.x & 7, idx = blockIdx.x >> 3;
    int s = (xcd < rr) ? xcd*(q+1) + idx : rr*(q+1) + (xcd - rr)*q + idx;
    const int n0 = (s % 6) * 128, m0 = (s / 6) * 128;
    const int tid = threadIdx.x;
    const int wave = tid >> 6, lane = tid & 63;
    const int wr = (wave >> 1)*64, wc = (wave & 1)*64;
    const int fr = lane & 15, fq = lane >> 4;
    const int xk = (fq ^ (fr & 3)) * 8;

    f32x4_ acc[4][4] = {};

    #define CLA_(r) ((m0 + (r) < M_TOK) ? (m0 + (r)) : (M_TOK-1))
    #define CLB_(r) (n0 + (r))
    STAGE_TILE2(At[0], A2, CLA_, 0)
    STAGE_TILE2(Bt[0], W2, CLB_, 0)
    __syncthreads();
    for (int kt = 0; kt < NT_; kt++) {
        const int cur = kt & 1;
        if (kt + 1 < NT_) {
            STAGE_TILE2(At[cur^1], A2, CLA_, (kt+1)*32)
            STAGE_TILE2(Bt[cur^1], W2, CLB_, (kt+1)*32)
        }
        bf16x8_ a[4], bb[4];
        #pragma unroll
        for (int i = 0; i < 4; i++) {
            a[i]  = *(const bf16x8_*)&At[cur][(wr + i*16 + fr)*32 + xk];
            bb[i] = *(const bf16x8_*)&Bt[cur][(wc + i*16 + fr)*32 + xk];
        }
        #pragma unroll
        for (int mi = 0; mi < 4; mi++)
            #pragma unroll
            for (int ni = 0; ni < 4; ni++)
                acc[mi][ni] = __builtin_amdgcn_mfma_f32_16x16x32_bf16(a[mi], bb[ni], acc[mi][ni], 0, 0, 0);
        __syncthreads();
    }
    #undef CLA_
    #undef CLB_

    const float w0 = SC[0], w12 = SC[1] + SC[2];
    float bv[4];
    #pragma unroll
    for (int ni = 0; ni < 4; ni++) bv[ni] = bias[n0 + wc + ni*16 + fr];
    #pragma unroll
    for (int mi = 0; mi < 4; mi++) {
        #pragma unroll
        for (int j = 0; j < 4; j++) {
            int row = m0 + wr + mi*16 + fq*4 + j;
            if (row < M_TOK) {
                int b = row / N_;
                int n = row - b*N_;
                float* orow = out + (size_t)row*768 + n0 + wc;
                if (n == 0) {
                    const float* xr = x + (size_t)row*768 + n0 + wc;
                    #pragma unroll
                    for (int ni = 0; ni < 4; ni++) {
                        float m = acc[mi][ni][j] + bv[ni];
                        orow[ni*16 + fr] = w0*m + w12*xr[ni*16 + fr];
                    }
                } else {
                    size_t qb = ((size_t)(row - b - 1))*768 + n0 + wc;
                    #pragma unroll
                    for (int ni = 0; ni < 4; ni++) {
                        float m = acc[mi][ni][j] + bv[ni];
                        orow[ni*16 + fr] = w0*m + cb[qb + ni*16 + fr];
                    }
                }
            }
        }
    }
}

// ---------------- fused flash attention (bf16 MFMA) ----------------
__global__ __launch_bounds__(256) void flash_attn(
    const unsigned short* __restrict__ qkbf,
    const unsigned short* __restrict__ vbfT,
    const float* __restrict__ v_b,
    unsigned short* __restrict__ msa2)
{
    __shared__ unsigned short Kb[224][64];
    __shared__ unsigned short Vt[64][256];
    const int bh = blockIdx.x;
    const int b = bh / NH_, h = bh % NH_;
    const int tid = threadIdx.x;
    const int wv = tid >> 6, lane = tid & 63;
    const int fr = lane & 15, fq = lane >> 4;

    {
        const unsigned short* Kg = qkbf + (size_t)(b*N_)*1536 + 768 + h*64;
        int r = tid >> 3; const int ch = tid & 7;
        #pragma unroll
        for (int rnd = 0; rnd < 7; rnd++, r += 32) {
            uint4 val = make_uint4(0u,0u,0u,0u);
            if (r < N_) val = *(const uint4*)(Kg + (size_t)r*1536 + ch*8);
            *(uint4*)&Kb[r][(ch ^ (r & 7))*8] = val;
        }
    }
    {
        const unsigned short* Vg = vbfT + (size_t)bh*(64*224);
        #pragma unroll
        for (int rnd = 0; rnd < 8; rnd++) {
            int job = rnd*256 + tid;
            int d = job >> 5, ch = job & 31;
            uint4 val = make_uint4(0u,0u,0u,0u);
            if (ch < 24) val = *(const uint4*)(Vg + (size_t)d*224 + ch*8);
            else if (ch == 24) {
                val = *(const uint4*)(Vg + (size_t)d*224 + 192);
                val.z &= 0xFFFFu; val.w = 0u;
            }
            *(uint4*)&Vt[d][(ch ^ (d & 7))*8] = val;
        }
    }
    bf16x8_ qf[4][2];
    #pragma unroll
    for (int nf = 0; nf < 4; nf++) {
        int qr = wv*64 + nf*16 + fr; if (qr > N_-1) qr = N_-1;
        const unsigned short* Qg = qkbf + (size_t)(b*N_ + qr)*1536 + h*64;
        qf[nf][0] = *(const bf16x8_*)(Qg + fq*8);
        qf[nf][1] = *(const bf16x8_*)(Qg + 32 + fq*8);
    }
    __syncthreads();

    f32x4_ o[4][4];
    #pragma unroll
    for (int i = 0; i < 4; i++)
        #pragma unroll
        for (int j2 = 0; j2 < 4; j2++) { o[i][j2][0]=0.f; o[i][j2][1]=0.f; o[i][j2][2]=0.f; o[i][j2][3]=0.f; }
    float m_[4] = {-1e30f,-1e30f,-1e30f,-1e30f};
    float l_[4] = {0.f,0.f,0.f,0.f};

    for (int t = 0; t < 14; t++) {
        const int krow = t*16 + fr;
        bf16x8_ kf0 = *(const bf16x8_*)&Kb[krow][( fq      ^ (fr & 7))*8];
        bf16x8_ kf1 = *(const bf16x8_*)&Kb[krow][((fq + 4) ^ (fr & 7))*8];
        f32x4_ st[4];
        #pragma unroll
        for (int nf = 0; nf < 4; nf++) {
            f32x4_ z = {0.f,0.f,0.f,0.f};
            z = __builtin_amdgcn_mfma_f32_16x16x32_bf16(kf0, qf[nf][0], z, 0,0,0);
            z = __builtin_amdgcn_mfma_f32_16x16x32_bf16(kf1, qf[nf][1], z, 0,0,0);
            st[nf] = z;
        }
        const int cbase = t*16 + fq*4;
        float p[4][4];
        #pragma unroll
        for (int nf = 0; nf < 4; nf++) {
            #pragma unroll
            for (int jj = 0; jj < 4; jj++)
                st[nf][jj] = (cbase + jj < N_) ? st[nf][jj]*SCALE_ : -1e30f;
            float tm = fmaxf(fmaxf(st[nf][0],st[nf][1]), fmaxf(st[nf][2],st[nf][3]));
            tm = fmaxf(tm, __shfl_xor(tm, 16));
            tm = fmaxf(tm, __shfl_xor(tm, 32));
            float mn = fmaxf(m_[nf], tm);
            float sc = __expf(m_[nf] - mn);
            float ps = 0.f;
            #pragma unroll
            for (int jj = 0; jj < 4; jj++) {
                float e = __expf(st[nf][jj] - mn);
                p[nf][jj] = e; ps += e;
            }
            ps += __shfl_xor(ps, 16);
            ps += __shfl_xor(ps, 32);
            l_[nf] = l_[nf]*sc + ps;
            m_[nf] = mn;
            #pragma unroll
            for (int df = 0; df < 4; df++) {
                o[df][nf][0]*=sc; o[df][nf][1]*=sc; o[df][nf][2]*=sc; o[df][nf][3]*=sc;
            }
        }
        bf16x8_ pa[4];
        const bool half = (fq < 2);
        #pragma unroll
        for (int nf = 0; nf < 4; nf++) {
            #pragma unroll
            for (int tt = 0; tt < 8; tt++) {
                int src = fr + 16*((fq & 1)*2 + (tt >> 2));
                float v = __shfl(p[nf][tt & 3], src);
                pa[nf][tt] = half ? (short)bfr_(v) : (short)0;
            }
        }
        #pragma unroll
        for (int df = 0; df < 4; df++) {
            bf16x8_ vf = *(const bf16x8_*)&Vt[df*16 + fr][((t*2 + fq) ^ (fr & 7))*8];
            #pragma unroll
            for (int nf = 0; nf < 4; nf++)
                o[df][nf] = __builtin_amdgcn_mfma_f32_16x16x32_bf16(vf, pa[nf], o[df][nf], 0,0,0);
        }
    }
    #pragma unroll
    for (int nf = 0; nf < 4; nf++) {
        int qr = wv*64 + nf*16 + fr;
        if (qr >= N_) continue;
        float inv = 1.f / l_[nf];
        unsigned short* orow = msa2 + (size_t)(b*N_ + qr)*768 + h*64;
        #pragma unroll
        for (int df = 0; df < 4; df++) {
            const float4 vb4 = *(const float4*)&v_b[h*64 + df*16 + fq*4];
            unsigned u0 = (unsigned)bfr_(o[df][nf][0]*inv + vb4.x)
                        | ((unsigned)bfr_(o[df][nf][1]*inv + vb4.y) << 16);
            unsigned u1 = (unsigned)bfr_(o[df][nf][2]*inv + vb4.z)
                        | ((unsigned)bfr_(o[df][nf][3]*inv + vb4.w) << 16);
            uint2 w; w.x = u0; w.y = u1;
            *(uint2*)(orow + df*16 + fq*4) = w;
        }
    }
}

// ---------------- new_v (bf16 in, bf16 out) ----------------
__global__ __launch_bounds__(256) void newv_kernel(
    const unsigned short* __restrict__ vbf, const float* __restrict__ SC,
    unsigned short* __restrict__ newvb)
{
    int idx = blockIdx.x*256 + threadIdx.x;
    if (idx >= M_PATCH*64) return;
    int d = idx & 63; int bp = idx >> 6;
    int p = bp % NP_, b = bp / NP_;
    const unsigned short* src = vbf + (size_t)(b*N_ + 1 + p)*768 + d;
    float vh[12];
    #pragma unroll
    for (int h = 0; h < 12; h++) vh[h] = bf2f_(src[h*64]);
    #pragma unroll
    for (int k = 0; k < 9; k++) {
        float s = 0.f;
        #pragma unroll
        for (int h = 0; h < 12; h++) s += vh[h]*SC[HP_OFF + h*9 + k];
        newvb[((size_t)bp*9 + k)*64 + d] = bfr_(s);
    }
}

// ---------------- fused c1pre + c3pre + BN partial stats (bf16 newv) ----------------
__global__ __launch_bounds__(256) void fuse13_kernel(
    const unsigned short* __restrict__ newvb, const float* __restrict__ SC,
    float* __restrict__ c1buf, float* __restrict__ c3buf, float* __restrict__ part)
{
    __shared__ float sd1[256], sq1[256], sd3[256], sq3[256];
    int tid = threadIdx.x;
    float s1 = 0.f, q1 = 0.f, s3 = 0.f, q3 = 0.f;
    for (int i = blockIdx.x*256 + tid; i < M_PATCH*64; i += 65536) {
        int d = i & 63; int bij = i >> 6;
        int j = bij % 14; int bi = bij / 14; int irow = bi % 14; int b = bi / 14;
        float c1v = bf2f_(newvb[((size_t)bij*9 + 4)*64 + d]) + SC[NVB_OFF + d*9 + 4];
        float c3v = SC[SVB_OFF + d];
        #pragma unroll
        for (int p = 0; p < 9; p++) {
            int h1 = p % 3, h2 = p / 3;
            int y = irow + h1 - 1, xx = j + h2 - 1;
            if (y >= 0 && y < 14 && xx >= 0 && xx < 14)
                c3v += bf2f_(newvb[(((size_t)b*NP_ + y*14 + xx)*9 + p)*64 + d]);
        }
        c1buf[i] = c1v; c3buf[i] = c3v;
        s1 += c1v; q1 += c1v*c1v; s3 += c3v; q3 += c3v*c3v;
    }
    sd1[tid] = s1; sq1[tid] = q1; sd3[tid] = s3; sq3[tid] = q3;
    __syncthreads();
    if (tid < 64) {
        part[blockIdx.x*256 + tid]       = sd1[tid]+sd1[tid+64]+sd1[tid+128]+sd1[tid+192];
        part[blockIdx.x*256 + 64 + tid]  = sq1[tid]+sq1[tid+64]+sq1[tid+128]+sq1[tid+192];
        part[blockIdx.x*256 + 128 + tid] = sd3[tid]+sd3[tid+64]+sd3[tid+128]+sd3[tid+192];
        part[blockIdx.x*256 + 192 + tid] = sq3[tid]+sq3[tid+64]+sq3[tid+128]+sq3[tid+192];
    }
}

// ---------------- reduce both BN stats -> scale/offset pairs ----------------
__global__ void bnreduce2_kernel(const float* __restrict__ part,
                                 const float* __restrict__ g1, const float* __restrict__ b1,
                                 const float* __restrict__ g3, const float* __restrict__ b3,
                                 float* __restrict__ stats)
{
    __shared__ float red[256];
    int t = threadIdx.x;  // 256
    float s = 0.f;
    for (int i = 0; i < 256; i++) s += part[i*256 + t];
    red[t] = s;
    __syncthreads();
    const float invN = 1.0f/12544.0f;
    if (t < 64) {
        float mean = red[t]*invN;
        float var  = red[64+t]*invN - mean*mean;
        float sc = rsqrtf(var + BN_EPS_) * g1[t];
        stats[t]      = sc;
        stats[64+t]   = b1[t] - mean*sc;
    } else if (t < 128) {
        int d = t - 64;
        float mean = red[128+d]*invN;
        float var  = red[192+d]*invN - mean*mean;
        float sc = rsqrtf(var + BN_EPS_) * g3[d];
        stats[128+d]  = sc;
        stats[192+d]  = b3[d] - mean*sc;
    }
}

// ---------------- combined branch weights: Wc[c][0:64]=w2*W1, [64:128]=w1*W3 ----------------
__global__ __launch_bounds__(256) void w13_kernel(
    const float* __restrict__ proj_w, const float* __restrict__ SC, float* __restrict__ Wc)
{
    int idx = blockIdx.x*256 + threadIdx.x;
    if (idx >= 768*128) return;
    int d2 = idx & 127, c = idx >> 7;
    float s = 0.f;
    if (d2 < 64) {
        #pragma unroll
        for (int h = 0; h < 12; h++)
            s += proj_w[(size_t)c*768 + h*64 + d2] * SC[HP_OFF + h*9 + 4];
        s *= SC[2];   // w2 * W1
    } else {
        int dd = d2 - 64;
        #pragma unroll
        for (int h = 0; h < 12; h++)
            s += proj_w[(size_t)c*768 + h*64 + dd] * SC[HPROW_OFF + h];
        s *= SC[1];   // w1 * W3
    }
    Wc[idx] = s;
}

// ---------------- combined c1/c3 GEMM with inline BN+relu; outputs blended contribution ----
__global__ __launch_bounds__(256) void gemm_c13(
    const float* __restrict__ c1buf, const float* __restrict__ c3buf,
    const float* __restrict__ stats, const float* __restrict__ Wc,
    const float* __restrict__ proj_b, const float* __restrict__ SC,
    float* __restrict__ cblend)
{
    __shared__ float As[16][68];
    __shared__ float Bs[16][68];
    __shared__ float st[256];
    const int tid = threadIdx.x;
    const int tx = tid & 15, ty = tid >> 4;
    const int m0 = blockIdx.y * 64, n0 = blockIdx.x * 64;
    st[tid] = stats[tid];
    __syncthreads();
    float acc[4][4] = {};
    for (int k0 = 0; k0 < 128; k0 += 16) {
        int k = k0 + tx;
        #pragma unroll
        for (int i = 0; i < 4; i++) {
            int r = ty + i*16;
            float a;
            if (k < 64) {
                float v = c1buf[(size_t)(m0 + r)*64 + k];
                a = fmaxf(v*st[k] + st[64+k], 0.f);
            } else {
                int kk = k - 64;
                float v = c3buf[(size_t)(m0 + r)*64 + kk];
                a = fmaxf(v*st[128+kk] + st[192+kk], 0.f);
            }
            As[tx][r] = a;
            Bs[tx][r] = Wc[(size_t)(n0 + r)*128 + k];
        }
        __syncthreads();
        #pragma unroll
        for (int kk = 0; kk < 16; kk++) {
            const float4 a4 = *(const float4*)&As[kk][ty*4];
            const float4 b4 = *(const float4*)&Bs[kk][tx*4];
            const float a[4] = {a4.x, a4.y, a4.z, a4.w};
            const float b[4] = {b4.x, b4.y, b4.z, b4.w};
            #pragma unroll
            for (int i = 0; i < 4; i++)
                #pragma unroll
                for (int j = 0; j < 4; j++)
                    acc[i][j] += a[i]*b[j];
        }
        __syncthreads();
    }
    const float w12 = SC[1] + SC[2];
    const float4 pb4 = *(const float4*)&proj_b[n0 + tx*4];
    float4 bv = make_float4(w12*pb4.x, w12*pb4.y, w12*pb4.z, w12*pb4.w);
    #pragma unroll
    for (int i = 0; i < 4; i++) {
        int m = m0 + ty*4 + i;
        float4 o = make_float4(acc[i][0]+bv.x, acc[i][1]+bv.y, acc[i][2]+bv.z, acc[i][3]+bv.w);
        *(float4*)&cblend[(size_t)m*768 + n0 + tx*4] = o;
    }
}

// ---------------- launch ----------------
extern "C" void kernel_launch(void* const* d_in, const int* in_sizes, int n_in,
                              void* d_out, int out_size, void* d_ws, size_t ws_size,
                              hipStream_t stream)
{
    const float* x        = (const float*)d_in[0];
    const float* uniforms = (const float*)d_in[1];
    const float* qk_w     = (const float*)d_in[2];
    const float* qk_b     = (const float*)d_in[3];
    const float* v_w      = (const float*)d_in[4];
    const float* v_b      = (const float*)d_in[5];
    const float* proj_w   = (const float*)d_in[6];
    const float* proj_b   = (const float*)d_in[7];
    const float* bn1_g    = (const float*)d_in[8];
    const float* bn1_b    = (const float*)d_in[9];
    const float* bn3_g    = (const float*)d_in[10];
    const float* bn3_b    = (const float*)d_in[11];
    const float* kth      = (const float*)d_in[12];
    const float* head_probs = (const float*)d_in[13];
    float* out = (float*)d_out;

    // ws regions; every alias written-in-full (or written-then-read) in order each call
    float* ws = (float*)d_ws;
    float* R1 = ws;                     // 19,365,888 floats
    float* R2 = ws + 19365888;          //  9,682,944 floats
    float* R3 = ws + 29048832;          //  9,682,944 floats
    float* SC = ws + 38731776;          //    132,096 floats
    // R1: qkbf bf16 (floats [0,9682944)) + vbfT bf16 (floats [9682944,15187968)) -> flash;
    //     then newvb bf16 [0,3612672) (after flash); then cblend [0,9633792) (after fuse13).
    unsigned short* qkbf = (unsigned short*)R1;
    unsigned short* vbfT = (unsigned short*)R1 + 19365888;
    unsigned short* newvb = (unsigned short*)R1;
    float* cblend = R1;
    // R2: vbf bf16 (floats [0,4841472)) -> newv; then c1buf/c3buf (after newv).
    unsigned short* vbf = (unsigned short*)R2;
    float* c1buf = R2;
    float* c3buf = R2 + 802816;
    // R3: x2 bf16 [0,4841472) -> msa2 bf16 (same); part at +5000000; pjw2 at +6000000.
    unsigned int*   x2   = (unsigned int*)R3;
    unsigned short* msa2 = (unsigned short*)R3;
    float* part = R3 + 5000000;
    unsigned int* pjw2 = (unsigned int*)(R3 + 6000000);
    // d_out: W2a/W2b bf16 weights (dead after gemm_qkv) -> final out.
    unsigned int* W2a = (unsigned int*)out;
    unsigned int* W2b = (unsigned int*)out + 589824;
    float* stats = SC + STATS_OFF;
    float* Wc    = SC + WC_OFF;

    prep_kernel<<<1, 256, 0, stream>>>(uniforms, kth, head_probs, v_b, SC, out + OUT_MAIN);

    conv_hi<<<4728, 256, 0, stream>>>(x, x2, 1210368);
    conv_hi<<<576, 256, 0, stream>>>(qk_w, W2a, 147456);
    conv_hi<<<288, 256, 0, stream>>>(v_w, W2b, 73728);

    gemm_qkv<<<1782, 256, 0, stream>>>((const unsigned short*)x2,
                                       (const unsigned short*)W2a, qk_b,
                                       qkbf, vbf, (unsigned short*)vbfT);

    flash_attn<<<768, 256, 0, stream>>>(qkbf, (const unsigned short*)vbfT, v_b, msa2);

    // conv branch chain (consolidated)
    newv_kernel<<<3136, 256, 0, stream>>>(vbf, SC, newvb);
    fuse13_kernel<<<256, 256, 0, stream>>>(newvb, SC, c1buf, c3buf, part);
    bnreduce2_kernel<<<1, 256, 0, stream>>>(part, bn1_g, bn1_b, bn3_g, bn3_b, stats);
    w13_kernel<<<384, 256, 0, stream>>>(proj_w, SC, Wc);
    gemm_c13<<<dim3(12,196), 256, 0, stream>>>(c1buf, c3buf, stats, Wc, proj_b, SC, cblend);

    // proj + fused blend -> out
    conv_hi<<<288, 256, 0, stream>>>(proj_w, pjw2, 73728);
    gemm_proj<<<594, 256, 0, stream>>>(msa2, (const unsigned short*)pjw2, proj_b,
                                       x, cblend, SC, out);
}

// Round 12
// 315.189 us; speedup vs baseline: 12.6766x; 1.0253x over previous
//
#include <hip/hip_runtime.h>
#include <cstdint>
#include <cstddef>

// ---------------- problem constants ----------------
#define B_    64
#define N_    197
#define DIM_  768
#define NH_   12
#define HD_   64
#define NP_   196
#define SCALE_ 0.125f
#define EPS_   1.1920929e-07f
#define BN_EPS_ 1e-5f
#define ALPHA_ 0.01f

#define M_TOK   (B_*N_)        // 12608
#define M_PATCH (B_*NP_)       // 12544
#define OUT_MAIN (M_TOK*DIM_)  // 9682944

#define K2_ 768                // single-bf16 GEMM K
#define NT_ 24                 // K2_/32 K-steps

// scalar workspace layout (float offsets within SC)
#define W_OFF     0
#define HP_OFF    16
#define HPROW_OFF 128
#define NVB_OFF   144
#define SVB_OFF   720
#define STATS_OFF 784          // 256 floats: sc1,off1,sc3,off3
#define WC_OFF    2048         // 768*128 combined branch weights
#define SC_FLOATS 132096

typedef short bf16x8_ __attribute__((ext_vector_type(8)));
typedef float f32x4_  __attribute__((ext_vector_type(4)));

// ---------------- prep ----------------
__global__ void prep_kernel(const float* __restrict__ uniforms, const float* __restrict__ kth,
                            const float* __restrict__ head_probs, const float* __restrict__ v_b,
                            float* __restrict__ SC, float* __restrict__ out_tail)
{
    int t = threadIdx.x;
    if (t == 0) {
        float ind[3];
        for (int i = 0; i < 3; i++) {
            float s = 1.f/(1.f + expf(-kth[i]));
            float p = fminf(fmaxf(s, EPS_), 1.f - EPS_);
            float u = fminf(fmaxf(uniforms[i], EPS_), 1.f - EPS_);
            float logit = logf(u) - log1pf(-u) + logf(p) - log1pf(-p);
            ind[i] = (logit > 0.f) ? 1.f : 0.f;
        }
        SC[W_OFF+0] = ind[2];
        SC[W_OFF+1] = ind[1]*(1.f-ind[2]);
        SC[W_OFF+2] = ind[0]*(1.f-ind[1])*(1.f-ind[2]);
        float kprod = 1.f;
        for (int i = 0; i < 3; i++) {
            float ktv = 1.f/(1.f + expf(-kth[i]));
            kprod *= (ktv > 0.5f) ? 1.f : 0.f;
            out_tail[i]   = kprod;
            out_tail[3+i] = ktv;
        }
    }
    if (t < 9) {
        float mx = -1e30f;
        for (int h = 0; h < 12; h++) mx = fmaxf(mx, head_probs[h*9+t]);
        float e[12]; float s = 0.f;
        for (int h = 0; h < 12; h++) { e[h] = expf((head_probs[h*9+t]-mx)/ALPHA_); s += e[h]; }
        for (int h = 0; h < 12; h++) SC[HP_OFF + h*9 + t] = e[h]/s;
    }
    __syncthreads();
    if (t < 12) {
        float s = 0.f;
        for (int k = 0; k < 9; k++) s += SC[HP_OFF + t*9 + k];
        SC[HPROW_OFF + t] = s;
    }
    if (t < 64) {
        float sv = 0.f;
        for (int k = 0; k < 9; k++) {
            float s = 0.f;
            for (int h = 0; h < 12; h++) s += v_b[h*64+t]*SC[HP_OFF + h*9 + k];
            SC[NVB_OFF + t*9 + k] = s;
            sv += s;
        }
        SC[SVB_OFF + t] = sv;
    }
}

// ---------------- fp32 -> bf16 (RNE) ----------------
__device__ __forceinline__ unsigned short bfr_(float f) {
    unsigned u = __float_as_uint(f);
    return (unsigned short)((u + 0x7FFFu + ((u >> 16) & 1u)) >> 16);
}
__device__ __forceinline__ float bf2f_(unsigned short u) {
    return __uint_as_float((unsigned)u << 16);
}

__global__ __launch_bounds__(256) void conv_hi(const float* __restrict__ in,
                                               unsigned int* __restrict__ out, int n8)
{
    int i = blockIdx.x*256 + threadIdx.x;
    if (i >= n8) return;
    float4 a = ((const float4*)in)[2*i];
    float4 b = ((const float4*)in)[2*i+1];
    unsigned r0 = (unsigned)bfr_(a.x) | ((unsigned)bfr_(a.y) << 16);
    unsigned r1 = (unsigned)bfr_(a.z) | ((unsigned)bfr_(a.w) << 16);
    unsigned r2 = (unsigned)bfr_(b.x) | ((unsigned)bfr_(b.y) << 16);
    unsigned r3 = (unsigned)bfr_(b.z) | ((unsigned)bfr_(b.w) << 16);
    ((uint4*)out)[i] = make_uint4(r0, r1, r2, r3);
}

// ---- global_load_lds staging into a given LDS buffer (linear [128][32] ushorts) ----
// LDS slot (row r, chunk c=lane&3) receives global k-chunk (c ^ (r&3)); read XORs back.
// Per wave: 2 loads per call (vmcnt += 2).
#define STAGE_TILE2(LDSPTR, GBASE, ROWCLAMP, KOFF)                                       \
    {                                                                                    \
        _Pragma("unroll")                                                                \
        for (int i_ = 0; i_ < 2; i_++) {                                                 \
            int r_ = wave*32 + i_*16 + (lane >> 2);                                      \
            int gr_ = ROWCLAMP(r_);                                                      \
            const unsigned short* gp_ = (GBASE) + (size_t)gr_*K2_ + (KOFF)               \
                                        + (((lane & 3) ^ (r_ & 3)) * 8);                 \
            __builtin_amdgcn_global_load_lds(                                            \
                (const __attribute__((address_space(1))) unsigned int*)gp_,              \
                (__attribute__((address_space(3))) unsigned int*)&(LDSPTR)[(wave*32 + i_*16)*32], \
                16, 0, 0);                                                               \
        }                                                                                \
    }

// read-complete fence: ds_reads (memory ops) can't cross; then raw barrier (NO vmcnt drain)
#define BAR_LGKM() asm volatile("s_waitcnt lgkmcnt(0)\n\ts_barrier" ::: "memory")
// staged-tile fence: wait until only N newest loads remain in flight, then barrier
#define BAR_VM4()  asm volatile("s_waitcnt vmcnt(4)\n\ts_barrier" ::: "memory")
#define BAR_VM0()  asm volatile("s_waitcnt vmcnt(0)\n\ts_barrier" ::: "memory")

// ---------------- merged qk+v GEMM (bf16 MFMA, 2-deep counted-vmcnt pipeline) ----------------
__global__ __launch_bounds__(256) void gemm_qkv(
    const unsigned short* __restrict__ A2, const unsigned short* __restrict__ W2,
    const float* __restrict__ qk_b,
    unsigned short* __restrict__ qkbf, unsigned short* __restrict__ vbf,
    unsigned short* __restrict__ vbfT)
{
    __shared__ unsigned short At[2][128*32];
    __shared__ unsigned short Bt[2][128*32];
    const int nwg = 1782;
    int q = nwg >> 3, rr = nwg & 7;
    int xcd = blockIdx.x & 7, idx = blockIdx.x >> 3;
    int s = (xcd < rr) ? xcd*(q+1) + idx : rr*(q+1) + (xcd - rr)*q + idx;
    const int n0 = (s % 18) * 128, m0 = (s / 18) * 128;
    const int tid = threadIdx.x;
    const int wave = tid >> 6, lane = tid & 63;
    const int wr = (wave >> 1)*64, wc = (wave & 1)*64;
    const int fr = lane & 15, fq = lane >> 4;
    const int xk = (fq ^ (fr & 3)) * 8;

    f32x4_ acc[4][4] = {};

    #define CLA_(r) ((m0 + (r) < M_TOK) ? (m0 + (r)) : (M_TOK-1))
    #define CLB_(r) (n0 + (r))
    // prologue: stage tiles 0 and 1; wait for tile 0 only (tile 1 stays in flight)
    STAGE_TILE2(At[0], A2, CLA_, 0)
    STAGE_TILE2(Bt[0], W2, CLB_, 0)
    STAGE_TILE2(At[1], A2, CLA_, 32)
    STAGE_TILE2(Bt[1], W2, CLB_, 32)
    BAR_VM4();
    for (int kt = 0; kt < NT_; kt++) {
        const int cur = kt & 1;
        bf16x8_ a[4], bb[4];
        #pragma unroll
        for (int i = 0; i < 4; i++) {
            a[i]  = *(const bf16x8_*)&At[cur][(wr + i*16 + fr)*32 + xk];
            bb[i] = *(const bf16x8_*)&Bt[cur][(wc + i*16 + fr)*32 + xk];
        }
        #pragma unroll
        for (int mi = 0; mi < 4; mi++)
            #pragma unroll
            for (int ni = 0; ni < 4; ni++)
                acc[mi][ni] = __builtin_amdgcn_mfma_f32_16x16x32_bf16(a[mi], bb[ni], acc[mi][ni], 0, 0, 0);
        BAR_LGKM();                       // all waves done reading buf[cur]
        if (kt + 2 < NT_) {
            STAGE_TILE2(At[cur], A2, CLA_, (kt+2)*32)
            STAGE_TILE2(Bt[cur], W2, CLB_, (kt+2)*32)
            BAR_VM4();                    // tile kt+1 ready; tile kt+2 in flight
        } else if (kt + 1 < NT_) {
            BAR_VM0();                    // drain for final tile
        }
    }
    #undef CLA_
    #undef CLB_

    if (n0 < 1536) {
        float bv[4];
        #pragma unroll
        for (int ni = 0; ni < 4; ni++) bv[ni] = qk_b[n0 + wc + ni*16 + fr];
        #pragma unroll
        for (int mi = 0; mi < 4; mi++) {
            #pragma unroll
            for (int j = 0; j < 4; j++) {
                int row = m0 + wr + mi*16 + fq*4 + j;
                if (row < M_TOK) {
                    unsigned short* crow = qkbf + (size_t)row*1536 + n0 + wc;
                    #pragma unroll
                    for (int ni = 0; ni < 4; ni++)
                        crow[ni*16 + fr] = bfr_(acc[mi][ni][j] + bv[ni]);
                }
            }
        }
    } else {
        const int v0 = n0 - 1536;
        #pragma unroll
        for (int mi = 0; mi < 4; mi++) {
            #pragma unroll
            for (int j = 0; j < 4; j++) {
                int row = m0 + wr + mi*16 + fq*4 + j;
                if (row < M_TOK) {
                    int bq = row / N_;
                    int cc = row - bq*N_;
                    unsigned short* vrow = vbf + (size_t)row*768 + v0 + wc;
                    #pragma unroll
                    for (int ni = 0; ni < 4; ni++) {
                        unsigned short vb16 = bfr_(acc[mi][ni][j]);
                        int vcol = v0 + wc + ni*16 + fr;
                        vrow[ni*16 + fr] = vb16;
                        int hh = vcol >> 6, dd = vcol & 63;
                        vbfT[((size_t)(bq*NH_ + hh)*64 + dd)*224 + cc] = vb16;
                    }
                }
            }
        }
    }
}

// ---------------- proj GEMM (bf16 MFMA, 2-deep pipeline) + fused blend epilogue ----------------
__global__ __launch_bounds__(256) void gemm_proj(
    const unsigned short* __restrict__ A2, const unsigned short* __restrict__ W2,
    const float* __restrict__ bias,
    const float* __restrict__ x, const float* __restrict__ cb,
    const float* __restrict__ SC, float* __restrict__ out)
{
    __shared__ unsigned short At[2][128*32];
    __shared__ unsigned short Bt[2][128*32];
    const int nwg = gridDim.x;
    int q = nwg >> 3, rr = nwg & 7;
    int xcd = blockIdx.x & 7, idx = blockIdx.x >> 3;
    int s = (xcd < rr) ? xcd*(q+1) + idx : rr*(q+1) + (xcd - rr)*q + idx;
    const int n0 = (s % 6) * 128, m0 = (s / 6) * 128;
    const int tid = threadIdx.x;
    const int wave = tid >> 6, lane = tid & 63;
    const int wr = (wave >> 1)*64, wc = (wave & 1)*64;
    const int fr = lane & 15, fq = lane >> 4;
    const int xk = (fq ^ (fr & 3)) * 8;

    f32x4_ acc[4][4] = {};

    #define CLA_(r) ((m0 + (r) < M_TOK) ? (m0 + (r)) : (M_TOK-1))
    #define CLB_(r) (n0 + (r))
    STAGE_TILE2(At[0], A2, CLA_, 0)
    STAGE_TILE2(Bt[0], W2, CLB_, 0)
    STAGE_TILE2(At[1], A2, CLA_, 32)
    STAGE_TILE2(Bt[1], W2, CLB_, 32)
    BAR_VM4();
    for (int kt = 0; kt < NT_; kt++) {
        const int cur = kt & 1;
        bf16x8_ a[4], bb[4];
        #pragma unroll
        for (int i = 0; i < 4; i++) {
            a[i]  = *(const bf16x8_*)&At[cur][(wr + i*16 + fr)*32 + xk];
            bb[i] = *(const bf16x8_*)&Bt[cur][(wc + i*16 + fr)*32 + xk];
        }
        #pragma unroll
        for (int mi = 0; mi < 4; mi++)
            #pragma unroll
            for (int ni = 0; ni < 4; ni++)
                acc[mi][ni] = __builtin_amdgcn_mfma_f32_16x16x32_bf16(a[mi], bb[ni], acc[mi][ni], 0, 0, 0);
        BAR_LGKM();
        if (kt + 2 < NT_) {
            STAGE_TILE2(At[cur], A2, CLA_, (kt+2)*32)
            STAGE_TILE2(Bt[cur], W2, CLB_, (kt+2)*32)
            BAR_VM4();
        } else if (kt + 1 < NT_) {
            BAR_VM0();
        }
    }
    #undef CLA_
    #undef CLB_

    const float w0 = SC[0], w12 = SC[1] + SC[2];
    float bv[4];
    #pragma unroll
    for (int ni = 0; ni < 4; ni++) bv[ni] = bias[n0 + wc + ni*16 + fr];
    #pragma unroll
    for (int mi = 0; mi < 4; mi++) {
        #pragma unroll
        for (int j = 0; j < 4; j++) {
            int row = m0 + wr + mi*16 + fq*4 + j;
            if (row < M_TOK) {
                int b = row / N_;
                int n = row - b*N_;
                float* orow = out + (size_t)row*768 + n0 + wc;
                if (n == 0) {
                    const float* xr = x + (size_t)row*768 + n0 + wc;
                    #pragma unroll
                    for (int ni = 0; ni < 4; ni++) {
                        float m = acc[mi][ni][j] + bv[ni];
                        orow[ni*16 + fr] = w0*m + w12*xr[ni*16 + fr];
                    }
                } else {
                    size_t qb = ((size_t)(row - b - 1))*768 + n0 + wc;
                    #pragma unroll
                    for (int ni = 0; ni < 4; ni++) {
                        float m = acc[mi][ni][j] + bv[ni];
                        orow[ni*16 + fr] = w0*m + cb[qb + ni*16 + fr];
                    }
                }
            }
        }
    }
}

// ---------------- fused flash attention (bf16 MFMA) ----------------
__global__ __launch_bounds__(256) void flash_attn(
    const unsigned short* __restrict__ qkbf,
    const unsigned short* __restrict__ vbfT,
    const float* __restrict__ v_b,
    unsigned short* __restrict__ msa2)
{
    __shared__ unsigned short Kb[224][64];
    __shared__ unsigned short Vt[64][256];
    const int bh = blockIdx.x;
    const int b = bh / NH_, h = bh % NH_;
    const int tid = threadIdx.x;
    const int wv = tid >> 6, lane = tid & 63;
    const int fr = lane & 15, fq = lane >> 4;

    {
        const unsigned short* Kg = qkbf + (size_t)(b*N_)*1536 + 768 + h*64;
        int r = tid >> 3; const int ch = tid & 7;
        #pragma unroll
        for (int rnd = 0; rnd < 7; rnd++, r += 32) {
            uint4 val = make_uint4(0u,0u,0u,0u);
            if (r < N_) val = *(const uint4*)(Kg + (size_t)r*1536 + ch*8);
            *(uint4*)&Kb[r][(ch ^ (r & 7))*8] = val;
        }
    }
    {
        const unsigned short* Vg = vbfT + (size_t)bh*(64*224);
        #pragma unroll
        for (int rnd = 0; rnd < 8; rnd++) {
            int job = rnd*256 + tid;
            int d = job >> 5, ch = job & 31;
            uint4 val = make_uint4(0u,0u,0u,0u);
            if (ch < 24) val = *(const uint4*)(Vg + (size_t)d*224 + ch*8);
            else if (ch == 24) {
                val = *(const uint4*)(Vg + (size_t)d*224 + 192);
                val.z &= 0xFFFFu; val.w = 0u;
            }
            *(uint4*)&Vt[d][(ch ^ (d & 7))*8] = val;
        }
    }
    bf16x8_ qf[4][2];
    #pragma unroll
    for (int nf = 0; nf < 4; nf++) {
        int qr = wv*64 + nf*16 + fr; if (qr > N_-1) qr = N_-1;
        const unsigned short* Qg = qkbf + (size_t)(b*N_ + qr)*1536 + h*64;
        qf[nf][0] = *(const bf16x8_*)(Qg + fq*8);
        qf[nf][1] = *(const bf16x8_*)(Qg + 32 + fq*8);
    }
    __syncthreads();

    f32x4_ o[4][4];
    #pragma unroll
    for (int i = 0; i < 4; i++)
        #pragma unroll
        for (int j2 = 0; j2 < 4; j2++) { o[i][j2][0]=0.f; o[i][j2][1]=0.f; o[i][j2][2]=0.f; o[i][j2][3]=0.f; }
    float m_[4] = {-1e30f,-1e30f,-1e30f,-1e30f};
    float l_[4] = {0.f,0.f,0.f,0.f};

    for (int t = 0; t < 14; t++) {
        const int krow = t*16 + fr;
        bf16x8_ kf0 = *(const bf16x8_*)&Kb[krow][( fq      ^ (fr & 7))*8];
        bf16x8_ kf1 = *(const bf16x8_*)&Kb[krow][((fq + 4) ^ (fr & 7))*8];
        f32x4_ st[4];
        #pragma unroll
        for (int nf = 0; nf < 4; nf++) {
            f32x4_ z = {0.f,0.f,0.f,0.f};
            z = __builtin_amdgcn_mfma_f32_16x16x32_bf16(kf0, qf[nf][0], z, 0,0,0);
            z = __builtin_amdgcn_mfma_f32_16x16x32_bf16(kf1, qf[nf][1], z, 0,0,0);
            st[nf] = z;
        }
        const int cbase = t*16 + fq*4;
        float p[4][4];
        #pragma unroll
        for (int nf = 0; nf < 4; nf++) {
            #pragma unroll
            for (int jj = 0; jj < 4; jj++)
                st[nf][jj] = (cbase + jj < N_) ? st[nf][jj]*SCALE_ : -1e30f;
            float tm = fmaxf(fmaxf(st[nf][0],st[nf][1]), fmaxf(st[nf][2],st[nf][3]));
            tm = fmaxf(tm, __shfl_xor(tm, 16));
            tm = fmaxf(tm, __shfl_xor(tm, 32));
            float mn = fmaxf(m_[nf], tm);
            float sc = __expf(m_[nf] - mn);
            float ps = 0.f;
            #pragma unroll
            for (int jj = 0; jj < 4; jj++) {
                float e = __expf(st[nf][jj] - mn);
                p[nf][jj] = e; ps += e;
            }
            ps += __shfl_xor(ps, 16);
            ps += __shfl_xor(ps, 32);
            l_[nf] = l_[nf]*sc + ps;
            m_[nf] = mn;
            #pragma unroll
            for (int df = 0; df < 4; df++) {
                o[df][nf][0]*=sc; o[df][nf][1]*=sc; o[df][nf][2]*=sc; o[df][nf][3]*=sc;
            }
        }
        bf16x8_ pa[4];
        const bool half = (fq < 2);
        #pragma unroll
        for (int nf = 0; nf < 4; nf++) {
            #pragma unroll
            for (int tt = 0; tt < 8; tt++) {
                int src = fr + 16*((fq & 1)*2 + (tt >> 2));
                float v = __shfl(p[nf][tt & 3], src);
                pa[nf][tt] = half ? (short)bfr_(v) : (short)0;
            }
        }
        #pragma unroll
        for (int df = 0; df < 4; df++) {
            bf16x8_ vf = *(const bf16x8_*)&Vt[df*16 + fr][((t*2 + fq) ^ (fr & 7))*8];
            #pragma unroll
            for (int nf = 0; nf < 4; nf++)
                o[df][nf] = __builtin_amdgcn_mfma_f32_16x16x32_bf16(vf, pa[nf], o[df][nf], 0,0,0);
        }
    }
    #pragma unroll
    for (int nf = 0; nf < 4; nf++) {
        int qr = wv*64 + nf*16 + fr;
        if (qr >= N_) continue;
        float inv = 1.f / l_[nf];
        unsigned short* orow = msa2 + (size_t)(b*N_ + qr)*768 + h*64;
        #pragma unroll
        for (int df = 0; df < 4; df++) {
            const float4 vb4 = *(const float4*)&v_b[h*64 + df*16 + fq*4];
            unsigned u0 = (unsigned)bfr_(o[df][nf][0]*inv + vb4.x)
                        | ((unsigned)bfr_(o[df][nf][1]*inv + vb4.y) << 16);
            unsigned u1 = (unsigned)bfr_(o[df][nf][2]*inv + vb4.z)
                        | ((unsigned)bfr_(o[df][nf][3]*inv + vb4.w) << 16);
            uint2 w; w.x = u0; w.y = u1;
            *(uint2*)(orow + df*16 + fq*4) = w;
        }
    }
}

// ---------------- new_v (bf16 in, bf16 out) ----------------
__global__ __launch_bounds__(256) void newv_kernel(
    const unsigned short* __restrict__ vbf, const float* __restrict__ SC,
    unsigned short* __restrict__ newvb)
{
    int idx = blockIdx.x*256 + threadIdx.x;
    if (idx >= M_PATCH*64) return;
    int d = idx & 63; int bp = idx >> 6;
    int p = bp % NP_, b = bp / NP_;
    const unsigned short* src = vbf + (size_t)(b*N_ + 1 + p)*768 + d;
    float vh[12];
    #pragma unroll
    for (int h = 0; h < 12; h++) vh[h] = bf2f_(src[h*64]);
    #pragma unroll
    for (int k = 0; k < 9; k++) {
        float s = 0.f;
        #pragma unroll
        for (int h = 0; h < 12; h++) s += vh[h]*SC[HP_OFF + h*9 + k];
        newvb[((size_t)bp*9 + k)*64 + d] = bfr_(s);
    }
}

// ---------------- fused c1pre + c3pre + BN partial stats (bf16 newv) ----------------
__global__ __launch_bounds__(256) void fuse13_kernel(
    const unsigned short* __restrict__ newvb, const float* __restrict__ SC,
    float* __restrict__ c1buf, float* __restrict__ c3buf, float* __restrict__ part)
{
    __shared__ float sd1[256], sq1[256], sd3[256], sq3[256];
    int tid = threadIdx.x;
    float s1 = 0.f, q1 = 0.f, s3 = 0.f, q3 = 0.f;
    for (int i = blockIdx.x*256 + tid; i < M_PATCH*64; i += 65536) {
        int d = i & 63; int bij = i >> 6;
        int j = bij % 14; int bi = bij / 14; int irow = bi % 14; int b = bi / 14;
        float c1v = bf2f_(newvb[((size_t)bij*9 + 4)*64 + d]) + SC[NVB_OFF + d*9 + 4];
        float c3v = SC[SVB_OFF + d];
        #pragma unroll
        for (int p = 0; p < 9; p++) {
            int h1 = p % 3, h2 = p / 3;
            int y = irow + h1 - 1, xx = j + h2 - 1;
            if (y >= 0 && y < 14 && xx >= 0 && xx < 14)
                c3v += bf2f_(newvb[(((size_t)b*NP_ + y*14 + xx)*9 + p)*64 + d]);
        }
        c1buf[i] = c1v; c3buf[i] = c3v;
        s1 += c1v; q1 += c1v*c1v; s3 += c3v; q3 += c3v*c3v;
    }
    sd1[tid] = s1; sq1[tid] = q1; sd3[tid] = s3; sq3[tid] = q3;
    __syncthreads();
    if (tid < 64) {
        part[blockIdx.x*256 + tid]       = sd1[tid]+sd1[tid+64]+sd1[tid+128]+sd1[tid+192];
        part[blockIdx.x*256 + 64 + tid]  = sq1[tid]+sq1[tid+64]+sq1[tid+128]+sq1[tid+192];
        part[blockIdx.x*256 + 128 + tid] = sd3[tid]+sd3[tid+64]+sd3[tid+128]+sd3[tid+192];
        part[blockIdx.x*256 + 192 + tid] = sq3[tid]+sq3[tid+64]+sq3[tid+128]+sq3[tid+192];
    }
}

// ---------------- reduce both BN stats -> scale/offset pairs ----------------
__global__ void bnreduce2_kernel(const float* __restrict__ part,
                                 const float* __restrict__ g1, const float* __restrict__ b1,
                                 const float* __restrict__ g3, const float* __restrict__ b3,
                                 float* __restrict__ stats)
{
    __shared__ float red[256];
    int t = threadIdx.x;  // 256
    float s = 0.f;
    for (int i = 0; i < 256; i++) s += part[i*256 + t];
    red[t] = s;
    __syncthreads();
    const float invN = 1.0f/12544.0f;
    if (t < 64) {
        float mean = red[t]*invN;
        float var  = red[64+t]*invN - mean*mean;
        float sc = rsqrtf(var + BN_EPS_) * g1[t];
        stats[t]      = sc;
        stats[64+t]   = b1[t] - mean*sc;
    } else if (t < 128) {
        int d = t - 64;
        float mean = red[128+d]*invN;
        float var  = red[192+d]*invN - mean*mean;
        float sc = rsqrtf(var + BN_EPS_) * g3[d];
        stats[128+d]  = sc;
        stats[192+d]  = b3[d] - mean*sc;
    }
}

// ---------------- combined branch weights: Wc[c][0:64]=w2*W1, [64:128]=w1*W3 ----------------
__global__ __launch_bounds__(256) void w13_kernel(
    const float* __restrict__ proj_w, const float* __restrict__ SC, float* __restrict__ Wc)
{
    int idx = blockIdx.x*256 + threadIdx.x;
    if (idx >= 768*128) return;
    int d2 = idx & 127, c = idx >> 7;
    float s = 0.f;
    if (d2 < 64) {
        #pragma unroll
        for (int h = 0; h < 12; h++)
            s += proj_w[(size_t)c*768 + h*64 + d2] * SC[HP_OFF + h*9 + 4];
        s *= SC[2];   // w2 * W1
    } else {
        int dd = d2 - 64;
        #pragma unroll
        for (int h = 0; h < 12; h++)
            s += proj_w[(size_t)c*768 + h*64 + dd] * SC[HPROW_OFF + h];
        s *= SC[1];   // w1 * W3
    }
    Wc[idx] = s;
}

// ---------------- combined c1/c3 GEMM with inline BN+relu; outputs blended contribution ----
__global__ __launch_bounds__(256) void gemm_c13(
    const float* __restrict__ c1buf, const float* __restrict__ c3buf,
    const float* __restrict__ stats, const float* __restrict__ Wc,
    const float* __restrict__ proj_b, const float* __restrict__ SC,
    float* __restrict__ cblend)
{
    __shared__ float As[16][68];
    __shared__ float Bs[16][68];
    __shared__ float st[256];
    const int tid = threadIdx.x;
    const int tx = tid & 15, ty = tid >> 4;
    const int m0 = blockIdx.y * 64, n0 = blockIdx.x * 64;
    st[tid] = stats[tid];
    __syncthreads();
    float acc[4][4] = {};
    for (int k0 = 0; k0 < 128; k0 += 16) {
        int k = k0 + tx;
        #pragma unroll
        for (int i = 0; i < 4; i++) {
            int r = ty + i*16;
            float a;
            if (k < 64) {
                float v = c1buf[(size_t)(m0 + r)*64 + k];
                a = fmaxf(v*st[k] + st[64+k], 0.f);
            } else {
                int kk = k - 64;
                float v = c3buf[(size_t)(m0 + r)*64 + kk];
                a = fmaxf(v*st[128+kk] + st[192+kk], 0.f);
            }
            As[tx][r] = a;
            Bs[tx][r] = Wc[(size_t)(n0 + r)*128 + k];
        }
        __syncthreads();
        #pragma unroll
        for (int kk = 0; kk < 16; kk++) {
            const float4 a4 = *(const float4*)&As[kk][ty*4];
            const float4 b4 = *(const float4*)&Bs[kk][tx*4];
            const float a[4] = {a4.x, a4.y, a4.z, a4.w};
            const float b[4] = {b4.x, b4.y, b4.z, b4.w};
            #pragma unroll
            for (int i = 0; i < 4; i++)
                #pragma unroll
                for (int j = 0; j < 4; j++)
                    acc[i][j] += a[i]*b[j];
        }
        __syncthreads();
    }
    const float w12 = SC[1] + SC[2];
    const float4 pb4 = *(const float4*)&proj_b[n0 + tx*4];
    float4 bv = make_float4(w12*pb4.x, w12*pb4.y, w12*pb4.z, w12*pb4.w);
    #pragma unroll
    for (int i = 0; i < 4; i++) {
        int m = m0 + ty*4 + i;
        float4 o = make_float4(acc[i][0]+bv.x, acc[i][1]+bv.y, acc[i][2]+bv.z, acc[i][3]+bv.w);
        *(float4*)&cblend[(size_t)m*768 + n0 + tx*4] = o;
    }
}

// ---------------- launch ----------------
extern "C" void kernel_launch(void* const* d_in, const int* in_sizes, int n_in,
                              void* d_out, int out_size, void* d_ws, size_t ws_size,
                              hipStream_t stream)
{
    const float* x        = (const float*)d_in[0];
    const float* uniforms = (const float*)d_in[1];
    const float* qk_w     = (const float*)d_in[2];
    const float* qk_b     = (const float*)d_in[3];
    const float* v_w      = (const float*)d_in[4];
    const float* v_b      = (const float*)d_in[5];
    const float* proj_w   = (const float*)d_in[6];
    const float* proj_b   = (const float*)d_in[7];
    const float* bn1_g    = (const float*)d_in[8];
    const float* bn1_b    = (const float*)d_in[9];
    const float* bn3_g    = (const float*)d_in[10];
    const float* bn3_b    = (const float*)d_in[11];
    const float* kth      = (const float*)d_in[12];
    const float* head_probs = (const float*)d_in[13];
    float* out = (float*)d_out;

    // ws regions; every alias written-in-full (or written-then-read) in order each call
    float* ws = (float*)d_ws;
    float* R1 = ws;                     // 19,365,888 floats
    float* R2 = ws + 19365888;          //  9,682,944 floats
    float* R3 = ws + 29048832;          //  9,682,944 floats
    float* SC = ws + 38731776;          //    132,096 floats
    unsigned short* qkbf = (unsigned short*)R1;
    unsigned short* vbfT = (unsigned short*)R1 + 19365888;
    unsigned short* newvb = (unsigned short*)R1;
    float* cblend = R1;
    unsigned short* vbf = (unsigned short*)R2;
    float* c1buf = R2;
    float* c3buf = R2 + 802816;
    unsigned int*   x2   = (unsigned int*)R3;
    unsigned short* msa2 = (unsigned short*)R3;
    float* part = R3 + 5000000;
    unsigned int* pjw2 = (unsigned int*)(R3 + 6000000);
    unsigned int* W2a = (unsigned int*)out;
    unsigned int* W2b = (unsigned int*)out + 589824;
    float* stats = SC + STATS_OFF;
    float* Wc    = SC + WC_OFF;

    prep_kernel<<<1, 256, 0, stream>>>(uniforms, kth, head_probs, v_b, SC, out + OUT_MAIN);

    conv_hi<<<4728, 256, 0, stream>>>(x, x2, 1210368);
    conv_hi<<<576, 256, 0, stream>>>(qk_w, W2a, 147456);
    conv_hi<<<288, 256, 0, stream>>>(v_w, W2b, 73728);

    gemm_qkv<<<1782, 256, 0, stream>>>((const unsigned short*)x2,
                                       (const unsigned short*)W2a, qk_b,
                                       qkbf, vbf, (unsigned short*)vbfT);

    flash_attn<<<768, 256, 0, stream>>>(qkbf, (const unsigned short*)vbfT, v_b, msa2);

    // conv branch chain (consolidated)
    newv_kernel<<<3136, 256, 0, stream>>>(vbf, SC, newvb);
    fuse13_kernel<<<256, 256, 0, stream>>>(newvb, SC, c1buf, c3buf, part);
    bnreduce2_kernel<<<1, 256, 0, stream>>>(part, bn1_g, bn1_b, bn3_g, bn3_b, stats);
    w13_kernel<<<384, 256, 0, stream>>>(proj_w, SC, Wc);
    gemm_c13<<<dim3(12,196), 256, 0, stream>>>(c1buf, c3buf, stats, Wc, proj_b, SC, cblend);

    // proj + fused blend -> out
    conv_hi<<<288, 256, 0, stream>>>(proj_w, pjw2, 73728);
    gemm_proj<<<594, 256, 0, stream>>>(msa2, (const unsigned short*)pjw2, proj_b,
                                       x, cblend, SC, out);
}

// Round 13
// 297.593 us; speedup vs baseline: 13.4262x; 1.0591x over previous
//
#include <hip/hip_runtime.h>
#include <cstdint>
#include <cstddef>

// ---------------- problem constants ----------------
#define B_    64
#define N_    197
#define DIM_  768
#define NH_   12
#define HD_   64
#define NP_   196
#define SCALE_ 0.125f
#define EPS_   1.1920929e-07f
#define BN_EPS_ 1e-5f
#define ALPHA_ 0.01f

#define M_TOK   (B_*N_)        // 12608
#define M_PATCH (B_*NP_)       // 12544
#define OUT_MAIN (M_TOK*DIM_)  // 9682944

#define K2_ 768                // single-bf16 GEMM K
#define NT_ 24                 // K2_/32 K-steps

// scalar workspace layout (float offsets within SC)
#define W_OFF     0
#define HP_OFF    16
#define HPROW_OFF 128
#define NVB_OFF   144
#define SVB_OFF   720
#define STATS_OFF 784          // 256 floats: sc1,off1,sc3,off3
#define WC_OFF    2048         // 768*128 combined branch weights
#define SC_FLOATS 132096

typedef short bf16x8_ __attribute__((ext_vector_type(8)));
typedef float f32x4_  __attribute__((ext_vector_type(4)));

// ---------------- prep ----------------
__global__ void prep_kernel(const float* __restrict__ uniforms, const float* __restrict__ kth,
                            const float* __restrict__ head_probs, const float* __restrict__ v_b,
                            float* __restrict__ SC, float* __restrict__ out_tail)
{
    int t = threadIdx.x;
    if (t == 0) {
        float ind[3];
        for (int i = 0; i < 3; i++) {
            float s = 1.f/(1.f + expf(-kth[i]));
            float p = fminf(fmaxf(s, EPS_), 1.f - EPS_);
            float u = fminf(fmaxf(uniforms[i], EPS_), 1.f - EPS_);
            float logit = logf(u) - log1pf(-u) + logf(p) - log1pf(-p);
            ind[i] = (logit > 0.f) ? 1.f : 0.f;
        }
        SC[W_OFF+0] = ind[2];
        SC[W_OFF+1] = ind[1]*(1.f-ind[2]);
        SC[W_OFF+2] = ind[0]*(1.f-ind[1])*(1.f-ind[2]);
        float kprod = 1.f;
        for (int i = 0; i < 3; i++) {
            float ktv = 1.f/(1.f + expf(-kth[i]));
            kprod *= (ktv > 0.5f) ? 1.f : 0.f;
            out_tail[i]   = kprod;
            out_tail[3+i] = ktv;
        }
    }
    if (t < 9) {
        float mx = -1e30f;
        for (int h = 0; h < 12; h++) mx = fmaxf(mx, head_probs[h*9+t]);
        float e[12]; float s = 0.f;
        for (int h = 0; h < 12; h++) { e[h] = expf((head_probs[h*9+t]-mx)/ALPHA_); s += e[h]; }
        for (int h = 0; h < 12; h++) SC[HP_OFF + h*9 + t] = e[h]/s;
    }
    __syncthreads();
    if (t < 12) {
        float s = 0.f;
        for (int k = 0; k < 9; k++) s += SC[HP_OFF + t*9 + k];
        SC[HPROW_OFF + t] = s;
    }
    if (t < 64) {
        float sv = 0.f;
        for (int k = 0; k < 9; k++) {
            float s = 0.f;
            for (int h = 0; h < 12; h++) s += v_b[h*64+t]*SC[HP_OFF + h*9 + k];
            SC[NVB_OFF + t*9 + k] = s;
            sv += s;
        }
        SC[SVB_OFF + t] = sv;
    }
}

// ---------------- fp32 -> bf16 (RNE) ----------------
__device__ __forceinline__ unsigned short bfr_(float f) {
    unsigned u = __float_as_uint(f);
    return (unsigned short)((u + 0x7FFFu + ((u >> 16) & 1u)) >> 16);
}
__device__ __forceinline__ float bf2f_(unsigned short u) {
    return __uint_as_float((unsigned)u << 16);
}

__global__ __launch_bounds__(256) void conv_hi(const float* __restrict__ in,
                                               unsigned int* __restrict__ out, int n8)
{
    int i = blockIdx.x*256 + threadIdx.x;
    if (i >= n8) return;
    float4 a = ((const float4*)in)[2*i];
    float4 b = ((const float4*)in)[2*i+1];
    unsigned r0 = (unsigned)bfr_(a.x) | ((unsigned)bfr_(a.y) << 16);
    unsigned r1 = (unsigned)bfr_(a.z) | ((unsigned)bfr_(a.w) << 16);
    unsigned r2 = (unsigned)bfr_(b.x) | ((unsigned)bfr_(b.y) << 16);
    unsigned r3 = (unsigned)bfr_(b.z) | ((unsigned)bfr_(b.w) << 16);
    ((uint4*)out)[i] = make_uint4(r0, r1, r2, r3);
}

// ---- global_load_lds staging into a given LDS buffer (linear [128][32] ushorts) ----
#define STAGE_TILE2(LDSPTR, GBASE, ROWCLAMP, KOFF)                                       \
    {                                                                                    \
        _Pragma("unroll")                                                                \
        for (int i_ = 0; i_ < 2; i_++) {                                                 \
            int r_ = wave*32 + i_*16 + (lane >> 2);                                      \
            int gr_ = ROWCLAMP(r_);                                                      \
            const unsigned short* gp_ = (GBASE) + (size_t)gr_*K2_ + (KOFF)               \
                                        + (((lane & 3) ^ (r_ & 3)) * 8);                 \
            __builtin_amdgcn_global_load_lds(                                            \
                (const __attribute__((address_space(1))) unsigned int*)gp_,              \
                (__attribute__((address_space(3))) unsigned int*)&(LDSPTR)[(wave*32 + i_*16)*32], \
                16, 0, 0);                                                               \
        }                                                                                \
    }

#define BAR_LGKM() asm volatile("s_waitcnt lgkmcnt(0)\n\ts_barrier" ::: "memory")
#define BAR_VM4()  asm volatile("s_waitcnt vmcnt(4)\n\ts_barrier" ::: "memory")
#define BAR_VM0()  asm volatile("s_waitcnt vmcnt(0)\n\ts_barrier" ::: "memory")

// ---------------- merged qk+v GEMM (bf16 MFMA, 2-deep counted-vmcnt pipeline) ----------------
__global__ __launch_bounds__(256) void gemm_qkv(
    const unsigned short* __restrict__ A2, const unsigned short* __restrict__ W2,
    const float* __restrict__ qk_b,
    unsigned short* __restrict__ qkbf, unsigned short* __restrict__ vbf,
    unsigned short* __restrict__ vbfT)
{
    __shared__ unsigned short At[2][128*32];
    __shared__ unsigned short Bt[2][128*32];
    const int nwg = 1782;
    int q = nwg >> 3, rr = nwg & 7;
    int xcd = blockIdx.x & 7, idx = blockIdx.x >> 3;
    int s = (xcd < rr) ? xcd*(q+1) + idx : rr*(q+1) + (xcd - rr)*q + idx;
    const int n0 = (s % 18) * 128, m0 = (s / 18) * 128;
    const int tid = threadIdx.x;
    const int wave = tid >> 6, lane = tid & 63;
    const int wr = (wave >> 1)*64, wc = (wave & 1)*64;
    const int fr = lane & 15, fq = lane >> 4;
    const int xk = (fq ^ (fr & 3)) * 8;

    f32x4_ acc[4][4] = {};

    #define CLA_(r) ((m0 + (r) < M_TOK) ? (m0 + (r)) : (M_TOK-1))
    #define CLB_(r) (n0 + (r))
    STAGE_TILE2(At[0], A2, CLA_, 0)
    STAGE_TILE2(Bt[0], W2, CLB_, 0)
    STAGE_TILE2(At[1], A2, CLA_, 32)
    STAGE_TILE2(Bt[1], W2, CLB_, 32)
    BAR_VM4();
    for (int kt = 0; kt < NT_; kt++) {
        const int cur = kt & 1;
        bf16x8_ a[4], bb[4];
        #pragma unroll
        for (int i = 0; i < 4; i++) {
            a[i]  = *(const bf16x8_*)&At[cur][(wr + i*16 + fr)*32 + xk];
            bb[i] = *(const bf16x8_*)&Bt[cur][(wc + i*16 + fr)*32 + xk];
        }
        #pragma unroll
        for (int mi = 0; mi < 4; mi++)
            #pragma unroll
            for (int ni = 0; ni < 4; ni++)
                acc[mi][ni] = __builtin_amdgcn_mfma_f32_16x16x32_bf16(a[mi], bb[ni], acc[mi][ni], 0, 0, 0);
        BAR_LGKM();
        if (kt + 2 < NT_) {
            STAGE_TILE2(At[cur], A2, CLA_, (kt+2)*32)
            STAGE_TILE2(Bt[cur], W2, CLB_, (kt+2)*32)
            BAR_VM4();
        } else if (kt + 1 < NT_) {
            BAR_VM0();
        }
    }
    #undef CLA_
    #undef CLB_

    if (n0 < 1536) {
        float bv[4];
        #pragma unroll
        for (int ni = 0; ni < 4; ni++) bv[ni] = qk_b[n0 + wc + ni*16 + fr];
        #pragma unroll
        for (int mi = 0; mi < 4; mi++) {
            #pragma unroll
            for (int j = 0; j < 4; j++) {
                int row = m0 + wr + mi*16 + fq*4 + j;
                if (row < M_TOK) {
                    unsigned short* crow = qkbf + (size_t)row*1536 + n0 + wc;
                    #pragma unroll
                    for (int ni = 0; ni < 4; ni++)
                        crow[ni*16 + fr] = bfr_(acc[mi][ni][j] + bv[ni]);
                }
            }
        }
    } else {
        const int v0 = n0 - 1536;
        #pragma unroll
        for (int mi = 0; mi < 4; mi++) {
            #pragma unroll
            for (int j = 0; j < 4; j++) {
                int row = m0 + wr + mi*16 + fq*4 + j;
                if (row < M_TOK) {
                    int bq = row / N_;
                    int cc = row - bq*N_;
                    unsigned short* vrow = vbf + (size_t)row*768 + v0 + wc;
                    #pragma unroll
                    for (int ni = 0; ni < 4; ni++) {
                        unsigned short vb16 = bfr_(acc[mi][ni][j]);
                        int vcol = v0 + wc + ni*16 + fr;
                        vrow[ni*16 + fr] = vb16;
                        int hh = vcol >> 6, dd = vcol & 63;
                        vbfT[((size_t)(bq*NH_ + hh)*64 + dd)*224 + cc] = vb16;
                    }
                }
            }
        }
    }
}

// ---------------- proj GEMM (bf16 MFMA, 2-deep pipeline) + fused blend epilogue ----------------
__global__ __launch_bounds__(256) void gemm_proj(
    const unsigned short* __restrict__ A2, const unsigned short* __restrict__ W2,
    const float* __restrict__ bias,
    const float* __restrict__ x, const float* __restrict__ cb,
    const float* __restrict__ SC, float* __restrict__ out)
{
    __shared__ unsigned short At[2][128*32];
    __shared__ unsigned short Bt[2][128*32];
    const int nwg = gridDim.x;
    int q = nwg >> 3, rr = nwg & 7;
    int xcd = blockIdx.x & 7, idx = blockIdx.x >> 3;
    int s = (xcd < rr) ? xcd*(q+1) + idx : rr*(q+1) + (xcd - rr)*q + idx;
    const int n0 = (s % 6) * 128, m0 = (s / 6) * 128;
    const int tid = threadIdx.x;
    const int wave = tid >> 6, lane = tid & 63;
    const int wr = (wave >> 1)*64, wc = (wave & 1)*64;
    const int fr = lane & 15, fq = lane >> 4;
    const int xk = (fq ^ (fr & 3)) * 8;

    f32x4_ acc[4][4] = {};

    #define CLA_(r) ((m0 + (r) < M_TOK) ? (m0 + (r)) : (M_TOK-1))
    #define CLB_(r) (n0 + (r))
    STAGE_TILE2(At[0], A2, CLA_, 0)
    STAGE_TILE2(Bt[0], W2, CLB_, 0)
    STAGE_TILE2(At[1], A2, CLA_, 32)
    STAGE_TILE2(Bt[1], W2, CLB_, 32)
    BAR_VM4();
    for (int kt = 0; kt < NT_; kt++) {
        const int cur = kt & 1;
        bf16x8_ a[4], bb[4];
        #pragma unroll
        for (int i = 0; i < 4; i++) {
            a[i]  = *(const bf16x8_*)&At[cur][(wr + i*16 + fr)*32 + xk];
            bb[i] = *(const bf16x8_*)&Bt[cur][(wc + i*16 + fr)*32 + xk];
        }
        #pragma unroll
        for (int mi = 0; mi < 4; mi++)
            #pragma unroll
            for (int ni = 0; ni < 4; ni++)
                acc[mi][ni] = __builtin_amdgcn_mfma_f32_16x16x32_bf16(a[mi], bb[ni], acc[mi][ni], 0, 0, 0);
        BAR_LGKM();
        if (kt + 2 < NT_) {
            STAGE_TILE2(At[cur], A2, CLA_, (kt+2)*32)
            STAGE_TILE2(Bt[cur], W2, CLB_, (kt+2)*32)
            BAR_VM4();
        } else if (kt + 1 < NT_) {
            BAR_VM0();
        }
    }
    #undef CLA_
    #undef CLB_

    const float w0 = SC[0], w12 = SC[1] + SC[2];
    float bv[4];
    #pragma unroll
    for (int ni = 0; ni < 4; ni++) bv[ni] = bias[n0 + wc + ni*16 + fr];
    #pragma unroll
    for (int mi = 0; mi < 4; mi++) {
        #pragma unroll
        for (int j = 0; j < 4; j++) {
            int row = m0 + wr + mi*16 + fq*4 + j;
            if (row < M_TOK) {
                int b = row / N_;
                int n = row - b*N_;
                float* orow = out + (size_t)row*768 + n0 + wc;
                if (n == 0) {
                    const float* xr = x + (size_t)row*768 + n0 + wc;
                    #pragma unroll
                    for (int ni = 0; ni < 4; ni++) {
                        float m = acc[mi][ni][j] + bv[ni];
                        orow[ni*16 + fr] = w0*m + w12*xr[ni*16 + fr];
                    }
                } else {
                    size_t qb = ((size_t)(row - b - 1))*768 + n0 + wc;
                    #pragma unroll
                    for (int ni = 0; ni < 4; ni++) {
                        float m = acc[mi][ni][j] + bv[ni];
                        orow[ni*16 + fr] = w0*m + cb[qb + ni*16 + fr];
                    }
                }
            }
        }
    }
}

// ---------------- fused flash attention v2 (bf16 MFMA, no staging, LDS P-transfer) ----------------
__global__ __launch_bounds__(256) void flash_attn(
    const unsigned short* __restrict__ qkbf,
    const unsigned short* __restrict__ vbfT,
    const float* __restrict__ v_b,
    unsigned short* __restrict__ msa2)
{
    __shared__ unsigned short Plds[4][4][16][24];   // [wave][nf][q][k], 24-pad rows
    const int bh = blockIdx.x;
    const int b = bh / NH_, h = bh % NH_;
    const int tid = threadIdx.x;
    const int wv = tid >> 6, lane = tid & 63;
    const int fr = lane & 15, fq = lane >> 4;

    const unsigned short* Kg = qkbf + (size_t)(b*N_)*1536 + 768 + h*64;
    const unsigned short* Vg = vbfT + (size_t)bh*(64*224);

    // Q fragments (global, clamped rows)
    bf16x8_ qf[4][2];
    #pragma unroll
    for (int nf = 0; nf < 4; nf++) {
        int qr = wv*64 + nf*16 + fr; if (qr > N_-1) qr = N_-1;
        const unsigned short* Qg = qkbf + (size_t)(b*N_ + qr)*1536 + h*64;
        qf[nf][0] = *(const bf16x8_*)(Qg + fq*8);
        qf[nf][1] = *(const bf16x8_*)(Qg + 32 + fq*8);
    }

    f32x4_ o[4][4];
    #pragma unroll
    for (int i = 0; i < 4; i++)
        #pragma unroll
        for (int j2 = 0; j2 < 4; j2++) { o[i][j2][0]=0.f; o[i][j2][1]=0.f; o[i][j2][2]=0.f; o[i][j2][3]=0.f; }
    float m_[4] = {-1e30f,-1e30f,-1e30f,-1e30f};
    float l_[4] = {0.f,0.f,0.f,0.f};

    for (int t = 0; t < 14; t++) {
        // K fragments direct from global (L2); clamped rows masked below
        int kr = t*16 + fr; if (kr > N_-1) kr = N_-1;
        const unsigned short* krp = Kg + (size_t)kr*1536;
        bf16x8_ kf0 = *(const bf16x8_*)(krp + fq*8);
        bf16x8_ kf1 = *(const bf16x8_*)(krp + 32 + fq*8);
        f32x4_ st[4];
        #pragma unroll
        for (int nf = 0; nf < 4; nf++) {
            f32x4_ z = {0.f,0.f,0.f,0.f};
            z = __builtin_amdgcn_mfma_f32_16x16x32_bf16(kf0, qf[nf][0], z, 0,0,0);
            z = __builtin_amdgcn_mfma_f32_16x16x32_bf16(kf1, qf[nf][1], z, 0,0,0);
            st[nf] = z;
        }
        const int cbase = t*16 + fq*4;
        #pragma unroll
        for (int nf = 0; nf < 4; nf++) {
            #pragma unroll
            for (int jj = 0; jj < 4; jj++)
                st[nf][jj] = (cbase + jj < N_) ? st[nf][jj]*SCALE_ : -1e30f;
            float tm = fmaxf(fmaxf(st[nf][0],st[nf][1]), fmaxf(st[nf][2],st[nf][3]));
            tm = fmaxf(tm, __shfl_xor(tm, 16));
            tm = fmaxf(tm, __shfl_xor(tm, 32));
            // defer-max (T13): only rescale when running max grows by > 8
            if (__any(tm > m_[nf] + 8.f)) {
                float mn = fmaxf(m_[nf], tm);
                float sc = __expf(m_[nf] - mn);
                l_[nf] *= sc;
                m_[nf] = mn;
                #pragma unroll
                for (int df = 0; df < 4; df++) {
                    o[df][nf][0]*=sc; o[df][nf][1]*=sc; o[df][nf][2]*=sc; o[df][nf][3]*=sc;
                }
            }
            float mn = m_[nf];
            float e0 = __expf(st[nf][0] - mn);
            float e1 = __expf(st[nf][1] - mn);
            float e2 = __expf(st[nf][2] - mn);
            float e3 = __expf(st[nf][3] - mn);
            float ps = e0 + e1 + e2 + e3;
            ps += __shfl_xor(ps, 16);
            ps += __shfl_xor(ps, 32);
            l_[nf] += ps;
            // write P (bf16) to per-wave LDS, transposed [q][k]
            unsigned lo = (unsigned)bfr_(e0) | ((unsigned)bfr_(e1) << 16);
            unsigned hi = (unsigned)bfr_(e2) | ((unsigned)bfr_(e3) << 16);
            *(uint2*)&Plds[wv][nf][fr][fq*4] = make_uint2(lo, hi);
        }
        // same-wave LDS fence: drain writes, then read P fragments
        asm volatile("s_waitcnt lgkmcnt(0)" ::: "memory");
        __builtin_amdgcn_sched_barrier(0);
        bf16x8_ pa[4];
        #pragma unroll
        for (int nf = 0; nf < 4; nf++) {
            if (fq < 2) pa[nf] = *(const bf16x8_*)&Plds[wv][nf][fr][fq*8];
            else { bf16x8_ z2 = {0,0,0,0,0,0,0,0}; pa[nf] = z2; }
        }
        // V fragments direct from global (L2); clamped cols multiply pa=0
        #pragma unroll
        for (int df = 0; df < 4; df++) {
            int d = df*16 + fr;
            int ko = t*16 + fq*8; if (ko > 216) ko = 216;
            bf16x8_ vf = *(const bf16x8_*)(Vg + (size_t)d*224 + ko);
            #pragma unroll
            for (int nf = 0; nf < 4; nf++)
                o[df][nf] = __builtin_amdgcn_mfma_f32_16x16x32_bf16(vf, pa[nf], o[df][nf], 0,0,0);
        }
    }
    // epilogue: normalize, add v_b, store bf16
    #pragma unroll
    for (int nf = 0; nf < 4; nf++) {
        int qr = wv*64 + nf*16 + fr;
        if (qr >= N_) continue;
        float inv = 1.f / l_[nf];
        unsigned short* orow = msa2 + (size_t)(b*N_ + qr)*768 + h*64;
        #pragma unroll
        for (int df = 0; df < 4; df++) {
            const float4 vb4 = *(const float4*)&v_b[h*64 + df*16 + fq*4];
            unsigned u0 = (unsigned)bfr_(o[df][nf][0]*inv + vb4.x)
                        | ((unsigned)bfr_(o[df][nf][1]*inv + vb4.y) << 16);
            unsigned u1 = (unsigned)bfr_(o[df][nf][2]*inv + vb4.z)
                        | ((unsigned)bfr_(o[df][nf][3]*inv + vb4.w) << 16);
            uint2 w; w.x = u0; w.y = u1;
            *(uint2*)(orow + df*16 + fq*4) = w;
        }
    }
}

// ---------------- new_v (bf16 in, bf16 out) ----------------
__global__ __launch_bounds__(256) void newv_kernel(
    const unsigned short* __restrict__ vbf, const float* __restrict__ SC,
    unsigned short* __restrict__ newvb)
{
    int idx = blockIdx.x*256 + threadIdx.x;
    if (idx >= M_PATCH*64) return;
    int d = idx & 63; int bp = idx >> 6;
    int p = bp % NP_, b = bp / NP_;
    const unsigned short* src = vbf + (size_t)(b*N_ + 1 + p)*768 + d;
    float vh[12];
    #pragma unroll
    for (int h = 0; h < 12; h++) vh[h] = bf2f_(src[h*64]);
    #pragma unroll
    for (int k = 0; k < 9; k++) {
        float s = 0.f;
        #pragma unroll
        for (int h = 0; h < 12; h++) s += vh[h]*SC[HP_OFF + h*9 + k];
        newvb[((size_t)bp*9 + k)*64 + d] = bfr_(s);
    }
}

// ---------------- fused c1pre + c3pre + BN partial stats (bf16 newv) ----------------
__global__ __launch_bounds__(256) void fuse13_kernel(
    const unsigned short* __restrict__ newvb, const float* __restrict__ SC,
    float* __restrict__ c1buf, float* __restrict__ c3buf, float* __restrict__ part)
{
    __shared__ float sd1[256], sq1[256], sd3[256], sq3[256];
    int tid = threadIdx.x;
    float s1 = 0.f, q1 = 0.f, s3 = 0.f, q3 = 0.f;
    for (int i = blockIdx.x*256 + tid; i < M_PATCH*64; i += 65536) {
        int d = i & 63; int bij = i >> 6;
        int j = bij % 14; int bi = bij / 14; int irow = bi % 14; int b = bi / 14;
        float c1v = bf2f_(newvb[((size_t)bij*9 + 4)*64 + d]) + SC[NVB_OFF + d*9 + 4];
        float c3v = SC[SVB_OFF + d];
        #pragma unroll
        for (int p = 0; p < 9; p++) {
            int h1 = p % 3, h2 = p / 3;
            int y = irow + h1 - 1, xx = j + h2 - 1;
            if (y >= 0 && y < 14 && xx >= 0 && xx < 14)
                c3v += bf2f_(newvb[(((size_t)b*NP_ + y*14 + xx)*9 + p)*64 + d]);
        }
        c1buf[i] = c1v; c3buf[i] = c3v;
        s1 += c1v; q1 += c1v*c1v; s3 += c3v; q3 += c3v*c3v;
    }
    sd1[tid] = s1; sq1[tid] = q1; sd3[tid] = s3; sq3[tid] = q3;
    __syncthreads();
    if (tid < 64) {
        part[blockIdx.x*256 + tid]       = sd1[tid]+sd1[tid+64]+sd1[tid+128]+sd1[tid+192];
        part[blockIdx.x*256 + 64 + tid]  = sq1[tid]+sq1[tid+64]+sq1[tid+128]+sq1[tid+192];
        part[blockIdx.x*256 + 128 + tid] = sd3[tid]+sd3[tid+64]+sd3[tid+128]+sd3[tid+192];
        part[blockIdx.x*256 + 192 + tid] = sq3[tid]+sq3[tid+64]+sq3[tid+128]+sq3[tid+192];
    }
}

// ---------------- reduce both BN stats -> scale/offset pairs ----------------
__global__ void bnreduce2_kernel(const float* __restrict__ part,
                                 const float* __restrict__ g1, const float* __restrict__ b1,
                                 const float* __restrict__ g3, const float* __restrict__ b3,
                                 float* __restrict__ stats)
{
    __shared__ float red[256];
    int t = threadIdx.x;  // 256
    float s = 0.f;
    for (int i = 0; i < 256; i++) s += part[i*256 + t];
    red[t] = s;
    __syncthreads();
    const float invN = 1.0f/12544.0f;
    if (t < 64) {
        float mean = red[t]*invN;
        float var  = red[64+t]*invN - mean*mean;
        float sc = rsqrtf(var + BN_EPS_) * g1[t];
        stats[t]      = sc;
        stats[64+t]   = b1[t] - mean*sc;
    } else if (t < 128) {
        int d = t - 64;
        float mean = red[128+d]*invN;
        float var  = red[192+d]*invN - mean*mean;
        float sc = rsqrtf(var + BN_EPS_) * g3[d];
        stats[128+d]  = sc;
        stats[192+d]  = b3[d] - mean*sc;
    }
}

// ---------------- combined branch weights: Wc[c][0:64]=w2*W1, [64:128]=w1*W3 ----------------
__global__ __launch_bounds__(256) void w13_kernel(
    const float* __restrict__ proj_w, const float* __restrict__ SC, float* __restrict__ Wc)
{
    int idx = blockIdx.x*256 + threadIdx.x;
    if (idx >= 768*128) return;
    int d2 = idx & 127, c = idx >> 7;
    float s = 0.f;
    if (d2 < 64) {
        #pragma unroll
        for (int h = 0; h < 12; h++)
            s += proj_w[(size_t)c*768 + h*64 + d2] * SC[HP_OFF + h*9 + 4];
        s *= SC[2];   // w2 * W1
    } else {
        int dd = d2 - 64;
        #pragma unroll
        for (int h = 0; h < 12; h++)
            s += proj_w[(size_t)c*768 + h*64 + dd] * SC[HPROW_OFF + h];
        s *= SC[1];   // w1 * W3
    }
    Wc[idx] = s;
}

// ---------------- combined c1/c3 GEMM with inline BN+relu; outputs blended contribution ----
__global__ __launch_bounds__(256) void gemm_c13(
    const float* __restrict__ c1buf, const float* __restrict__ c3buf,
    const float* __restrict__ stats, const float* __restrict__ Wc,
    const float* __restrict__ proj_b, const float* __restrict__ SC,
    float* __restrict__ cblend)
{
    __shared__ float As[16][68];
    __shared__ float Bs[16][68];
    __shared__ float st[256];
    const int tid = threadIdx.x;
    const int tx = tid & 15, ty = tid >> 4;
    const int m0 = blockIdx.y * 64, n0 = blockIdx.x * 64;
    st[tid] = stats[tid];
    __syncthreads();
    float acc[4][4] = {};
    for (int k0 = 0; k0 < 128; k0 += 16) {
        int k = k0 + tx;
        #pragma unroll
        for (int i = 0; i < 4; i++) {
            int r = ty + i*16;
            float a;
            if (k < 64) {
                float v = c1buf[(size_t)(m0 + r)*64 + k];
                a = fmaxf(v*st[k] + st[64+k], 0.f);
            } else {
                int kk = k - 64;
                float v = c3buf[(size_t)(m0 + r)*64 + kk];
                a = fmaxf(v*st[128+kk] + st[192+kk], 0.f);
            }
            As[tx][r] = a;
            Bs[tx][r] = Wc[(size_t)(n0 + r)*128 + k];
        }
        __syncthreads();
        #pragma unroll
        for (int kk = 0; kk < 16; kk++) {
            const float4 a4 = *(const float4*)&As[kk][ty*4];
            const float4 b4 = *(const float4*)&Bs[kk][tx*4];
            const float a[4] = {a4.x, a4.y, a4.z, a4.w};
            const float b[4] = {b4.x, b4.y, b4.z, b4.w};
            #pragma unroll
            for (int i = 0; i < 4; i++)
                #pragma unroll
                for (int j = 0; j < 4; j++)
                    acc[i][j] += a[i]*b[j];
        }
        __syncthreads();
    }
    const float w12 = SC[1] + SC[2];
    const float4 pb4 = *(const float4*)&proj_b[n0 + tx*4];
    float4 bv = make_float4(w12*pb4.x, w12*pb4.y, w12*pb4.z, w12*pb4.w);
    #pragma unroll
    for (int i = 0; i < 4; i++) {
        int m = m0 + ty*4 + i;
        float4 o = make_float4(acc[i][0]+bv.x, acc[i][1]+bv.y, acc[i][2]+bv.z, acc[i][3]+bv.w);
        *(float4*)&cblend[(size_t)m*768 + n0 + tx*4] = o;
    }
}

// ---------------- launch ----------------
extern "C" void kernel_launch(void* const* d_in, const int* in_sizes, int n_in,
                              void* d_out, int out_size, void* d_ws, size_t ws_size,
                              hipStream_t stream)
{
    const float* x        = (const float*)d_in[0];
    const float* uniforms = (const float*)d_in[1];
    const float* qk_w     = (const float*)d_in[2];
    const float* qk_b     = (const float*)d_in[3];
    const float* v_w      = (const float*)d_in[4];
    const float* v_b      = (const float*)d_in[5];
    const float* proj_w   = (const float*)d_in[6];
    const float* proj_b   = (const float*)d_in[7];
    const float* bn1_g    = (const float*)d_in[8];
    const float* bn1_b    = (const float*)d_in[9];
    const float* bn3_g    = (const float*)d_in[10];
    const float* bn3_b    = (const float*)d_in[11];
    const float* kth      = (const float*)d_in[12];
    const float* head_probs = (const float*)d_in[13];
    float* out = (float*)d_out;

    // ws regions; every alias written-in-full (or written-then-read) in order each call
    float* ws = (float*)d_ws;
    float* R1 = ws;                     // 19,365,888 floats
    float* R2 = ws + 19365888;          //  9,682,944 floats
    float* R3 = ws + 29048832;          //  9,682,944 floats
    float* SC = ws + 38731776;          //    132,096 floats
    unsigned short* qkbf = (unsigned short*)R1;
    unsigned short* vbfT = (unsigned short*)R1 + 19365888;
    unsigned short* newvb = (unsigned short*)R1;
    float* cblend = R1;
    unsigned short* vbf = (unsigned short*)R2;
    float* c1buf = R2;
    float* c3buf = R2 + 802816;
    unsigned int*   x2   = (unsigned int*)R3;
    unsigned short* msa2 = (unsigned short*)R3;
    float* part = R3 + 5000000;
    unsigned int* pjw2 = (unsigned int*)(R3 + 6000000);
    unsigned int* W2a = (unsigned int*)out;
    unsigned int* W2b = (unsigned int*)out + 589824;
    float* stats = SC + STATS_OFF;
    float* Wc    = SC + WC_OFF;

    prep_kernel<<<1, 256, 0, stream>>>(uniforms, kth, head_probs, v_b, SC, out + OUT_MAIN);

    conv_hi<<<4728, 256, 0, stream>>>(x, x2, 1210368);
    conv_hi<<<576, 256, 0, stream>>>(qk_w, W2a, 147456);
    conv_hi<<<288, 256, 0, stream>>>(v_w, W2b, 73728);

    gemm_qkv<<<1782, 256, 0, stream>>>((const unsigned short*)x2,
                                       (const unsigned short*)W2a, qk_b,
                                       qkbf, vbf, (unsigned short*)vbfT);

    flash_attn<<<768, 256, 0, stream>>>(qkbf, (const unsigned short*)vbfT, v_b, msa2);

    // conv branch chain (consolidated)
    newv_kernel<<<3136, 256, 0, stream>>>(vbf, SC, newvb);
    fuse13_kernel<<<256, 256, 0, stream>>>(newvb, SC, c1buf, c3buf, part);
    bnreduce2_kernel<<<1, 256, 0, stream>>>(part, bn1_g, bn1_b, bn3_g, bn3_b, stats);
    w13_kernel<<<384, 256, 0, stream>>>(proj_w, SC, Wc);
    gemm_c13<<<dim3(12,196), 256, 0, stream>>>(c1buf, c3buf, stats, Wc, proj_b, SC, cblend);

    // proj + fused blend -> out
    conv_hi<<<288, 256, 0, stream>>>(proj_w, pjw2, 73728);
    gemm_proj<<<594, 256, 0, stream>>>(msa2, (const unsigned short*)pjw2, proj_b,
                                       x, cblend, SC, out);
}

// Round 14
// 263.658 us; speedup vs baseline: 15.1543x; 1.1287x over previous
//
#include <hip/hip_runtime.h>
#include <cstdint>
#include <cstddef>

// ---------------- problem constants ----------------
#define B_    64
#define N_    197
#define DIM_  768
#define NH_   12
#define HD_   64
#define NP_   196
#define SCALE_ 0.125f
#define EPS_   1.1920929e-07f
#define BN_EPS_ 1e-5f
#define ALPHA_ 0.01f

#define M_TOK   (B_*N_)        // 12608
#define M_PATCH (B_*NP_)       // 12544
#define OUT_MAIN (M_TOK*DIM_)  // 9682944

#define K2_  768               // qkv GEMM K (bf16)
#define NT_  24                // K2_/32
#define K2P_ 896               // proj GEMM K = 768 (msa) + 128 (act13)
#define NTP_ 28                // K2P_/32

// scalar workspace layout (float offsets within SC)
#define W_OFF     0
#define HP_OFF    16
#define HPROW_OFF 128
#define NVB_OFF   144
#define SVB_OFF   720
#define STATS_OFF 784          // 256 floats: sc1,off1,sc3,off3
#define SC_FLOATS 132096

typedef short bf16x8_ __attribute__((ext_vector_type(8)));
typedef float f32x4_  __attribute__((ext_vector_type(4)));

// ---------------- prep ----------------
__global__ void prep_kernel(const float* __restrict__ uniforms, const float* __restrict__ kth,
                            const float* __restrict__ head_probs, const float* __restrict__ v_b,
                            float* __restrict__ SC, float* __restrict__ out_tail)
{
    int t = threadIdx.x;
    if (t == 0) {
        float ind[3];
        for (int i = 0; i < 3; i++) {
            float s = 1.f/(1.f + expf(-kth[i]));
            float p = fminf(fmaxf(s, EPS_), 1.f - EPS_);
            float u = fminf(fmaxf(uniforms[i], EPS_), 1.f - EPS_);
            float logit = logf(u) - log1pf(-u) + logf(p) - log1pf(-p);
            ind[i] = (logit > 0.f) ? 1.f : 0.f;
        }
        SC[W_OFF+0] = ind[2];
        SC[W_OFF+1] = ind[1]*(1.f-ind[2]);
        SC[W_OFF+2] = ind[0]*(1.f-ind[1])*(1.f-ind[2]);
        float kprod = 1.f;
        for (int i = 0; i < 3; i++) {
            float ktv = 1.f/(1.f + expf(-kth[i]));
            kprod *= (ktv > 0.5f) ? 1.f : 0.f;
            out_tail[i]   = kprod;
            out_tail[3+i] = ktv;
        }
    }
    if (t < 9) {
        float mx = -1e30f;
        for (int h = 0; h < 12; h++) mx = fmaxf(mx, head_probs[h*9+t]);
        float e[12]; float s = 0.f;
        for (int h = 0; h < 12; h++) { e[h] = expf((head_probs[h*9+t]-mx)/ALPHA_); s += e[h]; }
        for (int h = 0; h < 12; h++) SC[HP_OFF + h*9 + t] = e[h]/s;
    }
    __syncthreads();
    if (t < 12) {
        float s = 0.f;
        for (int k = 0; k < 9; k++) s += SC[HP_OFF + t*9 + k];
        SC[HPROW_OFF + t] = s;
    }
    if (t < 64) {
        float sv = 0.f;
        for (int k = 0; k < 9; k++) {
            float s = 0.f;
            for (int h = 0; h < 12; h++) s += v_b[h*64+t]*SC[HP_OFF + h*9 + k];
            SC[NVB_OFF + t*9 + k] = s;
            sv += s;
        }
        SC[SVB_OFF + t] = sv;
    }
}

// ---------------- fp32 -> bf16 (RNE) ----------------
__device__ __forceinline__ unsigned short bfr_(float f) {
    unsigned u = __float_as_uint(f);
    return (unsigned short)((u + 0x7FFFu + ((u >> 16) & 1u)) >> 16);
}
__device__ __forceinline__ float bf2f_(unsigned short u) {
    return __uint_as_float((unsigned)u << 16);
}

__global__ __launch_bounds__(256) void conv_hi(const float* __restrict__ in,
                                               unsigned int* __restrict__ out, int n8)
{
    int i = blockIdx.x*256 + threadIdx.x;
    if (i >= n8) return;
    float4 a = ((const float4*)in)[2*i];
    float4 b = ((const float4*)in)[2*i+1];
    unsigned r0 = (unsigned)bfr_(a.x) | ((unsigned)bfr_(a.y) << 16);
    unsigned r1 = (unsigned)bfr_(a.z) | ((unsigned)bfr_(a.w) << 16);
    unsigned r2 = (unsigned)bfr_(b.x) | ((unsigned)bfr_(b.y) << 16);
    unsigned r3 = (unsigned)bfr_(b.z) | ((unsigned)bfr_(b.w) << 16);
    ((uint4*)out)[i] = make_uint4(r0, r1, r2, r3);
}

// ---- global_load_lds staging (linear [128][32] ushorts; per-lane XOR src, XOR read) ----
#define STAGE_TILE2(LDSPTR, GBASE, ROWCLAMP, KOFF, STRIDE)                               \
    {                                                                                    \
        _Pragma("unroll")                                                                \
        for (int i_ = 0; i_ < 2; i_++) {                                                 \
            int r_ = wave*32 + i_*16 + (lane >> 2);                                      \
            int gr_ = ROWCLAMP(r_);                                                      \
            const unsigned short* gp_ = (GBASE) + (size_t)gr_*(STRIDE) + (KOFF)          \
                                        + (((lane & 3) ^ (r_ & 3)) * 8);                 \
            __builtin_amdgcn_global_load_lds(                                            \
                (const __attribute__((address_space(1))) unsigned int*)gp_,              \
                (__attribute__((address_space(3))) unsigned int*)&(LDSPTR)[(wave*32 + i_*16)*32], \
                16, 0, 0);                                                               \
        }                                                                                \
    }

#define BAR_LGKM() asm volatile("s_waitcnt lgkmcnt(0)\n\ts_barrier" ::: "memory")
#define BAR_VM4()  asm volatile("s_waitcnt vmcnt(4)\n\ts_barrier" ::: "memory")
#define BAR_VM0()  asm volatile("s_waitcnt vmcnt(0)\n\ts_barrier" ::: "memory")

// ---------------- merged qk+v GEMM (bf16 MFMA, 2-deep counted-vmcnt pipeline) ----------------
__global__ __launch_bounds__(256) void gemm_qkv(
    const unsigned short* __restrict__ A2, const unsigned short* __restrict__ W2,
    const float* __restrict__ qk_b,
    unsigned short* __restrict__ qkbf, unsigned short* __restrict__ vbf,
    unsigned short* __restrict__ vbfT)
{
    __shared__ unsigned short At[2][128*32];
    __shared__ unsigned short Bt[2][128*32];
    const int nwg = 1782;
    int q = nwg >> 3, rr = nwg & 7;
    int xcd = blockIdx.x & 7, idx = blockIdx.x >> 3;
    int s = (xcd < rr) ? xcd*(q+1) + idx : rr*(q+1) + (xcd - rr)*q + idx;
    const int n0 = (s % 18) * 128, m0 = (s / 18) * 128;
    const int tid = threadIdx.x;
    const int wave = tid >> 6, lane = tid & 63;
    const int wr = (wave >> 1)*64, wc = (wave & 1)*64;
    const int fr = lane & 15, fq = lane >> 4;
    const int xk = (fq ^ (fr & 3)) * 8;

    f32x4_ acc[4][4] = {};

    #define CLA_(r) ((m0 + (r) < M_TOK) ? (m0 + (r)) : (M_TOK-1))
    #define CLB_(r) (n0 + (r))
    STAGE_TILE2(At[0], A2, CLA_, 0, K2_)
    STAGE_TILE2(Bt[0], W2, CLB_, 0, K2_)
    STAGE_TILE2(At[1], A2, CLA_, 32, K2_)
    STAGE_TILE2(Bt[1], W2, CLB_, 32, K2_)
    BAR_VM4();
    for (int kt = 0; kt < NT_; kt++) {
        const int cur = kt & 1;
        bf16x8_ a[4], bb[4];
        #pragma unroll
        for (int i = 0; i < 4; i++) {
            a[i]  = *(const bf16x8_*)&At[cur][(wr + i*16 + fr)*32 + xk];
            bb[i] = *(const bf16x8_*)&Bt[cur][(wc + i*16 + fr)*32 + xk];
        }
        #pragma unroll
        for (int mi = 0; mi < 4; mi++)
            #pragma unroll
            for (int ni = 0; ni < 4; ni++)
                acc[mi][ni] = __builtin_amdgcn_mfma_f32_16x16x32_bf16(a[mi], bb[ni], acc[mi][ni], 0, 0, 0);
        BAR_LGKM();
        if (kt + 2 < NT_) {
            STAGE_TILE2(At[cur], A2, CLA_, (kt+2)*32, K2_)
            STAGE_TILE2(Bt[cur], W2, CLB_, (kt+2)*32, K2_)
            BAR_VM4();
        } else if (kt + 1 < NT_) {
            BAR_VM0();
        }
    }
    #undef CLA_
    #undef CLB_

    if (n0 < 1536) {
        float bv[4];
        #pragma unroll
        for (int ni = 0; ni < 4; ni++) bv[ni] = qk_b[n0 + wc + ni*16 + fr];
        #pragma unroll
        for (int mi = 0; mi < 4; mi++) {
            #pragma unroll
            for (int j = 0; j < 4; j++) {
                int row = m0 + wr + mi*16 + fq*4 + j;
                if (row < M_TOK) {
                    unsigned short* crow = qkbf + (size_t)row*1536 + n0 + wc;
                    #pragma unroll
                    for (int ni = 0; ni < 4; ni++)
                        crow[ni*16 + fr] = bfr_(acc[mi][ni][j] + bv[ni]);
                }
            }
        }
    } else {
        const int v0 = n0 - 1536;
        #pragma unroll
        for (int mi = 0; mi < 4; mi++) {
            #pragma unroll
            for (int j = 0; j < 4; j++) {
                int row = m0 + wr + mi*16 + fq*4 + j;
                if (row < M_TOK) {
                    int bq = row / N_;
                    int cc = row - bq*N_;
                    unsigned short* vrow = vbf + (size_t)row*768 + v0 + wc;
                    #pragma unroll
                    for (int ni = 0; ni < 4; ni++) {
                        unsigned short vb16 = bfr_(acc[mi][ni][j]);
                        int vcol = v0 + wc + ni*16 + fr;
                        vrow[ni*16 + fr] = vb16;
                        int hh = vcol >> 6, dd = vcol & 63;
                        vbfT[((size_t)(bq*NH_ + hh)*64 + dd)*224 + cc] = vb16;
                    }
                }
            }
        }
    }
}

// ---------------- proj+branch GEMM (K=896 bf16 MFMA) + fused blend epilogue ----------------
// A = [msa2 | act13] (stride 896); W' = [w0*Pw | Wc] (stride 896).
__global__ __launch_bounds__(256) void gemm_proj(
    const unsigned short* __restrict__ A2, const unsigned short* __restrict__ W2,
    const float* __restrict__ bias,
    const float* __restrict__ x, const float* __restrict__ SC,
    float* __restrict__ out)
{
    __shared__ unsigned short At[2][128*32];
    __shared__ unsigned short Bt[2][128*32];
    const int nwg = gridDim.x;
    int q = nwg >> 3, rr = nwg & 7;
    int xcd = blockIdx.x & 7, idx = blockIdx.x >> 3;
    int s = (xcd < rr) ? xcd*(q+1) + idx : rr*(q+1) + (xcd - rr)*q + idx;
    const int n0 = (s % 6) * 128, m0 = (s / 6) * 128;
    const int tid = threadIdx.x;
    const int wave = tid >> 6, lane = tid & 63;
    const int wr = (wave >> 1)*64, wc = (wave & 1)*64;
    const int fr = lane & 15, fq = lane >> 4;
    const int xk = (fq ^ (fr & 3)) * 8;

    f32x4_ acc[4][4] = {};

    #define CLA_(r) ((m0 + (r) < M_TOK) ? (m0 + (r)) : (M_TOK-1))
    #define CLB_(r) (n0 + (r))
    STAGE_TILE2(At[0], A2, CLA_, 0, K2P_)
    STAGE_TILE2(Bt[0], W2, CLB_, 0, K2P_)
    STAGE_TILE2(At[1], A2, CLA_, 32, K2P_)
    STAGE_TILE2(Bt[1], W2, CLB_, 32, K2P_)
    BAR_VM4();
    for (int kt = 0; kt < NTP_; kt++) {
        const int cur = kt & 1;
        bf16x8_ a[4], bb[4];
        #pragma unroll
        for (int i = 0; i < 4; i++) {
            a[i]  = *(const bf16x8_*)&At[cur][(wr + i*16 + fr)*32 + xk];
            bb[i] = *(const bf16x8_*)&Bt[cur][(wc + i*16 + fr)*32 + xk];
        }
        #pragma unroll
        for (int mi = 0; mi < 4; mi++)
            #pragma unroll
            for (int ni = 0; ni < 4; ni++)
                acc[mi][ni] = __builtin_amdgcn_mfma_f32_16x16x32_bf16(a[mi], bb[ni], acc[mi][ni], 0, 0, 0);
        BAR_LGKM();
        if (kt + 2 < NTP_) {
            STAGE_TILE2(At[cur], A2, CLA_, (kt+2)*32, K2P_)
            STAGE_TILE2(Bt[cur], W2, CLB_, (kt+2)*32, K2P_)
            BAR_VM4();
        } else if (kt + 1 < NTP_) {
            BAR_VM0();
        }
    }
    #undef CLA_
    #undef CLB_

    const float w0 = SC[0], w12 = SC[1] + SC[2];
    float bv[4];
    #pragma unroll
    for (int ni = 0; ni < 4; ni++) bv[ni] = bias[n0 + wc + ni*16 + fr];
    #pragma unroll
    for (int mi = 0; mi < 4; mi++) {
        #pragma unroll
        for (int j = 0; j < 4; j++) {
            int row = m0 + wr + mi*16 + fq*4 + j;
            if (row < M_TOK) {
                int b = row / N_;
                int n = row - b*N_;
                float* orow = out + (size_t)row*768 + n0 + wc;
                if (n == 0) {
                    const float* xr = x + (size_t)row*768 + n0 + wc;
                    #pragma unroll
                    for (int ni = 0; ni < 4; ni++)
                        orow[ni*16 + fr] = acc[mi][ni][j] + w0*bv[ni] + w12*xr[ni*16 + fr];
                } else {
                    #pragma unroll
                    for (int ni = 0; ni < 4; ni++)
                        orow[ni*16 + fr] = acc[mi][ni][j] + (w0 + w12)*bv[ni];
                }
            }
        }
    }
}

// ---------------- fused flash attention v2 (bf16 MFMA, no staging, LDS P-transfer) ----------------
__global__ __launch_bounds__(256) void flash_attn(
    const unsigned short* __restrict__ qkbf,
    const unsigned short* __restrict__ vbfT,
    const float* __restrict__ v_b,
    unsigned short* __restrict__ msa2)
{
    __shared__ unsigned short Plds[4][4][16][24];
    const int bh = blockIdx.x;
    const int b = bh / NH_, h = bh % NH_;
    const int tid = threadIdx.x;
    const int wv = tid >> 6, lane = tid & 63;
    const int fr = lane & 15, fq = lane >> 4;

    const unsigned short* Kg = qkbf + (size_t)(b*N_)*1536 + 768 + h*64;
    const unsigned short* Vg = vbfT + (size_t)bh*(64*224);

    bf16x8_ qf[4][2];
    #pragma unroll
    for (int nf = 0; nf < 4; nf++) {
        int qr = wv*64 + nf*16 + fr; if (qr > N_-1) qr = N_-1;
        const unsigned short* Qg = qkbf + (size_t)(b*N_ + qr)*1536 + h*64;
        qf[nf][0] = *(const bf16x8_*)(Qg + fq*8);
        qf[nf][1] = *(const bf16x8_*)(Qg + 32 + fq*8);
    }

    f32x4_ o[4][4];
    #pragma unroll
    for (int i = 0; i < 4; i++)
        #pragma unroll
        for (int j2 = 0; j2 < 4; j2++) { o[i][j2][0]=0.f; o[i][j2][1]=0.f; o[i][j2][2]=0.f; o[i][j2][3]=0.f; }
    float m_[4] = {-1e30f,-1e30f,-1e30f,-1e30f};
    float l_[4] = {0.f,0.f,0.f,0.f};

    for (int t = 0; t < 14; t++) {
        int kr = t*16 + fr; if (kr > N_-1) kr = N_-1;
        const unsigned short* krp = Kg + (size_t)kr*1536;
        bf16x8_ kf0 = *(const bf16x8_*)(krp + fq*8);
        bf16x8_ kf1 = *(const bf16x8_*)(krp + 32 + fq*8);
        f32x4_ st[4];
        #pragma unroll
        for (int nf = 0; nf < 4; nf++) {
            f32x4_ z = {0.f,0.f,0.f,0.f};
            z = __builtin_amdgcn_mfma_f32_16x16x32_bf16(kf0, qf[nf][0], z, 0,0,0);
            z = __builtin_amdgcn_mfma_f32_16x16x32_bf16(kf1, qf[nf][1], z, 0,0,0);
            st[nf] = z;
        }
        const int cbase = t*16 + fq*4;
        #pragma unroll
        for (int nf = 0; nf < 4; nf++) {
            #pragma unroll
            for (int jj = 0; jj < 4; jj++)
                st[nf][jj] = (cbase + jj < N_) ? st[nf][jj]*SCALE_ : -1e30f;
            float tm = fmaxf(fmaxf(st[nf][0],st[nf][1]), fmaxf(st[nf][2],st[nf][3]));
            tm = fmaxf(tm, __shfl_xor(tm, 16));
            tm = fmaxf(tm, __shfl_xor(tm, 32));
            if (__any(tm > m_[nf] + 8.f)) {
                float mn = fmaxf(m_[nf], tm);
                float sc = __expf(m_[nf] - mn);
                l_[nf] *= sc;
                m_[nf] = mn;
                #pragma unroll
                for (int df = 0; df < 4; df++) {
                    o[df][nf][0]*=sc; o[df][nf][1]*=sc; o[df][nf][2]*=sc; o[df][nf][3]*=sc;
                }
            }
            float mn = m_[nf];
            float e0 = __expf(st[nf][0] - mn);
            float e1 = __expf(st[nf][1] - mn);
            float e2 = __expf(st[nf][2] - mn);
            float e3 = __expf(st[nf][3] - mn);
            float ps = e0 + e1 + e2 + e3;
            ps += __shfl_xor(ps, 16);
            ps += __shfl_xor(ps, 32);
            l_[nf] += ps;
            unsigned lo = (unsigned)bfr_(e0) | ((unsigned)bfr_(e1) << 16);
            unsigned hi = (unsigned)bfr_(e2) | ((unsigned)bfr_(e3) << 16);
            *(uint2*)&Plds[wv][nf][fr][fq*4] = make_uint2(lo, hi);
        }
        asm volatile("s_waitcnt lgkmcnt(0)" ::: "memory");
        __builtin_amdgcn_sched_barrier(0);
        bf16x8_ pa[4];
        #pragma unroll
        for (int nf = 0; nf < 4; nf++) {
            if (fq < 2) pa[nf] = *(const bf16x8_*)&Plds[wv][nf][fr][fq*8];
            else { bf16x8_ z2 = {0,0,0,0,0,0,0,0}; pa[nf] = z2; }
        }
        #pragma unroll
        for (int df = 0; df < 4; df++) {
            int d = df*16 + fr;
            int ko = t*16 + fq*8; if (ko > 216) ko = 216;
            bf16x8_ vf = *(const bf16x8_*)(Vg + (size_t)d*224 + ko);
            #pragma unroll
            for (int nf = 0; nf < 4; nf++)
                o[df][nf] = __builtin_amdgcn_mfma_f32_16x16x32_bf16(vf, pa[nf], o[df][nf], 0,0,0);
        }
    }
    #pragma unroll
    for (int nf = 0; nf < 4; nf++) {
        int qr = wv*64 + nf*16 + fr;
        if (qr >= N_) continue;
        float inv = 1.f / l_[nf];
        unsigned short* orow = msa2 + (size_t)(b*N_ + qr)*K2P_ + h*64;
        #pragma unroll
        for (int df = 0; df < 4; df++) {
            const float4 vb4 = *(const float4*)&v_b[h*64 + df*16 + fq*4];
            unsigned u0 = (unsigned)bfr_(o[df][nf][0]*inv + vb4.x)
                        | ((unsigned)bfr_(o[df][nf][1]*inv + vb4.y) << 16);
            unsigned u1 = (unsigned)bfr_(o[df][nf][2]*inv + vb4.z)
                        | ((unsigned)bfr_(o[df][nf][3]*inv + vb4.w) << 16);
            uint2 w; w.x = u0; w.y = u1;
            *(uint2*)(orow + df*16 + fq*4) = w;
        }
    }
}

// ---------------- new_v (bf16 in, bf16 out) ----------------
__global__ __launch_bounds__(256) void newv_kernel(
    const unsigned short* __restrict__ vbf, const float* __restrict__ SC,
    unsigned short* __restrict__ newvb)
{
    int idx = blockIdx.x*256 + threadIdx.x;
    if (idx >= M_PATCH*64) return;
    int d = idx & 63; int bp = idx >> 6;
    int p = bp % NP_, b = bp / NP_;
    const unsigned short* src = vbf + (size_t)(b*N_ + 1 + p)*768 + d;
    float vh[12];
    #pragma unroll
    for (int h = 0; h < 12; h++) vh[h] = bf2f_(src[h*64]);
    #pragma unroll
    for (int k = 0; k < 9; k++) {
        float s = 0.f;
        #pragma unroll
        for (int h = 0; h < 12; h++) s += vh[h]*SC[HP_OFF + h*9 + k];
        newvb[((size_t)bp*9 + k)*64 + d] = bfr_(s);
    }
}

// ---------------- fused c1pre + c3pre + BN partial stats -> bf16 c13 ----------------
__global__ __launch_bounds__(256) void fuse13_kernel(
    const unsigned short* __restrict__ newvb, const float* __restrict__ SC,
    unsigned short* __restrict__ c13bf, float* __restrict__ part)
{
    __shared__ float sd1[256], sq1[256], sd3[256], sq3[256];
    int tid = threadIdx.x;
    float s1 = 0.f, q1 = 0.f, s3 = 0.f, q3 = 0.f;
    for (int i = blockIdx.x*256 + tid; i < M_PATCH*64; i += 65536) {
        int d = i & 63; int bij = i >> 6;
        int j = bij % 14; int bi = bij / 14; int irow = bi % 14; int b = bi / 14;
        float c1v = bf2f_(newvb[((size_t)bij*9 + 4)*64 + d]) + SC[NVB_OFF + d*9 + 4];
        float c3v = SC[SVB_OFF + d];
        #pragma unroll
        for (int p = 0; p < 9; p++) {
            int h1 = p % 3, h2 = p / 3;
            int y = irow + h1 - 1, xx = j + h2 - 1;
            if (y >= 0 && y < 14 && xx >= 0 && xx < 14)
                c3v += bf2f_(newvb[(((size_t)b*NP_ + y*14 + xx)*9 + p)*64 + d]);
        }
        c13bf[(size_t)bij*128 + d]      = bfr_(c1v);
        c13bf[(size_t)bij*128 + 64 + d] = bfr_(c3v);
        s1 += c1v; q1 += c1v*c1v; s3 += c3v; q3 += c3v*c3v;
    }
    sd1[tid] = s1; sq1[tid] = q1; sd3[tid] = s3; sq3[tid] = q3;
    __syncthreads();
    if (tid < 64) {
        part[blockIdx.x*256 + tid]       = sd1[tid]+sd1[tid+64]+sd1[tid+128]+sd1[tid+192];
        part[blockIdx.x*256 + 64 + tid]  = sq1[tid]+sq1[tid+64]+sq1[tid+128]+sq1[tid+192];
        part[blockIdx.x*256 + 128 + tid] = sd3[tid]+sd3[tid+64]+sd3[tid+128]+sd3[tid+192];
        part[blockIdx.x*256 + 192 + tid] = sq3[tid]+sq3[tid+64]+sq3[tid+128]+sq3[tid+192];
    }
}

// ---------------- reduce both BN stats -> scale/offset pairs ----------------
__global__ void bnreduce2_kernel(const float* __restrict__ part,
                                 const float* __restrict__ g1, const float* __restrict__ b1,
                                 const float* __restrict__ g3, const float* __restrict__ b3,
                                 float* __restrict__ stats)
{
    __shared__ float red[256];
    int t = threadIdx.x;  // 256
    float s = 0.f;
    for (int i = 0; i < 256; i++) s += part[i*256 + t];
    red[t] = s;
    __syncthreads();
    const float invN = 1.0f/12544.0f;
    if (t < 64) {
        float mean = red[t]*invN;
        float var  = red[64+t]*invN - mean*mean;
        float sc = rsqrtf(var + BN_EPS_) * g1[t];
        stats[t]      = sc;
        stats[64+t]   = b1[t] - mean*sc;
    } else if (t < 128) {
        int d = t - 64;
        float mean = red[128+d]*invN;
        float var  = red[192+d]*invN - mean*mean;
        float sc = rsqrtf(var + BN_EPS_) * g3[d];
        stats[128+d]  = sc;
        stats[192+d]  = b3[d] - mean*sc;
    }
}

// ---------------- BN apply + relu -> act13 (bf16, M_TOK layout, cls rows = 0) ----------------
__global__ __launch_bounds__(256) void bnapply13_kernel(
    const unsigned short* __restrict__ c13bf, const float* __restrict__ stats,
    unsigned short* __restrict__ msa2)
{
    int idx = blockIdx.x*256 + threadIdx.x;
    if (idx >= M_TOK*128) return;
    int k = idx & 127; int row = idx >> 7;
    int b = row / N_; int n = row - b*N_;
    float val = 0.f;
    if (n > 0) {
        float v = bf2f_(c13bf[(size_t)(b*NP_ + n - 1)*128 + k]);
        float sc, off;
        if (k < 64) { sc = stats[k]; off = stats[64+k]; }
        else        { sc = stats[64+k]; off = stats[128+k]; }   // 128+(k-64), 192+(k-64)
        val = fmaxf(v*sc + off, 0.f);
    }
    msa2[(size_t)row*K2P_ + 768 + k] = bfr_(val);
}

// ---------------- combined proj weights: Wp[c][0:768]=w0*proj_w, [768:896]=Wc ----------------
__global__ __launch_bounds__(256) void w13_kernel(
    const float* __restrict__ proj_w, const float* __restrict__ SC,
    unsigned short* __restrict__ Wp)
{
    int idx = blockIdx.x*256 + threadIdx.x;
    if (idx >= 768*K2P_) return;
    int k = idx % K2P_, c = idx / K2P_;
    float s;
    if (k < 768) {
        s = SC[0] * proj_w[(size_t)c*768 + k];
    } else {
        int d2 = k - 768;
        s = 0.f;
        if (d2 < 64) {
            #pragma unroll
            for (int h = 0; h < 12; h++)
                s += proj_w[(size_t)c*768 + h*64 + d2] * SC[HP_OFF + h*9 + 4];
            s *= SC[2];   // w2 * W1
        } else {
            int dd = d2 - 64;
            #pragma unroll
            for (int h = 0; h < 12; h++)
                s += proj_w[(size_t)c*768 + h*64 + dd] * SC[HPROW_OFF + h];
            s *= SC[1];   // w1 * W3
        }
    }
    Wp[(size_t)c*K2P_ + k] = bfr_(s);
}

// ---------------- launch ----------------
extern "C" void kernel_launch(void* const* d_in, const int* in_sizes, int n_in,
                              void* d_out, int out_size, void* d_ws, size_t ws_size,
                              hipStream_t stream)
{
    const float* x        = (const float*)d_in[0];
    const float* uniforms = (const float*)d_in[1];
    const float* qk_w     = (const float*)d_in[2];
    const float* qk_b     = (const float*)d_in[3];
    const float* v_w      = (const float*)d_in[4];
    const float* v_b      = (const float*)d_in[5];
    const float* proj_w   = (const float*)d_in[6];
    const float* proj_b   = (const float*)d_in[7];
    const float* bn1_g    = (const float*)d_in[8];
    const float* bn1_b    = (const float*)d_in[9];
    const float* bn3_g    = (const float*)d_in[10];
    const float* bn3_b    = (const float*)d_in[11];
    const float* kth      = (const float*)d_in[12];
    const float* head_probs = (const float*)d_in[13];
    float* out = (float*)d_out;

    // ws regions; every alias written-in-full (or written-then-read) in order each call
    float* ws = (float*)d_ws;
    float* R1 = ws;                     // 19,365,888 floats
    float* R2 = ws + 19365888;          //  9,682,944 floats
    float* R3 = ws + 29048832;          //  9,682,944 floats
    float* SC = ws + 38731776;          //    132,096 floats
    // R1: qkbf ushort [0,19365888) + vbfT ushort [19365888,30375936) -> flash; then newvb.
    unsigned short* qkbf = (unsigned short*)R1;
    unsigned short* vbfT = (unsigned short*)R1 + 19365888;
    unsigned short* newvb = (unsigned short*)R1;
    // R2: vbf ushort [0,9682944) -> newv; then c13bf ushort [0,1605632) (after newv).
    unsigned short* vbf = (unsigned short*)R2;
    unsigned short* c13bf = (unsigned short*)R2;
    // R3: x2 floats [0,4841472) -> msa2 ushort [0,11296768) (floats [0,5648384));
    //     part floats [6000000,6065536); Wp ushort at floats [6200000,+344064).
    unsigned int*   x2   = (unsigned int*)R3;
    unsigned short* msa2 = (unsigned short*)R3;
    float* part = R3 + 6000000;
    unsigned short* Wp = (unsigned short*)(R3 + 6200000);
    // d_out: W2a/W2b bf16 weights (dead after gemm_qkv) -> final out (gemm_proj).
    unsigned int* W2a = (unsigned int*)out;
    unsigned int* W2b = (unsigned int*)out + 589824;
    float* stats = SC + STATS_OFF;

    prep_kernel<<<1, 256, 0, stream>>>(uniforms, kth, head_probs, v_b, SC, out + OUT_MAIN);

    conv_hi<<<4728, 256, 0, stream>>>(x, x2, 1210368);
    conv_hi<<<576, 256, 0, stream>>>(qk_w, W2a, 147456);
    conv_hi<<<288, 256, 0, stream>>>(v_w, W2b, 73728);

    gemm_qkv<<<1782, 256, 0, stream>>>((const unsigned short*)x2,
                                       (const unsigned short*)W2a, qk_b,
                                       qkbf, vbf, (unsigned short*)vbfT);

    flash_attn<<<768, 256, 0, stream>>>(qkbf, (const unsigned short*)vbfT, v_b, msa2);

    // conv branch chain
    newv_kernel<<<3136, 256, 0, stream>>>(vbf, SC, newvb);
    fuse13_kernel<<<256, 256, 0, stream>>>(newvb, SC, c13bf, part);
    bnreduce2_kernel<<<1, 256, 0, stream>>>(part, bn1_g, bn1_b, bn3_g, bn3_b, stats);
    bnapply13_kernel<<<6304, 256, 0, stream>>>(c13bf, stats, msa2);
    w13_kernel<<<2688, 256, 0, stream>>>(proj_w, SC, Wp);

    // proj + branch + blend -> out (K=896)
    gemm_proj<<<594, 256, 0, stream>>>(msa2, Wp, proj_b, x, SC, out);
}